// Round 1
// baseline (1657.739 us; speedup 1.0000x reference)
//
#include <hip/hip_runtime.h>
#include <math.h>

constexpr int BB = 2;
constexpr int SEQ = 2048;
constexpr int HD = 1024;
constexpr int DH = 64;       // head dim
constexpr int NHEAD = 8;
constexpr int D3 = 192;      // 3*DH
constexpr int KSEL = 256;    // SEQ / SPARSITY
constexpr int RHALF = 16;    // N_ROT/2
constexpr float NEG = -1e30f;

// ---------------- router: scores[b][n][t] = X[b,t,:] . rw[:,n] ----------------
__global__ __launch_bounds__(256) void router_kernel(const float* __restrict__ X,
    const float* __restrict__ rw, float* __restrict__ scores) {
  int bt = blockIdx.x;                       // b*SEQ + t
  __shared__ float xs[HD];
  const float* xrow = X + (size_t)bt * HD;
  for (int i = threadIdx.x; i < HD; i += 256) xs[i] = xrow[i];
  __syncthreads();
  int n = threadIdx.x >> 5;                  // 8 groups of 32
  int lane = threadIdx.x & 31;
  float acc = 0.f;
  for (int h = lane; h < HD; h += 32) acc += xs[h] * rw[h * NHEAD + n];
  for (int off = 16; off > 0; off >>= 1) acc += __shfl_down(acc, off, 32);
  if (lane == 0) {
    int b = bt / SEQ, t = bt % SEQ;
    scores[((size_t)b * NHEAD + n) * SEQ + t] = acc;
  }
}

// ---------------- top-k (k=256) by rank counting; outputs sorted indices + gates ----
__global__ __launch_bounds__(1024) void topk_kernel(const float* __restrict__ scores,
    int* __restrict__ sel, float* __restrict__ gates) {
  int bn = blockIdx.x;                        // b*NHEAD + n
  __shared__ float s[SEQ];
  __shared__ int psum[1024];
  const float* sp = scores + (size_t)bn * SEQ;
  for (int i = threadIdx.x; i < SEQ; i += 1024) s[i] = sp[i];
  __syncthreads();
  int t0 = threadIdx.x * 2;
  float v0 = s[t0], v1 = s[t0 + 1];
  int r0 = 0, r1 = 0;
  for (int j = 0; j < SEQ; j++) {
    float sj = s[j];
    r0 += (sj > v0) || (sj == v0 && j < t0);
    r1 += (sj > v1) || (sj == v1 && j < t0 + 1);
  }
  int f0 = r0 < KSEL, f1 = r1 < KSEL;
  psum[threadIdx.x] = f0 + f1;
  __syncthreads();
  for (int off = 1; off < 1024; off <<= 1) {
    int val = psum[threadIdx.x];
    int add = (threadIdx.x >= off) ? psum[threadIdx.x - off] : 0;
    __syncthreads();
    psum[threadIdx.x] = val + add;
    __syncthreads();
  }
  int base = psum[threadIdx.x] - (f0 + f1);   // exclusive prefix
  if (f0) { sel[bn * KSEL + base] = t0;
            gates[bn * KSEL + base] = 1.f / (1.f + __expf(-v0)); base++; }
  if (f1) { sel[bn * KSEL + base] = t0 + 1;
            gates[bn * KSEL + base] = 1.f / (1.f + __expf(-v1)); }
}

// ---------------- tiled f32 GEMM 64x64, K step 16 ----------------
__global__ __launch_bounds__(256) void gemm_tile(const float* __restrict__ A, int lda,
    const float* __restrict__ Bw, int ldb, float* __restrict__ C, int ldc, int Kdim) {
  __shared__ float As[16][68];
  __shared__ float Bs[16][68];
  int m0 = blockIdx.x * 64, n0 = blockIdx.y * 64;
  int tid = threadIdx.x;
  int tx = tid & 15, ty = tid >> 4;
  int ra = tid >> 2, ca = (tid & 3) * 4;
  int kb = tid >> 4, cb = (tid & 15) * 4;
  float acc[4][4] = {};
  for (int k0 = 0; k0 < Kdim; k0 += 16) {
    float4 av = *(const float4*)(A + (size_t)(m0 + ra) * lda + k0 + ca);
    As[ca + 0][ra] = av.x; As[ca + 1][ra] = av.y;
    As[ca + 2][ra] = av.z; As[ca + 3][ra] = av.w;
    *(float4*)&Bs[kb][cb] = *(const float4*)(Bw + (size_t)(k0 + kb) * ldb + n0 + cb);
    __syncthreads();
#pragma unroll
    for (int kk = 0; kk < 16; kk++) {
      float4 a4 = *(const float4*)&As[kk][ty * 4];
      float4 b4 = *(const float4*)&Bs[kk][tx * 4];
      float aa[4] = {a4.x, a4.y, a4.z, a4.w};
      float bb[4] = {b4.x, b4.y, b4.z, b4.w};
#pragma unroll
      for (int i = 0; i < 4; i++)
#pragma unroll
        for (int j = 0; j < 4; j++) acc[i][j] += aa[i] * bb[j];
    }
    __syncthreads();
  }
#pragma unroll
  for (int i = 0; i < 4; i++) {
    float4 r = make_float4(acc[i][0], acc[i][1], acc[i][2], acc[i][3]);
    *(float4*)(C + (size_t)(m0 + ty * 4 + i) * ldc + n0 + tx * 4) = r;
  }
}

// ---------------- mosa qkv: gathered-rows GEMM per (b,n) ----------------
__global__ __launch_bounds__(256) void gemm_mosa_qkv(const float* __restrict__ X,
    const float* __restrict__ wqkv, const int* __restrict__ sel, float* __restrict__ qkvm) {
  __shared__ float As[16][68];
  __shared__ float Bs[16][68];
  int bn = blockIdx.x; int b = bn / NHEAD, n = bn % NHEAD;
  int m0 = blockIdx.y * 64, n0 = blockIdx.z * 64;
  int tid = threadIdx.x;
  int tx = tid & 15, ty = tid >> 4;
  int ra = tid >> 2, ca = (tid & 3) * 4;
  int kb = tid >> 4, cb = (tid & 15) * 4;
  int grow = sel[bn * KSEL + m0 + ra];
  const float* arow = X + (size_t)(b * SEQ + grow) * HD;
  float acc[4][4] = {};
  for (int k0 = 0; k0 < HD; k0 += 16) {
    float4 av = *(const float4*)(arow + k0 + ca);
    As[ca + 0][ra] = av.x; As[ca + 1][ra] = av.y;
    As[ca + 2][ra] = av.z; As[ca + 3][ra] = av.w;
    *(float4*)&Bs[kb][cb] =
        *(const float4*)(wqkv + (size_t)(k0 + kb) * (NHEAD * D3) + n * D3 + n0 + cb);
    __syncthreads();
#pragma unroll
    for (int kk = 0; kk < 16; kk++) {
      float4 a4 = *(const float4*)&As[kk][ty * 4];
      float4 b4 = *(const float4*)&Bs[kk][tx * 4];
      float aa[4] = {a4.x, a4.y, a4.z, a4.w};
      float bb[4] = {b4.x, b4.y, b4.z, b4.w};
#pragma unroll
      for (int i = 0; i < 4; i++)
#pragma unroll
        for (int j = 0; j < 4; j++) acc[i][j] += aa[i] * bb[j];
    }
    __syncthreads();
  }
#pragma unroll
  for (int i = 0; i < 4; i++) {
    float4 r = make_float4(acc[i][0], acc[i][1], acc[i][2], acc[i][3]);
    *(float4*)(qkvm + ((size_t)bn * KSEL + m0 + ty * 4 + i) * D3 + n0 + tx * 4) = r;
  }
}

// ---------------- RoPE (in place on Q and K halves) ----------------
__global__ void rope_mosa(float* __restrict__ qkvm, const int* __restrict__ sel) {
  int tid = blockIdx.x * 256 + threadIdx.x;
  if (tid >= BB * NHEAD * KSEL * RHALF) return;
  int j = tid & (RHALF - 1);
  int row = tid >> 4;                       // bn*KSEL + r
  float pos = (float)sel[row];
  float inv = powf(10000.f, -(float)j / (float)RHALF);
  float ang = pos * inv;
  float c = cosf(ang), sn = sinf(ang);
  float* qp = qkvm + (size_t)row * D3;
  float q1 = qp[j], q2 = qp[j + RHALF];
  qp[j] = q1 * c - q2 * sn; qp[j + RHALF] = q1 * sn + q2 * c;
  float* kp = qp + DH;
  float k1 = kp[j], k2 = kp[j + RHALF];
  kp[j] = k1 * c - k2 * sn; kp[j + RHALF] = k1 * sn + k2 * c;
}

__global__ void rope_dense(float* __restrict__ qkvd) {
  int tid = blockIdx.x * 256 + threadIdx.x;
  if (tid >= BB * SEQ * NHEAD * RHALF) return;
  int j = tid & (RHALF - 1);
  int row = tid >> 4;                       // (b*SEQ+t)*NHEAD + n
  int t = (row / NHEAD) & (SEQ - 1);
  float pos = (float)t;
  float inv = powf(10000.f, -(float)j / (float)RHALF);
  float ang = pos * inv;
  float c = cosf(ang), sn = sinf(ang);
  float* qp = qkvd + (size_t)row * D3;
  float q1 = qp[j], q2 = qp[j + RHALF];
  qp[j] = q1 * c - q2 * sn; qp[j + RHALF] = q1 * sn + q2 * c;
  float* kp = qp + DH;
  float k1 = kp[j], k2 = kp[j + RHALF];
  kp[j] = k1 * c - k2 * sn; kp[j + RHALF] = k1 * sn + k2 * c;
}

// ---------------- mosa attention: 1 thread per query row, 256 keys ----------------
__global__ __launch_bounds__(256) void mosa_attn(const float* __restrict__ qkvm,
    const int* __restrict__ sel, const float* __restrict__ gates, float* __restrict__ avm) {
  int bn = blockIdx.x; int b = bn / NHEAD, n = bn % NHEAD;
  int q = threadIdx.x;
  const float* basep = qkvm + (size_t)bn * KSEL * D3;
  float4 qv[16], ov[16];
  const float4* q4 = (const float4*)(basep + (size_t)q * D3);
#pragma unroll
  for (int i = 0; i < 16; i++) {
    float4 t = q4[i];
    qv[i] = make_float4(t.x * .125f, t.y * .125f, t.z * .125f, t.w * .125f);
    ov[i] = make_float4(0.f, 0.f, 0.f, 0.f);
  }
  float m = NEG, l = 0.f;
  for (int k = 0; k < KSEL; k++) {
    const float4* k4 = (const float4*)(basep + (size_t)k * D3 + DH);
    float s = 0.f;
#pragma unroll
    for (int i = 0; i < 16; i++) {
      float4 kv = k4[i];
      s += qv[i].x * kv.x + qv[i].y * kv.y + qv[i].z * kv.z + qv[i].w * kv.w;
    }
    if (k > q) s = NEG;                     // causal in compact (sorted) space
    float mn = fmaxf(m, s);
    float scale = __expf(m - mn), p = __expf(s - mn);
    l = l * scale + p;
    const float4* v4 = (const float4*)(basep + (size_t)k * D3 + 2 * DH);
#pragma unroll
    for (int i = 0; i < 16; i++) {
      float4 vv = v4[i];
      ov[i].x = ov[i].x * scale + p * vv.x;
      ov[i].y = ov[i].y * scale + p * vv.y;
      ov[i].z = ov[i].z * scale + p * vv.z;
      ov[i].w = ov[i].w * scale + p * vv.w;
    }
    m = mn;
  }
  float g = gates[bn * KSEL + q];
  float inv = g / l;
  int t = sel[bn * KSEL + q];
  float* orow = avm + ((size_t)(b * SEQ + t)) * (NHEAD * DH) + n * DH;
#pragma unroll
  for (int i = 0; i < 16; i++)
    ((float4*)orow)[i] = make_float4(ov[i].x * inv, ov[i].y * inv, ov[i].z * inv, ov[i].w * inv);
}

// ---------------- dense attention: 64 queries/block, 4-way key split + LDS merge ----
__global__ __launch_bounds__(256) void dense_attn(const float* __restrict__ qkvd,
                                                  float* __restrict__ avd) {
  int bn = blockIdx.x; int b = bn / NHEAD, n = bn % NHEAD;
  int qt = blockIdx.y;
  int qi = threadIdx.x & 63;
  int sub = threadIdx.x >> 6;               // one wave per sub
  int q = qt * 64 + qi;
  const int rs = NHEAD * D3;                // row stride (floats) per t
  const float* base = qkvd + ((size_t)(b * SEQ)) * rs + (size_t)n * D3;
  float4 qv[16], ov[16];
  {
    const float4* q4 = (const float4*)(base + (size_t)q * rs);
#pragma unroll
    for (int i = 0; i < 16; i++) {
      float4 t = q4[i];
      qv[i] = make_float4(t.x * .125f, t.y * .125f, t.z * .125f, t.w * .125f);
      ov[i] = make_float4(0.f, 0.f, 0.f, 0.f);
    }
  }
  float m = NEG, l = 0.f;
  int ntile = qt + 1;
  for (int kt = sub; kt < ntile; kt += 4) {
    const float* krow0 = base + (size_t)(kt * 64) * rs;
    for (int kk = 0; kk < 64; kk++) {
      int k = kt * 64 + kk;
      const float4* k4 = (const float4*)(krow0 + (size_t)kk * rs + DH);
      float s = 0.f;
#pragma unroll
      for (int i = 0; i < 16; i++) {
        float4 kv = k4[i];
        s += qv[i].x * kv.x + qv[i].y * kv.y + qv[i].z * kv.z + qv[i].w * kv.w;
      }
      if (k > q) s = NEG;
      float mn = fmaxf(m, s);
      float scale = __expf(m - mn), p = __expf(s - mn);
      l = l * scale + p;
      const float4* v4 = (const float4*)(krow0 + (size_t)kk * rs + 2 * DH);
#pragma unroll
      for (int i = 0; i < 16; i++) {
        float4 vv = v4[i];
        ov[i].x = ov[i].x * scale + p * vv.x;
        ov[i].y = ov[i].y * scale + p * vv.y;
        ov[i].z = ov[i].z * scale + p * vv.z;
        ov[i].w = ov[i].w * scale + p * vv.w;
      }
      m = mn;
    }
  }
  // merge the 4 partial online-softmax states per query
  __shared__ float Om[3][DH][64];
  __shared__ float Ml[3][64][2];
  if (sub > 0) {
    int si = sub - 1;
#pragma unroll
    for (int i = 0; i < 16; i++) {
      Om[si][4 * i + 0][qi] = ov[i].x;
      Om[si][4 * i + 1][qi] = ov[i].y;
      Om[si][4 * i + 2][qi] = ov[i].z;
      Om[si][4 * i + 3][qi] = ov[i].w;
    }
    Ml[si][qi][0] = m; Ml[si][qi][1] = l;
  }
  __syncthreads();
  if (sub == 0) {
    float m1 = Ml[0][qi][0], m2 = Ml[1][qi][0], m3 = Ml[2][qi][0];
    float M = fmaxf(fmaxf(m, m1), fmaxf(m2, m3));
    float c0 = __expf(m - M), c1 = __expf(m1 - M), c2 = __expf(m2 - M), c3 = __expf(m3 - M);
    float L = c0 * l + c1 * Ml[0][qi][1] + c2 * Ml[1][qi][1] + c3 * Ml[2][qi][1];
    float inv = 1.f / L;
    float* orow = avd + ((size_t)(b * SEQ + q)) * (NHEAD * DH) + n * DH;
#pragma unroll
    for (int i = 0; i < 16; i++) {
      float4 r;
      r.x = inv * (c0 * ov[i].x + c1 * Om[0][4*i+0][qi] + c2 * Om[1][4*i+0][qi] + c3 * Om[2][4*i+0][qi]);
      r.y = inv * (c0 * ov[i].y + c1 * Om[0][4*i+1][qi] + c2 * Om[1][4*i+1][qi] + c3 * Om[2][4*i+1][qi]);
      r.z = inv * (c0 * ov[i].z + c1 * Om[0][4*i+2][qi] + c2 * Om[1][4*i+2][qi] + c3 * Om[2][4*i+2][qi]);
      r.w = inv * (c0 * ov[i].w + c1 * Om[0][4*i+3][qi] + c2 * Om[1][4*i+3][qi] + c3 * Om[2][4*i+3][qi]);
      ((float4*)orow)[i] = r;
    }
  }
}

// ---------------- final: C = A1@W1 + A2@W2 (M=4096,K=512 each,N=1024) ----------------
__global__ __launch_bounds__(256) void gemm_final(const float* __restrict__ A1,
    const float* __restrict__ W1, const float* __restrict__ A2,
    const float* __restrict__ W2, float* __restrict__ C) {
  __shared__ float As[16][68];
  __shared__ float Bs[16][68];
  int m0 = blockIdx.x * 64, n0 = blockIdx.y * 64;
  int tid = threadIdx.x;
  int tx = tid & 15, ty = tid >> 4;
  int ra = tid >> 2, ca = (tid & 3) * 4;
  int kb = tid >> 4, cb = (tid & 15) * 4;
  float acc[4][4] = {};
  for (int pass = 0; pass < 2; pass++) {
    const float* A = pass ? A2 : A1;
    const float* W = pass ? W2 : W1;
    for (int k0 = 0; k0 < 512; k0 += 16) {
      float4 av = *(const float4*)(A + (size_t)(m0 + ra) * 512 + k0 + ca);
      As[ca + 0][ra] = av.x; As[ca + 1][ra] = av.y;
      As[ca + 2][ra] = av.z; As[ca + 3][ra] = av.w;
      *(float4*)&Bs[kb][cb] = *(const float4*)(W + (size_t)(k0 + kb) * HD + n0 + cb);
      __syncthreads();
#pragma unroll
      for (int kk = 0; kk < 16; kk++) {
        float4 a4 = *(const float4*)&As[kk][ty * 4];
        float4 b4 = *(const float4*)&Bs[kk][tx * 4];
        float aa[4] = {a4.x, a4.y, a4.z, a4.w};
        float bb[4] = {b4.x, b4.y, b4.z, b4.w};
#pragma unroll
        for (int i = 0; i < 4; i++)
#pragma unroll
          for (int j = 0; j < 4; j++) acc[i][j] += aa[i] * bb[j];
      }
      __syncthreads();
    }
  }
#pragma unroll
  for (int i = 0; i < 4; i++) {
    float4 r = make_float4(acc[i][0], acc[i][1], acc[i][2], acc[i][3]);
    *(float4*)(C + (size_t)(m0 + ty * 4 + i) * HD + n0 + tx * 4) = r;
  }
}

extern "C" void kernel_launch(void* const* d_in, const int* in_sizes, int n_in,
                              void* d_out, int out_size, void* d_ws, size_t ws_size,
                              hipStream_t stream) {
  const float* X          = (const float*)d_in[0];
  const float* router_w   = (const float*)d_in[1];
  const float* mosa_wqkv  = (const float*)d_in[2];
  const float* mosa_wo    = (const float*)d_in[3];
  const float* dense_wqkv = (const float*)d_in[4];
  const float* dense_wo   = (const float*)d_in[5];
  float* out = (float*)d_out;
  char* ws = (char*)d_ws;

  // workspace layout (bytes)
  float* scores = (float*)(ws + 0);                   // 2*8*2048*4       = 131072
  int*   sel    = (int*)  (ws + 131072);              // 2*8*256*4        = 16384
  float* gates  = (float*)(ws + 147456);              // 16384
  float* qkvm   = (float*)(ws + 163840);              // 2*8*256*192*4    = 3145728
  float* avm    = (float*)(ws + 3309568);             // 2*2048*512*4     = 8388608
  float* qkvd   = (float*)(ws + 11698176);            // 2*2048*1536*4    = 25165824
  float* avd    = (float*)(ws + 36864000);            // 8388608  (end: 45252608)

  hipMemsetAsync(avm, 0, (size_t)BB * SEQ * NHEAD * DH * sizeof(float), stream);

  router_kernel<<<BB * SEQ, 256, 0, stream>>>(X, router_w, scores);
  topk_kernel<<<BB * NHEAD, 1024, 0, stream>>>(scores, sel, gates);
  gemm_mosa_qkv<<<dim3(BB * NHEAD, KSEL / 64, D3 / 64), 256, 0, stream>>>(X, mosa_wqkv, sel, qkvm);
  rope_mosa<<<(BB * NHEAD * KSEL * RHALF + 255) / 256, 256, 0, stream>>>(qkvm, sel);
  mosa_attn<<<BB * NHEAD, 256, 0, stream>>>(qkvm, sel, gates, avm);
  gemm_tile<<<dim3(BB * SEQ / 64, (NHEAD * D3) / 64), 256, 0, stream>>>(
      X, HD, dense_wqkv, NHEAD * D3, qkvd, NHEAD * D3, HD);
  rope_dense<<<(BB * SEQ * NHEAD * RHALF + 255) / 256, 256, 0, stream>>>(qkvd);
  dense_attn<<<dim3(BB * NHEAD, SEQ / 64), 256, 0, stream>>>(qkvd, avd);
  gemm_final<<<dim3(BB * SEQ / 64, HD / 64), 256, 0, stream>>>(avm, mosa_wo, avd, dense_wo, out);
}

// Round 2
// 991.831 us; speedup vs baseline: 1.6714x; 1.6714x over previous
//
#include <hip/hip_runtime.h>
#include <math.h>

constexpr int BB = 2;
constexpr int SEQ = 2048;
constexpr int HD = 1024;
constexpr int DH = 64;       // head dim
constexpr int NHEAD = 8;
constexpr int D3 = 192;      // 3*DH
constexpr int KSEL = 256;    // SEQ / SPARSITY
constexpr int RHALF = 16;    // N_ROT/2
constexpr float NEG = -1e30f;

// ---------------- router: scores[b][n][t] = X[b,t,:] . rw[:,n] ----------------
__global__ __launch_bounds__(256) void router_kernel(const float* __restrict__ X,
    const float* __restrict__ rw, float* __restrict__ scores) {
  int bt = blockIdx.x;                       // b*SEQ + t
  __shared__ float xs[HD];
  const float* xrow = X + (size_t)bt * HD;
  for (int i = threadIdx.x; i < HD; i += 256) xs[i] = xrow[i];
  __syncthreads();
  int n = threadIdx.x >> 5;                  // 8 groups of 32
  int lane = threadIdx.x & 31;
  float acc = 0.f;
  for (int h = lane; h < HD; h += 32) acc += xs[h] * rw[h * NHEAD + n];
  for (int off = 16; off > 0; off >>= 1) acc += __shfl_down(acc, off, 32);
  if (lane == 0) {
    int b = bt / SEQ, t = bt % SEQ;
    scores[((size_t)b * NHEAD + n) * SEQ + t] = acc;
  }
}

// ---------------- top-k (k=256) by rank counting; outputs sorted indices + gates ----
__global__ __launch_bounds__(1024) void topk_kernel(const float* __restrict__ scores,
    int* __restrict__ sel, float* __restrict__ gates) {
  int bn = blockIdx.x;                        // b*NHEAD + n
  __shared__ float s[SEQ];
  __shared__ int psum[1024];
  const float* sp = scores + (size_t)bn * SEQ;
  for (int i = threadIdx.x; i < SEQ; i += 1024) s[i] = sp[i];
  __syncthreads();
  int t0 = threadIdx.x * 2;
  float v0 = s[t0], v1 = s[t0 + 1];
  int r0 = 0, r1 = 0;
  for (int j = 0; j < SEQ; j++) {
    float sj = s[j];
    r0 += (sj > v0) || (sj == v0 && j < t0);
    r1 += (sj > v1) || (sj == v1 && j < t0 + 1);
  }
  int f0 = r0 < KSEL, f1 = r1 < KSEL;
  psum[threadIdx.x] = f0 + f1;
  __syncthreads();
  for (int off = 1; off < 1024; off <<= 1) {
    int val = psum[threadIdx.x];
    int add = (threadIdx.x >= off) ? psum[threadIdx.x - off] : 0;
    __syncthreads();
    psum[threadIdx.x] = val + add;
    __syncthreads();
  }
  int base = psum[threadIdx.x] - (f0 + f1);   // exclusive prefix
  if (f0) { sel[bn * KSEL + base] = t0;
            gates[bn * KSEL + base] = 1.f / (1.f + __expf(-v0)); base++; }
  if (f1) { sel[bn * KSEL + base] = t0 + 1;
            gates[bn * KSEL + base] = 1.f / (1.f + __expf(-v1)); }
}

// ---------------- tiled f32 GEMM 64x64, K step 16 ----------------
__global__ __launch_bounds__(256) void gemm_tile(const float* __restrict__ A, int lda,
    const float* __restrict__ Bw, int ldb, float* __restrict__ C, int ldc, int Kdim) {
  __shared__ float As[16][68];
  __shared__ float Bs[16][68];
  int m0 = blockIdx.x * 64, n0 = blockIdx.y * 64;
  int tid = threadIdx.x;
  int tx = tid & 15, ty = tid >> 4;
  int ra = tid >> 2, ca = (tid & 3) * 4;
  int kb = tid >> 4, cb = (tid & 15) * 4;
  float acc[4][4] = {};
  for (int k0 = 0; k0 < Kdim; k0 += 16) {
    float4 av = *(const float4*)(A + (size_t)(m0 + ra) * lda + k0 + ca);
    As[ca + 0][ra] = av.x; As[ca + 1][ra] = av.y;
    As[ca + 2][ra] = av.z; As[ca + 3][ra] = av.w;
    *(float4*)&Bs[kb][cb] = *(const float4*)(Bw + (size_t)(k0 + kb) * ldb + n0 + cb);
    __syncthreads();
#pragma unroll
    for (int kk = 0; kk < 16; kk++) {
      float4 a4 = *(const float4*)&As[kk][ty * 4];
      float4 b4 = *(const float4*)&Bs[kk][tx * 4];
      float aa[4] = {a4.x, a4.y, a4.z, a4.w};
      float bb[4] = {b4.x, b4.y, b4.z, b4.w};
#pragma unroll
      for (int i = 0; i < 4; i++)
#pragma unroll
        for (int j = 0; j < 4; j++) acc[i][j] += aa[i] * bb[j];
    }
    __syncthreads();
  }
#pragma unroll
  for (int i = 0; i < 4; i++) {
    float4 r = make_float4(acc[i][0], acc[i][1], acc[i][2], acc[i][3]);
    *(float4*)(C + (size_t)(m0 + ty * 4 + i) * ldc + n0 + tx * 4) = r;
  }
}

// ---------------- mosa qkv: gathered-rows GEMM per (b,n) ----------------
__global__ __launch_bounds__(256) void gemm_mosa_qkv(const float* __restrict__ X,
    const float* __restrict__ wqkv, const int* __restrict__ sel, float* __restrict__ qkvm) {
  __shared__ float As[16][68];
  __shared__ float Bs[16][68];
  int bn = blockIdx.x; int b = bn / NHEAD, n = bn % NHEAD;
  int m0 = blockIdx.y * 64, n0 = blockIdx.z * 64;
  int tid = threadIdx.x;
  int tx = tid & 15, ty = tid >> 4;
  int ra = tid >> 2, ca = (tid & 3) * 4;
  int kb = tid >> 4, cb = (tid & 15) * 4;
  int grow = sel[bn * KSEL + m0 + ra];
  const float* arow = X + (size_t)(b * SEQ + grow) * HD;
  float acc[4][4] = {};
  for (int k0 = 0; k0 < HD; k0 += 16) {
    float4 av = *(const float4*)(arow + k0 + ca);
    As[ca + 0][ra] = av.x; As[ca + 1][ra] = av.y;
    As[ca + 2][ra] = av.z; As[ca + 3][ra] = av.w;
    *(float4*)&Bs[kb][cb] =
        *(const float4*)(wqkv + (size_t)(k0 + kb) * (NHEAD * D3) + n * D3 + n0 + cb);
    __syncthreads();
#pragma unroll
    for (int kk = 0; kk < 16; kk++) {
      float4 a4 = *(const float4*)&As[kk][ty * 4];
      float4 b4 = *(const float4*)&Bs[kk][tx * 4];
      float aa[4] = {a4.x, a4.y, a4.z, a4.w};
      float bb[4] = {b4.x, b4.y, b4.z, b4.w};
#pragma unroll
      for (int i = 0; i < 4; i++)
#pragma unroll
        for (int j = 0; j < 4; j++) acc[i][j] += aa[i] * bb[j];
    }
    __syncthreads();
  }
#pragma unroll
  for (int i = 0; i < 4; i++) {
    float4 r = make_float4(acc[i][0], acc[i][1], acc[i][2], acc[i][3]);
    *(float4*)(qkvm + ((size_t)bn * KSEL + m0 + ty * 4 + i) * D3 + n0 + tx * 4) = r;
  }
}

// ---------------- RoPE (in place on Q and K halves) ----------------
__global__ void rope_mosa(float* __restrict__ qkvm, const int* __restrict__ sel) {
  int tid = blockIdx.x * 256 + threadIdx.x;
  if (tid >= BB * NHEAD * KSEL * RHALF) return;
  int j = tid & (RHALF - 1);
  int row = tid >> 4;                       // bn*KSEL + r
  float pos = (float)sel[row];
  float inv = powf(10000.f, -(float)j / (float)RHALF);
  float ang = pos * inv;
  float c = cosf(ang), sn = sinf(ang);
  float* qp = qkvm + (size_t)row * D3;
  float q1 = qp[j], q2 = qp[j + RHALF];
  qp[j] = q1 * c - q2 * sn; qp[j + RHALF] = q1 * sn + q2 * c;
  float* kp = qp + DH;
  float k1 = kp[j], k2 = kp[j + RHALF];
  kp[j] = k1 * c - k2 * sn; kp[j + RHALF] = k1 * sn + k2 * c;
}

__global__ void rope_dense(float* __restrict__ qkvd) {
  int tid = blockIdx.x * 256 + threadIdx.x;
  if (tid >= BB * SEQ * NHEAD * RHALF) return;
  int j = tid & (RHALF - 1);
  int row = tid >> 4;                       // (b*SEQ+t)*NHEAD + n
  int t = (row / NHEAD) & (SEQ - 1);
  float pos = (float)t;
  float inv = powf(10000.f, -(float)j / (float)RHALF);
  float ang = pos * inv;
  float c = cosf(ang), sn = sinf(ang);
  float* qp = qkvd + (size_t)row * D3;
  float q1 = qp[j], q2 = qp[j + RHALF];
  qp[j] = q1 * c - q2 * sn; qp[j + RHALF] = q1 * sn + q2 * c;
  float* kp = qp + DH;
  float k1 = kp[j], k2 = kp[j + RHALF];
  kp[j] = k1 * c - k2 * sn; kp[j + RHALF] = k1 * sn + k2 * c;
}

// ---------------- unified flash attention ----------------
// 512 threads = two 256-thread groups; group 0 -> q-tile pair, group 1 -> q-tile nqt-1-pair.
// Per key tile: group 0 stages K (d-major), group 1 stages V (xor-swizzled rows).
// Each thread owns a 4x4 score / 4x4 output block; softmax stats via width-16 shfl_xor;
// PV uses __shfl to pull P values cross-lane (no LDS round-trip for P).
template <bool MOSA>
__global__ __launch_bounds__(512) void flash_attn(const float* __restrict__ qkv,
    const int* __restrict__ sel, const float* __restrict__ gates,
    float* __restrict__ outp, int nqt) {
  __shared__ float Qs[2][64][64];   // [g][d][r], Q pre-scaled by 1/8
  __shared__ float Ks[64][64];      // [d][c]
  __shared__ float Vs[64][64];      // [k][dh ^ (4*(k&15))]

  int bn = blockIdx.x;
  int pair = blockIdx.y;
  int qtA = pair, qtB = nqt - 1 - pair;
  int tid = threadIdx.x;
  int g = tid >> 8;                 // which q-tile group
  int myqt = g ? qtB : qtA;
  int q0 = myqt * 64;
  int t = tid & 255;
  int ty = t >> 4, tx = t & 15;

  const float* base;
  int rs;
  if (MOSA) { base = qkv + (size_t)bn * KSEL * D3; rs = D3; }
  else {
    int b = bn >> 3, n = bn & 7;
    base = qkv + ((size_t)b * SEQ) * (NHEAD * D3) + n * D3;
    rs = NHEAD * D3;
  }

  // stage my group's Q tile (d-major, scaled)
  {
    int r = t & 63, d0 = (t >> 6) * 16;
    const float* src = base + (size_t)(q0 + r) * rs + d0;
#pragma unroll
    for (int i = 0; i < 4; i++) {
      float4 v = *(const float4*)(src + 4 * i);
      Qs[g][d0 + 4 * i + 0][r] = v.x * 0.125f;
      Qs[g][d0 + 4 * i + 1][r] = v.y * 0.125f;
      Qs[g][d0 + 4 * i + 2][r] = v.z * 0.125f;
      Qs[g][d0 + 4 * i + 3][r] = v.w * 0.125f;
    }
  }

  float o[4][4] = {};
  float m[4], l[4];
#pragma unroll
  for (int i = 0; i < 4; i++) { m[i] = NEG; l[i] = 0.f; }

  for (int kt = 0; kt <= qtB; kt++) {
    __syncthreads();   // prev tile fully consumed (also covers Q staging at kt=0)
    {
      int r = tid & 63, d0 = ((tid >> 6) & 3) * 16;
      const float* src = base + (size_t)(kt * 64 + r) * rs + (g ? 2 * DH : DH) + d0;
      if (g == 0) {     // stage K, d-major transpose (scalar writes, conflict-free)
#pragma unroll
        for (int i = 0; i < 4; i++) {
          float4 v = *(const float4*)(src + 4 * i);
          Ks[d0 + 4 * i + 0][r] = v.x;
          Ks[d0 + 4 * i + 1][r] = v.y;
          Ks[d0 + 4 * i + 2][r] = v.z;
          Ks[d0 + 4 * i + 3][r] = v.w;
        }
      } else {          // stage V, row-major xor-swizzled (b128 writes spread over banks)
#pragma unroll
        for (int i = 0; i < 4; i++) {
          float4 v = *(const float4*)(src + 4 * i);
          *(float4*)&Vs[r][(d0 + 4 * i) ^ (4 * (r & 15))] = v;
        }
      }
    }
    __syncthreads();

    bool active = g || (kt <= qtA);
    if (active) {
      // S = Q.K^T (4x4 per thread)
      float s[4][4] = {};
#pragma unroll 8
      for (int d = 0; d < 64; d++) {
        float4 qv = *(const float4*)&Qs[g][d][4 * ty];
        float4 kv = *(const float4*)&Ks[d][4 * tx];
        float qa[4] = {qv.x, qv.y, qv.z, qv.w};
        float kb[4] = {kv.x, kv.y, kv.z, kv.w};
#pragma unroll
        for (int i = 0; i < 4; i++)
#pragma unroll
          for (int j = 0; j < 4; j++) s[i][j] += qa[i] * kb[j];
      }
      // causal mask on diagonal tile (compact-space causal == triangular for MOSA too)
      if (kt == myqt) {
#pragma unroll
        for (int i = 0; i < 4; i++)
#pragma unroll
          for (int j = 0; j < 4; j++)
            if (4 * tx + j > 4 * ty + i) s[i][j] = NEG;
      }
      // online softmax per row; p left in s[][]
#pragma unroll
      for (int i = 0; i < 4; i++) {
        float mx = fmaxf(fmaxf(s[i][0], s[i][1]), fmaxf(s[i][2], s[i][3]));
        mx = fmaxf(mx, __shfl_xor(mx, 1));
        mx = fmaxf(mx, __shfl_xor(mx, 2));
        mx = fmaxf(mx, __shfl_xor(mx, 4));
        mx = fmaxf(mx, __shfl_xor(mx, 8));
        float mn = fmaxf(m[i], mx);
        float sc = __expf(m[i] - mn);
        m[i] = mn;
#pragma unroll
        for (int j = 0; j < 4; j++) s[i][j] = __expf(s[i][j] - mn);
        float rsum = s[i][0] + s[i][1] + s[i][2] + s[i][3];
        rsum += __shfl_xor(rsum, 1);
        rsum += __shfl_xor(rsum, 2);
        rsum += __shfl_xor(rsum, 4);
        rsum += __shfl_xor(rsum, 8);
        l[i] = l[i] * sc + rsum;
#pragma unroll
        for (int j = 0; j < 4; j++) o[i][j] *= sc;
      }
      // O += P.V ; pull P cross-lane with shfl
      for (int txk = 0; txk < 16; txk++) {
        int lanesrc = (ty & 3) * 16 + txk;
#pragma unroll
        for (int j = 0; j < 4; j++) {
          int k = 4 * txk + j;
          float4 vv = *(const float4*)&Vs[k][(4 * tx) ^ (4 * (k & 15))];
          float p0 = __shfl(s[0][j], lanesrc);
          float p1 = __shfl(s[1][j], lanesrc);
          float p2 = __shfl(s[2][j], lanesrc);
          float p3 = __shfl(s[3][j], lanesrc);
          o[0][0] += p0 * vv.x; o[0][1] += p0 * vv.y; o[0][2] += p0 * vv.z; o[0][3] += p0 * vv.w;
          o[1][0] += p1 * vv.x; o[1][1] += p1 * vv.y; o[1][2] += p1 * vv.z; o[1][3] += p1 * vv.w;
          o[2][0] += p2 * vv.x; o[2][1] += p2 * vv.y; o[2][2] += p2 * vv.z; o[2][3] += p2 * vv.w;
          o[3][0] += p3 * vv.x; o[3][1] += p3 * vv.y; o[3][2] += p3 * vv.z; o[3][3] += p3 * vv.w;
        }
      }
    }
  }

  // epilogue
  int b = bn >> 3, n = bn & 7;
#pragma unroll
  for (int i = 0; i < 4; i++) {
    int qc = q0 + 4 * ty + i;
    float inv;
    size_t row;
    if (MOSA) {
      int trow = sel[bn * KSEL + qc];
      inv = gates[bn * KSEL + qc] / l[i];
      row = (size_t)(b * SEQ + trow);
    } else {
      inv = 1.f / l[i];
      row = (size_t)(b * SEQ + qc);
    }
    float4 r = make_float4(o[i][0] * inv, o[i][1] * inv, o[i][2] * inv, o[i][3] * inv);
    *(float4*)(outp + row * (NHEAD * DH) + n * DH + 4 * tx) = r;
  }
}

// ---------------- final: C = A1@W1 + A2@W2 (M=4096,K=512 each,N=1024) ----------------
__global__ __launch_bounds__(256) void gemm_final(const float* __restrict__ A1,
    const float* __restrict__ W1, const float* __restrict__ A2,
    const float* __restrict__ W2, float* __restrict__ C) {
  __shared__ float As[16][68];
  __shared__ float Bs[16][68];
  int m0 = blockIdx.x * 64, n0 = blockIdx.y * 64;
  int tid = threadIdx.x;
  int tx = tid & 15, ty = tid >> 4;
  int ra = tid >> 2, ca = (tid & 3) * 4;
  int kb = tid >> 4, cb = (tid & 15) * 4;
  float acc[4][4] = {};
  for (int pass = 0; pass < 2; pass++) {
    const float* A = pass ? A2 : A1;
    const float* W = pass ? W2 : W1;
    for (int k0 = 0; k0 < 512; k0 += 16) {
      float4 av = *(const float4*)(A + (size_t)(m0 + ra) * 512 + k0 + ca);
      As[ca + 0][ra] = av.x; As[ca + 1][ra] = av.y;
      As[ca + 2][ra] = av.z; As[ca + 3][ra] = av.w;
      *(float4*)&Bs[kb][cb] = *(const float4*)(W + (size_t)(k0 + kb) * HD + n0 + cb);
      __syncthreads();
#pragma unroll
      for (int kk = 0; kk < 16; kk++) {
        float4 a4 = *(const float4*)&As[kk][ty * 4];
        float4 b4 = *(const float4*)&Bs[kk][tx * 4];
        float aa[4] = {a4.x, a4.y, a4.z, a4.w};
        float bb[4] = {b4.x, b4.y, b4.z, b4.w};
#pragma unroll
        for (int i = 0; i < 4; i++)
#pragma unroll
          for (int j = 0; j < 4; j++) acc[i][j] += aa[i] * bb[j];
      }
      __syncthreads();
    }
  }
#pragma unroll
  for (int i = 0; i < 4; i++) {
    float4 r = make_float4(acc[i][0], acc[i][1], acc[i][2], acc[i][3]);
    *(float4*)(C + (size_t)(m0 + ty * 4 + i) * HD + n0 + tx * 4) = r;
  }
}

extern "C" void kernel_launch(void* const* d_in, const int* in_sizes, int n_in,
                              void* d_out, int out_size, void* d_ws, size_t ws_size,
                              hipStream_t stream) {
  const float* X          = (const float*)d_in[0];
  const float* router_w   = (const float*)d_in[1];
  const float* mosa_wqkv  = (const float*)d_in[2];
  const float* mosa_wo    = (const float*)d_in[3];
  const float* dense_wqkv = (const float*)d_in[4];
  const float* dense_wo   = (const float*)d_in[5];
  float* out = (float*)d_out;
  char* ws = (char*)d_ws;

  // workspace layout (bytes)
  float* scores = (float*)(ws + 0);                   // 131072
  int*   sel    = (int*)  (ws + 131072);              // 16384
  float* gates  = (float*)(ws + 147456);              // 16384
  float* qkvm   = (float*)(ws + 163840);              // 3145728
  float* avm    = (float*)(ws + 3309568);             // 8388608
  float* qkvd   = (float*)(ws + 11698176);            // 25165824
  float* avd    = (float*)(ws + 36864000);            // 8388608 (end: 45252608)

  hipMemsetAsync(avm, 0, (size_t)BB * SEQ * NHEAD * DH * sizeof(float), stream);

  router_kernel<<<BB * SEQ, 256, 0, stream>>>(X, router_w, scores);
  topk_kernel<<<BB * NHEAD, 1024, 0, stream>>>(scores, sel, gates);
  gemm_mosa_qkv<<<dim3(BB * NHEAD, KSEL / 64, D3 / 64), 256, 0, stream>>>(X, mosa_wqkv, sel, qkvm);
  rope_mosa<<<(BB * NHEAD * KSEL * RHALF + 255) / 256, 256, 0, stream>>>(qkvm, sel);
  flash_attn<true><<<dim3(BB * NHEAD, (KSEL / 64) / 2), 512, 0, stream>>>(
      qkvm, sel, gates, avm, KSEL / 64);
  gemm_tile<<<dim3(BB * SEQ / 64, (NHEAD * D3) / 64), 256, 0, stream>>>(
      X, HD, dense_wqkv, NHEAD * D3, qkvd, NHEAD * D3, HD);
  rope_dense<<<(BB * SEQ * NHEAD * RHALF + 255) / 256, 256, 0, stream>>>(qkvd);
  flash_attn<false><<<dim3(BB * NHEAD, (SEQ / 64) / 2), 512, 0, stream>>>(
      qkvd, (const int*)nullptr, (const float*)nullptr, avd, SEQ / 64);
  gemm_final<<<dim3(BB * SEQ / 64, HD / 64), 256, 0, stream>>>(avm, mosa_wo, avd, dense_wo, out);
}

// Round 3
// 524.607 us; speedup vs baseline: 3.1600x; 1.8906x over previous
//
#include <hip/hip_runtime.h>
#include <math.h>

constexpr int BB = 2;
constexpr int SEQ = 2048;
constexpr int HD = 1024;
constexpr int DH = 64;       // head dim
constexpr int NHEAD = 8;
constexpr int D3 = 192;      // 3*DH
constexpr int KSEL = 256;    // SEQ / SPARSITY
constexpr int RHALF = 16;    // N_ROT/2
constexpr float NEG = -1e30f;

typedef short short8 __attribute__((ext_vector_type(8)));
typedef float f32x4 __attribute__((ext_vector_type(4)));

__device__ __forceinline__ ushort bf16u(float f) {
  union { float f; unsigned u; } v; v.f = f;
  unsigned r = (v.u + 0x7FFFu + ((v.u >> 16) & 1u)) >> 16;
  return (ushort)r;
}
__device__ __forceinline__ float bf2f(ushort h) {
  union { unsigned u; float f; } v; v.u = ((unsigned)h) << 16;
  return v.f;
}

// ---------------- cast f32 -> bf16, 4 elems/thread ----------------
__global__ void cast_bf16x4(const float* __restrict__ x, ushort* __restrict__ y, int n4) {
  int i = blockIdx.x * 256 + threadIdx.x;
  if (i >= n4) return;
  float4 v = ((const float4*)x)[i];
  ushort4 r; r.x = bf16u(v.x); r.y = bf16u(v.y); r.z = bf16u(v.z); r.w = bf16u(v.w);
  ((ushort4*)y)[i] = r;
}

// ---------------- transpose + cast: W[K][N] f32 -> Wt[N][K] bf16 ----------------
__global__ __launch_bounds__(256) void transpose_cast(const float* __restrict__ W,
    ushort* __restrict__ Wt, int K, int N) {
  __shared__ float tile[32][33];
  int n0 = blockIdx.x * 32, k0 = blockIdx.y * 32;
  int tx = threadIdx.x & 31, ty = threadIdx.x >> 5;   // ty 0..7
#pragma unroll
  for (int i = 0; i < 4; i++)
    tile[ty + 8 * i][tx] = W[(size_t)(k0 + ty + 8 * i) * N + n0 + tx];
  __syncthreads();
#pragma unroll
  for (int i = 0; i < 4; i++)
    Wt[(size_t)(n0 + ty + 8 * i) * K + k0 + tx] = bf16u(tile[tx][ty + 8 * i]);
}

// ---------------- router: scores[b][n][t] = X[b,t,:] . rw[:,n] ----------------
__global__ __launch_bounds__(256) void router_kernel(const float* __restrict__ X,
    const float* __restrict__ rw, float* __restrict__ scores) {
  int bt = blockIdx.x;
  __shared__ float xs[HD];
  const float* xrow = X + (size_t)bt * HD;
  for (int i = threadIdx.x; i < HD; i += 256) xs[i] = xrow[i];
  __syncthreads();
  int n = threadIdx.x >> 5;
  int lane = threadIdx.x & 31;
  float acc = 0.f;
  for (int h = lane; h < HD; h += 32) acc += xs[h] * rw[h * NHEAD + n];
  for (int off = 16; off > 0; off >>= 1) acc += __shfl_down(acc, off, 32);
  if (lane == 0) {
    int b = bt / SEQ, t = bt % SEQ;
    scores[((size_t)b * NHEAD + n) * SEQ + t] = acc;
  }
}

// ---------------- top-k (k=256) by rank counting ----------------
__global__ __launch_bounds__(1024) void topk_kernel(const float* __restrict__ scores,
    int* __restrict__ sel, float* __restrict__ gates) {
  int bn = blockIdx.x;
  __shared__ float s[SEQ];
  __shared__ int psum[1024];
  const float* sp = scores + (size_t)bn * SEQ;
  for (int i = threadIdx.x; i < SEQ; i += 1024) s[i] = sp[i];
  __syncthreads();
  int t0 = threadIdx.x * 2;
  float v0 = s[t0], v1 = s[t0 + 1];
  int r0 = 0, r1 = 0;
  for (int j = 0; j < SEQ; j++) {
    float sj = s[j];
    r0 += (sj > v0) || (sj == v0 && j < t0);
    r1 += (sj > v1) || (sj == v1 && j < t0 + 1);
  }
  int f0 = r0 < KSEL, f1 = r1 < KSEL;
  psum[threadIdx.x] = f0 + f1;
  __syncthreads();
  for (int off = 1; off < 1024; off <<= 1) {
    int val = psum[threadIdx.x];
    int add = (threadIdx.x >= off) ? psum[threadIdx.x - off] : 0;
    __syncthreads();
    psum[threadIdx.x] = val + add;
    __syncthreads();
  }
  int base = psum[threadIdx.x] - (f0 + f1);
  if (f0) { sel[bn * KSEL + base] = t0;
            gates[bn * KSEL + base] = 1.f / (1.f + __expf(-v0)); base++; }
  if (f1) { sel[bn * KSEL + base] = t0 + 1;
            gates[bn * KSEL + base] = 1.f / (1.f + __expf(-v1)); }
}

// ---------------- mosa qkv: gathered-rows f32 GEMM per (b,n) ----------------
__global__ __launch_bounds__(256) void gemm_mosa_qkv(const float* __restrict__ X,
    const float* __restrict__ wqkv, const int* __restrict__ sel, float* __restrict__ qkvm) {
  __shared__ float As[16][68];
  __shared__ float Bs[16][68];
  int bn = blockIdx.x; int b = bn / NHEAD, n = bn % NHEAD;
  int m0 = blockIdx.y * 64, n0 = blockIdx.z * 64;
  int tid = threadIdx.x;
  int tx = tid & 15, ty = tid >> 4;
  int ra = tid >> 2, ca = (tid & 3) * 4;
  int kb = tid >> 4, cb = (tid & 15) * 4;
  int grow = sel[bn * KSEL + m0 + ra];
  const float* arow = X + (size_t)(b * SEQ + grow) * HD;
  float acc[4][4] = {};
  for (int k0 = 0; k0 < HD; k0 += 16) {
    float4 av = *(const float4*)(arow + k0 + ca);
    As[ca + 0][ra] = av.x; As[ca + 1][ra] = av.y;
    As[ca + 2][ra] = av.z; As[ca + 3][ra] = av.w;
    *(float4*)&Bs[kb][cb] =
        *(const float4*)(wqkv + (size_t)(k0 + kb) * (NHEAD * D3) + n * D3 + n0 + cb);
    __syncthreads();
#pragma unroll
    for (int kk = 0; kk < 16; kk++) {
      float4 a4 = *(const float4*)&As[kk][ty * 4];
      float4 b4 = *(const float4*)&Bs[kk][tx * 4];
      float aa[4] = {a4.x, a4.y, a4.z, a4.w};
      float bb[4] = {b4.x, b4.y, b4.z, b4.w};
#pragma unroll
      for (int i = 0; i < 4; i++)
#pragma unroll
        for (int j = 0; j < 4; j++) acc[i][j] += aa[i] * bb[j];
    }
    __syncthreads();
  }
#pragma unroll
  for (int i = 0; i < 4; i++) {
    float4 r = make_float4(acc[i][0], acc[i][1], acc[i][2], acc[i][3]);
    *(float4*)(qkvm + ((size_t)bn * KSEL + m0 + ty * 4 + i) * D3 + n0 + tx * 4) = r;
  }
}

// ---------------- mosa RoPE (f32 in place) ----------------
__global__ void rope_mosa(float* __restrict__ qkvm, const int* __restrict__ sel) {
  int tid = blockIdx.x * 256 + threadIdx.x;
  if (tid >= BB * NHEAD * KSEL * RHALF) return;
  int j = tid & (RHALF - 1);
  int row = tid >> 4;
  float pos = (float)sel[row];
  float inv = __expf((float)j * -0.5756462732485115f);
  float ang = pos * inv;
  float c = cosf(ang), sn = sinf(ang);
  float* qp = qkvm + (size_t)row * D3;
  float q1 = qp[j], q2 = qp[j + RHALF];
  qp[j] = q1 * c - q2 * sn; qp[j + RHALF] = q1 * sn + q2 * c;
  float* kp = qp + DH;
  float k1 = kp[j], k2 = kp[j + RHALF];
  kp[j] = k1 * c - k2 * sn; kp[j + RHALF] = k1 * sn + k2 * c;
}

// ---------------- dense RoPE on bf16 qkvb in place ----------------
__global__ void rope_dense_b(ushort* __restrict__ qkvb) {
  int tid = blockIdx.x * 256 + threadIdx.x;   // rows * 32
  int j = tid & 15;
  int which = (tid >> 4) & 1;                 // 0: Q, 1: K
  int row = tid >> 5;                         // (b*SEQ+t)*NHEAD + n
  int t = (row >> 3) & (SEQ - 1);
  float inv = __expf((float)j * -0.5756462732485115f);
  float ang = (float)t * inv;
  float c = cosf(ang), sn = sinf(ang);
  ushort* p = qkvb + (size_t)row * D3 + which * DH + j;
  float x1 = bf2f(p[0]), x2 = bf2f(p[RHALF]);
  p[0] = bf16u(x1 * c - x2 * sn);
  p[RHALF] = bf16u(x1 * sn + x2 * c);
}

// ---------------- mosa flash attention (f32, small) -> bf16 avm ----------------
__global__ __launch_bounds__(512) void mosa_flash(const float* __restrict__ qkv,
    const int* __restrict__ sel, const float* __restrict__ gates,
    ushort* __restrict__ outp, int nqt) {
  __shared__ float Qs[2][64][64];
  __shared__ float Ks[64][64];
  __shared__ float Vs[64][64];

  int bn = blockIdx.x;
  int pair = blockIdx.y;
  int qtA = pair, qtB = nqt - 1 - pair;
  int tid = threadIdx.x;
  int g = tid >> 8;
  int myqt = g ? qtB : qtA;
  int q0 = myqt * 64;
  int t = tid & 255;
  int ty = t >> 4, tx = t & 15;

  const float* base = qkv + (size_t)bn * KSEL * D3;
  const int rs = D3;

  {
    int r = t & 63, d0 = (t >> 6) * 16;
    const float* src = base + (size_t)(q0 + r) * rs + d0;
#pragma unroll
    for (int i = 0; i < 4; i++) {
      float4 v = *(const float4*)(src + 4 * i);
      Qs[g][d0 + 4 * i + 0][r] = v.x * 0.125f;
      Qs[g][d0 + 4 * i + 1][r] = v.y * 0.125f;
      Qs[g][d0 + 4 * i + 2][r] = v.z * 0.125f;
      Qs[g][d0 + 4 * i + 3][r] = v.w * 0.125f;
    }
  }

  float o[4][4] = {};
  float m[4], l[4];
#pragma unroll
  for (int i = 0; i < 4; i++) { m[i] = NEG; l[i] = 0.f; }

  for (int kt = 0; kt <= qtB; kt++) {
    __syncthreads();
    {
      int r = tid & 63, d0 = ((tid >> 6) & 3) * 16;
      const float* src = base + (size_t)(kt * 64 + r) * rs + (g ? 2 * DH : DH) + d0;
      if (g == 0) {
#pragma unroll
        for (int i = 0; i < 4; i++) {
          float4 v = *(const float4*)(src + 4 * i);
          Ks[d0 + 4 * i + 0][r] = v.x;
          Ks[d0 + 4 * i + 1][r] = v.y;
          Ks[d0 + 4 * i + 2][r] = v.z;
          Ks[d0 + 4 * i + 3][r] = v.w;
        }
      } else {
#pragma unroll
        for (int i = 0; i < 4; i++) {
          float4 v = *(const float4*)(src + 4 * i);
          *(float4*)&Vs[r][(d0 + 4 * i) ^ (4 * (r & 15))] = v;
        }
      }
    }
    __syncthreads();

    bool active = g || (kt <= qtA);
    if (active) {
      float s[4][4] = {};
#pragma unroll 8
      for (int d = 0; d < 64; d++) {
        float4 qv = *(const float4*)&Qs[g][d][4 * ty];
        float4 kv = *(const float4*)&Ks[d][4 * tx];
        float qa[4] = {qv.x, qv.y, qv.z, qv.w};
        float kb[4] = {kv.x, kv.y, kv.z, kv.w};
#pragma unroll
        for (int i = 0; i < 4; i++)
#pragma unroll
          for (int j = 0; j < 4; j++) s[i][j] += qa[i] * kb[j];
      }
      if (kt == myqt) {
#pragma unroll
        for (int i = 0; i < 4; i++)
#pragma unroll
          for (int j = 0; j < 4; j++)
            if (4 * tx + j > 4 * ty + i) s[i][j] = NEG;
      }
#pragma unroll
      for (int i = 0; i < 4; i++) {
        float mx = fmaxf(fmaxf(s[i][0], s[i][1]), fmaxf(s[i][2], s[i][3]));
        mx = fmaxf(mx, __shfl_xor(mx, 1));
        mx = fmaxf(mx, __shfl_xor(mx, 2));
        mx = fmaxf(mx, __shfl_xor(mx, 4));
        mx = fmaxf(mx, __shfl_xor(mx, 8));
        float mn = fmaxf(m[i], mx);
        float sc = __expf(m[i] - mn);
        m[i] = mn;
#pragma unroll
        for (int j = 0; j < 4; j++) s[i][j] = __expf(s[i][j] - mn);
        float rsum = s[i][0] + s[i][1] + s[i][2] + s[i][3];
        rsum += __shfl_xor(rsum, 1);
        rsum += __shfl_xor(rsum, 2);
        rsum += __shfl_xor(rsum, 4);
        rsum += __shfl_xor(rsum, 8);
        l[i] = l[i] * sc + rsum;
#pragma unroll
        for (int j = 0; j < 4; j++) o[i][j] *= sc;
      }
      for (int txk = 0; txk < 16; txk++) {
        int lanesrc = (ty & 3) * 16 + txk;
#pragma unroll
        for (int j = 0; j < 4; j++) {
          int k = 4 * txk + j;
          float4 vv = *(const float4*)&Vs[k][(4 * tx) ^ (4 * (k & 15))];
          float p0 = __shfl(s[0][j], lanesrc);
          float p1 = __shfl(s[1][j], lanesrc);
          float p2 = __shfl(s[2][j], lanesrc);
          float p3 = __shfl(s[3][j], lanesrc);
          o[0][0] += p0 * vv.x; o[0][1] += p0 * vv.y; o[0][2] += p0 * vv.z; o[0][3] += p0 * vv.w;
          o[1][0] += p1 * vv.x; o[1][1] += p1 * vv.y; o[1][2] += p1 * vv.z; o[1][3] += p1 * vv.w;
          o[2][0] += p2 * vv.x; o[2][1] += p2 * vv.y; o[2][2] += p2 * vv.z; o[2][3] += p2 * vv.w;
          o[3][0] += p3 * vv.x; o[3][1] += p3 * vv.y; o[3][2] += p3 * vv.z; o[3][3] += p3 * vv.w;
        }
      }
    }
  }

  int b = bn >> 3, n = bn & 7;
#pragma unroll
  for (int i = 0; i < 4; i++) {
    int qc = q0 + 4 * ty + i;
    int trow = sel[bn * KSEL + qc];
    float inv = gates[bn * KSEL + qc] / l[i];
    size_t row = (size_t)(b * SEQ + trow);
    ushort4 r4;
    r4.x = bf16u(o[i][0] * inv); r4.y = bf16u(o[i][1] * inv);
    r4.z = bf16u(o[i][2] * inv); r4.w = bf16u(o[i][3] * inv);
    *(ushort4*)(outp + row * (NHEAD * DH) + n * DH + 4 * tx) = r4;
  }
}

// ---------------- dense flash attention, MFMA bf16 ----------------
// 512 thr = 2 groups x 4 waves; group handles one 64-q tile (paired for balance).
// K rows and V^T staged in LDS bf16 by all threads; P round-trips via LDS.
__global__ __launch_bounds__(512) void flash_mfma(const ushort* __restrict__ qkvb,
    ushort* __restrict__ avd, int nqt) {
  __shared__ __align__(16) ushort Qs[2][64][72];
  __shared__ __align__(16) ushort Ks[64][72];
  __shared__ __align__(16) ushort Vt[64][72];
  __shared__ __align__(16) ushort Ps[2][64][72];

  int bn = blockIdx.x; int b = bn >> 3, n = bn & 7;
  int pair = blockIdx.y;
  int qtA = pair, qtB = nqt - 1 - pair;
  int tid = threadIdx.x;
  int g = tid >> 8;
  int myqt = g ? qtB : qtA;
  int t = tid & 255;
  int lane = tid & 63;
  int w = (tid >> 6) & 3;          // wave within group
  int cc = lane & 15, quad = lane >> 4;

  const int rs = NHEAD * D3;       // 1536 bf16 per token row
  const ushort* base = qkvb + ((size_t)(b * SEQ)) * rs + n * D3;

  // stage group's Q tile (Q pre-scaled by 1/8 in GEMM epilogue)
  {
    int r = t >> 2, cb = t & 3;
    const ushort* src = base + (size_t)(myqt * 64 + r) * rs;
    *(short8*)&Qs[g][r][8 * cb] = *(const short8*)(src + 8 * cb);
    *(short8*)&Qs[g][r][8 * (cb + 4)] = *(const short8*)(src + 8 * (cb + 4));
  }

  f32x4 oacc[4];
  float m_[4], l_[4];
#pragma unroll
  for (int i = 0; i < 4; i++) {
    m_[i] = NEG; l_[i] = 0.f;
#pragma unroll
    for (int r = 0; r < 4; r++) oacc[i][r] = 0.f;
  }

  for (int kt = 0; kt <= qtB; kt++) {
    __syncthreads();
    {
      // K: 64 rows x 8 chunks, 512 threads -> 1 chunk each (coalesced)
      int r = tid >> 3, c = tid & 7;
      const ushort* srck = base + (size_t)(kt * 64 + r) * rs + DH;
      *(short8*)&Ks[r][8 * c] = *(const short8*)(srck + 8 * c);
      // V^T: key = tid&63, d-chunk = tid>>6 (per-wave uniform -> conflict-free writes)
      int key = tid & 63, dc = tid >> 6;
      const ushort* srcv = base + (size_t)(kt * 64 + key) * rs + 2 * DH + 8 * dc;
      short8 vv = *(const short8*)srcv;
#pragma unroll
      for (int i2 = 0; i2 < 8; i2++) Vt[8 * dc + i2][key] = ((const ushort*)&vv)[i2];
    }
    __syncthreads();

    bool active = g || (kt <= qtA);
    if (active) {
      // S = Q.K^T
      f32x4 sacc[4];
#pragma unroll
      for (int j = 0; j < 4; j++)
#pragma unroll
        for (int r = 0; r < 4; r++) sacc[j][r] = 0.f;
#pragma unroll
      for (int ks = 0; ks < 2; ks++) {
        short8 aq = *(const short8*)&Qs[g][16 * w + cc][8 * quad + 32 * ks];
#pragma unroll
        for (int j = 0; j < 4; j++) {
          short8 bk = *(const short8*)&Ks[16 * j + cc][8 * quad + 32 * ks];
          sacc[j] = __builtin_amdgcn_mfma_f32_16x16x32_bf16(aq, bk, sacc[j], 0, 0, 0);
        }
      }
      // causal mask on diagonal tile
      if (kt == myqt) {
#pragma unroll
        for (int j = 0; j < 4; j++)
#pragma unroll
          for (int i = 0; i < 4; i++)
            if (16 * j + cc > 16 * w + 4 * quad + i) sacc[j][i] = NEG;
      }
      // online softmax per row (row = 16w + 4*quad + i, cols spread over 16 lanes)
      float p[4][4];
#pragma unroll
      for (int i = 0; i < 4; i++) {
        float mx = fmaxf(fmaxf(sacc[0][i], sacc[1][i]), fmaxf(sacc[2][i], sacc[3][i]));
        mx = fmaxf(mx, __shfl_xor(mx, 1));
        mx = fmaxf(mx, __shfl_xor(mx, 2));
        mx = fmaxf(mx, __shfl_xor(mx, 4));
        mx = fmaxf(mx, __shfl_xor(mx, 8));
        float mn = fmaxf(m_[i], mx);
        float sc = __expf(m_[i] - mn);
        m_[i] = mn;
        float rsum = 0.f;
#pragma unroll
        for (int j = 0; j < 4; j++) { p[j][i] = __expf(sacc[j][i] - mn); rsum += p[j][i]; }
        rsum += __shfl_xor(rsum, 1);
        rsum += __shfl_xor(rsum, 2);
        rsum += __shfl_xor(rsum, 4);
        rsum += __shfl_xor(rsum, 8);
        l_[i] = l_[i] * sc + rsum;
#pragma unroll
        for (int jd = 0; jd < 4; jd++) oacc[jd][i] *= sc;
      }
      // P -> LDS (C-layout scatter, bf16), then wave-local drain
#pragma unroll
      for (int j = 0; j < 4; j++)
#pragma unroll
        for (int i = 0; i < 4; i++)
          Ps[g][16 * w + 4 * quad + i][16 * j + cc] = bf16u(p[j][i]);
      __asm__ volatile("s_waitcnt lgkmcnt(0)" ::: "memory");
      // O += P.V via MFMA (a-frag from Ps, b-frag from V^T)
#pragma unroll
      for (int ks = 0; ks < 2; ks++) {
        short8 ap = *(const short8*)&Ps[g][16 * w + cc][8 * quad + 32 * ks];
#pragma unroll
        for (int jd = 0; jd < 4; jd++) {
          short8 bv = *(const short8*)&Vt[16 * jd + cc][8 * quad + 32 * ks];
          oacc[jd] = __builtin_amdgcn_mfma_f32_16x16x32_bf16(ap, bv, oacc[jd], 0, 0, 0);
        }
      }
    }
  }

  // epilogue: bf16 stores
#pragma unroll
  for (int i = 0; i < 4; i++) {
    float inv = 1.f / l_[i];
    int q = myqt * 64 + 16 * w + 4 * quad + i;
    ushort* orow = avd + ((size_t)(b * SEQ + q)) * (NHEAD * DH) + n * DH;
#pragma unroll
    for (int jd = 0; jd < 4; jd++)
      orow[16 * jd + cc] = bf16u(oacc[jd][i] * inv);
  }
}

// ---------------- bf16 MFMA GEMM, 128x128 tile, BK=32 ----------------
// A row-major [M][K] bf16, Bt row-major [N][K] bf16 (i.e. B^T), out [M][N].
// MODE 0: out f32 = A1@B1 + A2@B2.  MODE 1: out bf16 with Q-scale (col%192<64 -> *0.125).
template <int MODE>
__global__ __launch_bounds__(256) void gemm_bf16(
    const ushort* __restrict__ A1, const ushort* __restrict__ B1t, int K1,
    const ushort* __restrict__ A2, const ushort* __restrict__ B2t, int K2,
    void* __restrict__ outv, int N) {
  __shared__ __align__(16) ushort As[128][32];
  __shared__ __align__(16) ushort Bs[128][32];
  int m0 = blockIdx.x * 128, n0 = blockIdx.y * 128;
  int tid = threadIdx.x;
  int lane = tid & 63, wave = tid >> 6;
  int wm = wave & 1, wn = wave >> 1;
  int cc = lane & 15, quad = lane >> 4;
  int sr = tid >> 2, sc = tid & 3;

  f32x4 acc[4][4];
#pragma unroll
  for (int i = 0; i < 4; i++)
#pragma unroll
    for (int j = 0; j < 4; j++)
#pragma unroll
      for (int r = 0; r < 4; r++) acc[i][j][r] = 0.f;

  const int npass = (MODE == 0) ? 2 : 1;
  for (int pass = 0; pass < npass; pass++) {
    const ushort* A = pass ? A2 : A1;
    const ushort* Bt = pass ? B2t : B1t;
    int K = pass ? K2 : K1;
    for (int k0 = 0; k0 < K; k0 += 32) {
      __syncthreads();
      {
        short8 a0 = *(const short8*)(A + (size_t)(m0 + sr) * K + k0 + 8 * sc);
        short8 a1 = *(const short8*)(A + (size_t)(m0 + sr + 64) * K + k0 + 8 * sc);
        short8 b0 = *(const short8*)(Bt + (size_t)(n0 + sr) * K + k0 + 8 * sc);
        short8 b1 = *(const short8*)(Bt + (size_t)(n0 + sr + 64) * K + k0 + 8 * sc);
        *(short8*)&As[sr][8 * ((sc + (sr >> 1)) & 3)] = a0;
        *(short8*)&As[sr + 64][8 * ((sc + ((sr + 64) >> 1)) & 3)] = a1;
        *(short8*)&Bs[sr][8 * ((sc + (sr >> 1)) & 3)] = b0;
        *(short8*)&Bs[sr + 64][8 * ((sc + ((sr + 64) >> 1)) & 3)] = b1;
      }
      __syncthreads();
      short8 af[4], bfr[4];
#pragma unroll
      for (int i = 0; i < 4; i++) {
        int ra = 64 * wm + 16 * i + cc;
        af[i] = *(const short8*)&As[ra][8 * ((quad + (ra >> 1)) & 3)];
      }
#pragma unroll
      for (int j = 0; j < 4; j++) {
        int rb = 64 * wn + 16 * j + cc;
        bfr[j] = *(const short8*)&Bs[rb][8 * ((quad + (rb >> 1)) & 3)];
      }
#pragma unroll
      for (int i = 0; i < 4; i++)
#pragma unroll
        for (int j = 0; j < 4; j++)
          acc[i][j] = __builtin_amdgcn_mfma_f32_16x16x32_bf16(af[i], bfr[j], acc[i][j], 0, 0, 0);
    }
  }

#pragma unroll
  for (int i = 0; i < 4; i++) {
#pragma unroll
    for (int j = 0; j < 4; j++) {
      int colg = n0 + 64 * wn + 16 * j + cc;
#pragma unroll
      for (int r = 0; r < 4; r++) {
        int row = m0 + 64 * wm + 16 * i + 4 * quad + r;
        if (MODE == 0) {
          ((float*)outv)[(size_t)row * N + colg] = acc[i][j][r];
        } else {
          float v = acc[i][j][r];
          if ((colg % 192) < 64) v *= 0.125f;
          ((ushort*)outv)[(size_t)row * N + colg] = bf16u(v);
        }
      }
    }
  }
}

extern "C" void kernel_launch(void* const* d_in, const int* in_sizes, int n_in,
                              void* d_out, int out_size, void* d_ws, size_t ws_size,
                              hipStream_t stream) {
  const float* X          = (const float*)d_in[0];
  const float* router_w   = (const float*)d_in[1];
  const float* mosa_wqkv  = (const float*)d_in[2];
  const float* mosa_wo    = (const float*)d_in[3];
  const float* dense_wqkv = (const float*)d_in[4];
  const float* dense_wo   = (const float*)d_in[5];
  float* out = (float*)d_out;
  char* ws = (char*)d_ws;

  // workspace layout (bytes)
  float*  scores  = (float*) (ws + 0);          // 131072
  int*    sel     = (int*)   (ws + 131072);     // 16384
  float*  gates   = (float*) (ws + 147456);     // 16384
  float*  qkvm    = (float*) (ws + 163840);     // 3145728  (f32 mosa qkv)
  ushort* avm     = (ushort*)(ws + 3309568);    // 4194304  (bf16)
  ushort* avd     = (ushort*)(ws + 7503872);    // 4194304  (bf16)
  ushort* Xb      = (ushort*)(ws + 11698176);   // 8388608  (bf16 X)
  ushort* qkvb    = (ushort*)(ws + 20086784);   // 12582912 (bf16 dense qkv)
  ushort* Wqkv_t  = (ushort*)(ws + 32669696);   // 3145728
  ushort* Wdo_t   = (ushort*)(ws + 35815424);   // 1048576
  ushort* Wmo_t   = (ushort*)(ws + 36864000);   // 1048576  (end 37912576)

  hipMemsetAsync(avm, 0, (size_t)BB * SEQ * NHEAD * DH * sizeof(ushort), stream);

  // casts / transposes
  cast_bf16x4<<<4096, 256, 0, stream>>>(X, Xb, BB * SEQ * HD / 4);
  transpose_cast<<<dim3(1536 / 32, 1024 / 32), 256, 0, stream>>>(dense_wqkv, Wqkv_t, 1024, 1536);
  transpose_cast<<<dim3(1024 / 32, 512 / 32), 256, 0, stream>>>(dense_wo, Wdo_t, 512, 1024);
  transpose_cast<<<dim3(1024 / 32, 512 / 32), 256, 0, stream>>>(mosa_wo, Wmo_t, 512, 1024);

  // mosa branch (f32 compute, bf16 AV out)
  router_kernel<<<BB * SEQ, 256, 0, stream>>>(X, router_w, scores);
  topk_kernel<<<BB * NHEAD, 1024, 0, stream>>>(scores, sel, gates);
  gemm_mosa_qkv<<<dim3(BB * NHEAD, KSEL / 64, D3 / 64), 256, 0, stream>>>(X, mosa_wqkv, sel, qkvm);
  rope_mosa<<<(BB * NHEAD * KSEL * RHALF + 255) / 256, 256, 0, stream>>>(qkvm, sel);
  mosa_flash<<<dim3(BB * NHEAD, (KSEL / 64) / 2), 512, 0, stream>>>(qkvm, sel, gates, avm, KSEL / 64);

  // dense branch (bf16 MFMA)
  gemm_bf16<1><<<dim3(32, 12), 256, 0, stream>>>(Xb, Wqkv_t, 1024,
                                                 (const ushort*)nullptr, (const ushort*)nullptr, 0,
                                                 qkvb, NHEAD * D3);
  rope_dense_b<<<4096, 256, 0, stream>>>(qkvb);
  flash_mfma<<<dim3(BB * NHEAD, (SEQ / 64) / 2), 512, 0, stream>>>(qkvb, avd, SEQ / 64);

  // final: out = avm@mosa_wo + avd@dense_wo  (f32 out)
  gemm_bf16<0><<<dim3(32, 8), 256, 0, stream>>>(avm, Wmo_t, 512, avd, Wdo_t, 512, out, HD);
}

// Round 4
// 417.937 us; speedup vs baseline: 3.9665x; 1.2552x over previous
//
#include <hip/hip_runtime.h>
#include <math.h>

constexpr int BB = 2;
constexpr int SEQ = 2048;
constexpr int HD = 1024;
constexpr int DH = 64;       // head dim
constexpr int NHEAD = 8;
constexpr int D3 = 192;      // 3*DH
constexpr int KSEL = 256;    // SEQ / SPARSITY
constexpr int RHALF = 16;    // N_ROT/2
constexpr float NEG = -1e30f;

typedef short short8 __attribute__((ext_vector_type(8)));
typedef float f32x4 __attribute__((ext_vector_type(4)));

__device__ __forceinline__ ushort bf16u(float f) {
  union { float f; unsigned u; } v; v.f = f;
  unsigned r = (v.u + 0x7FFFu + ((v.u >> 16) & 1u)) >> 16;
  return (ushort)r;
}
__device__ __forceinline__ float bf2f(ushort h) {
  union { unsigned u; float f; } v; v.u = ((unsigned)h) << 16;
  return v.f;
}

// ---------------- cast f32 -> bf16, 4 elems/thread ----------------
__global__ void cast_bf16x4(const float* __restrict__ x, ushort* __restrict__ y, int n4) {
  int i = blockIdx.x * 256 + threadIdx.x;
  if (i >= n4) return;
  float4 v = ((const float4*)x)[i];
  ushort4 r; r.x = bf16u(v.x); r.y = bf16u(v.y); r.z = bf16u(v.z); r.w = bf16u(v.w);
  ((ushort4*)y)[i] = r;
}

// ---------------- transpose + cast: W[K][N] f32 -> Wt[N][K] bf16 ----------------
__global__ __launch_bounds__(256) void transpose_cast(const float* __restrict__ W,
    ushort* __restrict__ Wt, int K, int N) {
  __shared__ float tile[32][33];
  int n0 = blockIdx.x * 32, k0 = blockIdx.y * 32;
  int tx = threadIdx.x & 31, ty = threadIdx.x >> 5;   // ty 0..7
#pragma unroll
  for (int i = 0; i < 4; i++)
    tile[ty + 8 * i][tx] = W[(size_t)(k0 + ty + 8 * i) * N + n0 + tx];
  __syncthreads();
#pragma unroll
  for (int i = 0; i < 4; i++)
    Wt[(size_t)(n0 + ty + 8 * i) * K + k0 + tx] = bf16u(tile[tx][ty + 8 * i]);
}

// ---------------- router: scores[b][n][t] = X[b,t,:] . rw[:,n] ----------------
__global__ __launch_bounds__(256) void router_kernel(const float* __restrict__ X,
    const float* __restrict__ rw, float* __restrict__ scores) {
  int bt = blockIdx.x;
  __shared__ float xs[HD];
  const float* xrow = X + (size_t)bt * HD;
  for (int i = threadIdx.x; i < HD; i += 256) xs[i] = xrow[i];
  __syncthreads();
  int n = threadIdx.x >> 5;
  int lane = threadIdx.x & 31;
  float acc = 0.f;
  for (int h = lane; h < HD; h += 32) acc += xs[h] * rw[h * NHEAD + n];
  for (int off = 16; off > 0; off >>= 1) acc += __shfl_down(acc, off, 32);
  if (lane == 0) {
    int b = bt / SEQ, t = bt % SEQ;
    scores[((size_t)b * NHEAD + n) * SEQ + t] = acc;
  }
}

// ---------------- top-k stage 1: partial rank counts over j-chunks ----------------
// grid (16 rows, 16 chunks of 128 j); each thread owns 8 values of the row.
__global__ __launch_bounds__(256) void topk_partial(const float* __restrict__ scores,
    int* __restrict__ pranks) {
  int row = blockIdx.x;
  int c = blockIdx.y;
  __shared__ float chunk[128];
  const float* sp = scores + (size_t)row * SEQ;
  if (threadIdx.x < 128) chunk[threadIdx.x] = sp[c * 128 + threadIdx.x];
  __syncthreads();
  int t = threadIdx.x;
  float v[8]; int vi[8]; int p[8];
#pragma unroll
  for (int i = 0; i < 8; i++) { vi[i] = i * 256 + t; v[i] = sp[vi[i]]; p[i] = 0; }
  int jbase = c * 128;
#pragma unroll 4
  for (int j4 = 0; j4 < 128; j4 += 4) {
    float4 s4 = *(const float4*)&chunk[j4];
    float ss[4] = {s4.x, s4.y, s4.z, s4.w};
#pragma unroll
    for (int jj = 0; jj < 4; jj++) {
      float sj = ss[jj];
      int jg = jbase + j4 + jj;
#pragma unroll
      for (int i = 0; i < 8; i++)
        p[i] += (sj > v[i]) || (sj == v[i] && jg < vi[i]);
    }
  }
#pragma unroll
  for (int i = 0; i < 8; i++)
    pranks[((size_t)row * 16 + c) * SEQ + vi[i]] = p[i];
}

// ---------------- top-k stage 2: sum partials, select, scan, emit ----------------
__global__ __launch_bounds__(1024) void topk_select(const float* __restrict__ scores,
    const int* __restrict__ pranks, int* __restrict__ sel, float* __restrict__ gates) {
  int bn = blockIdx.x;
  __shared__ int psum[1024];
  int t0 = threadIdx.x * 2;
  int r0 = 0, r1 = 0;
#pragma unroll
  for (int c = 0; c < 16; c++) {
    const int* pr = pranks + ((size_t)bn * 16 + c) * SEQ;
    r0 += pr[t0];
    r1 += pr[t0 + 1];
  }
  float v0 = scores[(size_t)bn * SEQ + t0];
  float v1 = scores[(size_t)bn * SEQ + t0 + 1];
  int f0 = r0 < KSEL, f1 = r1 < KSEL;
  psum[threadIdx.x] = f0 + f1;
  __syncthreads();
  for (int off = 1; off < 1024; off <<= 1) {
    int val = psum[threadIdx.x];
    int add = (threadIdx.x >= off) ? psum[threadIdx.x - off] : 0;
    __syncthreads();
    psum[threadIdx.x] = val + add;
    __syncthreads();
  }
  int base = psum[threadIdx.x] - (f0 + f1);
  if (f0) { sel[bn * KSEL + base] = t0;
            gates[bn * KSEL + base] = 1.f / (1.f + __expf(-v0)); base++; }
  if (f1) { sel[bn * KSEL + base] = t0 + 1;
            gates[bn * KSEL + base] = 1.f / (1.f + __expf(-v1)); }
}

// ---------------- mosa qkv: gathered-rows f32 GEMM per (b,n) ----------------
__global__ __launch_bounds__(256) void gemm_mosa_qkv(const float* __restrict__ X,
    const float* __restrict__ wqkv, const int* __restrict__ sel, float* __restrict__ qkvm) {
  __shared__ float As[16][68];
  __shared__ float Bs[16][68];
  int bn = blockIdx.x; int b = bn / NHEAD, n = bn % NHEAD;
  int m0 = blockIdx.y * 64, n0 = blockIdx.z * 64;
  int tid = threadIdx.x;
  int tx = tid & 15, ty = tid >> 4;
  int ra = tid >> 2, ca = (tid & 3) * 4;
  int kb = tid >> 4, cb = (tid & 15) * 4;
  int grow = sel[bn * KSEL + m0 + ra];
  const float* arow = X + (size_t)(b * SEQ + grow) * HD;
  float acc[4][4] = {};
  for (int k0 = 0; k0 < HD; k0 += 16) {
    float4 av = *(const float4*)(arow + k0 + ca);
    As[ca + 0][ra] = av.x; As[ca + 1][ra] = av.y;
    As[ca + 2][ra] = av.z; As[ca + 3][ra] = av.w;
    *(float4*)&Bs[kb][cb] =
        *(const float4*)(wqkv + (size_t)(k0 + kb) * (NHEAD * D3) + n * D3 + n0 + cb);
    __syncthreads();
#pragma unroll
    for (int kk = 0; kk < 16; kk++) {
      float4 a4 = *(const float4*)&As[kk][ty * 4];
      float4 b4 = *(const float4*)&Bs[kk][tx * 4];
      float aa[4] = {a4.x, a4.y, a4.z, a4.w};
      float bb[4] = {b4.x, b4.y, b4.z, b4.w};
#pragma unroll
      for (int i = 0; i < 4; i++)
#pragma unroll
        for (int j = 0; j < 4; j++) acc[i][j] += aa[i] * bb[j];
    }
    __syncthreads();
  }
#pragma unroll
  for (int i = 0; i < 4; i++) {
    float4 r = make_float4(acc[i][0], acc[i][1], acc[i][2], acc[i][3]);
    *(float4*)(qkvm + ((size_t)bn * KSEL + m0 + ty * 4 + i) * D3 + n0 + tx * 4) = r;
  }
}

// ---------------- mosa RoPE (f32 in place) ----------------
__global__ void rope_mosa(float* __restrict__ qkvm, const int* __restrict__ sel) {
  int tid = blockIdx.x * 256 + threadIdx.x;
  if (tid >= BB * NHEAD * KSEL * RHALF) return;
  int j = tid & (RHALF - 1);
  int row = tid >> 4;
  float pos = (float)sel[row];
  float inv = __expf((float)j * -0.5756462732485115f);
  float ang = pos * inv;
  float c = cosf(ang), sn = sinf(ang);
  float* qp = qkvm + (size_t)row * D3;
  float q1 = qp[j], q2 = qp[j + RHALF];
  qp[j] = q1 * c - q2 * sn; qp[j + RHALF] = q1 * sn + q2 * c;
  float* kp = qp + DH;
  float k1 = kp[j], k2 = kp[j + RHALF];
  kp[j] = k1 * c - k2 * sn; kp[j + RHALF] = k1 * sn + k2 * c;
}

// ---------------- dense RoPE on bf16 qkvb in place ----------------
__global__ void rope_dense_b(ushort* __restrict__ qkvb) {
  int tid = blockIdx.x * 256 + threadIdx.x;   // rows * 32
  int j = tid & 15;
  int which = (tid >> 4) & 1;                 // 0: Q, 1: K
  int row = tid >> 5;                         // (b*SEQ+t)*NHEAD + n
  int t = (row >> 3) & (SEQ - 1);
  float inv = __expf((float)j * -0.5756462732485115f);
  float ang = (float)t * inv;
  float c = cosf(ang), sn = sinf(ang);
  ushort* p = qkvb + (size_t)row * D3 + which * DH + j;
  float x1 = bf2f(p[0]), x2 = bf2f(p[RHALF]);
  p[0] = bf16u(x1 * c - x2 * sn);
  p[RHALF] = bf16u(x1 * sn + x2 * c);
}

// ---------------- mosa flash attention (f32, small) -> bf16 avm ----------------
__global__ __launch_bounds__(512) void mosa_flash(const float* __restrict__ qkv,
    const int* __restrict__ sel, const float* __restrict__ gates,
    ushort* __restrict__ outp, int nqt) {
  __shared__ float Qs[2][64][64];
  __shared__ float Ks[64][64];
  __shared__ float Vs[64][64];

  int bn = blockIdx.x;
  int pair = blockIdx.y;
  int qtA = pair, qtB = nqt - 1 - pair;
  int tid = threadIdx.x;
  int g = tid >> 8;
  int myqt = g ? qtB : qtA;
  int q0 = myqt * 64;
  int t = tid & 255;
  int ty = t >> 4, tx = t & 15;

  const float* base = qkv + (size_t)bn * KSEL * D3;
  const int rs = D3;

  {
    int r = t & 63, d0 = (t >> 6) * 16;
    const float* src = base + (size_t)(q0 + r) * rs + d0;
#pragma unroll
    for (int i = 0; i < 4; i++) {
      float4 v = *(const float4*)(src + 4 * i);
      Qs[g][d0 + 4 * i + 0][r] = v.x * 0.125f;
      Qs[g][d0 + 4 * i + 1][r] = v.y * 0.125f;
      Qs[g][d0 + 4 * i + 2][r] = v.z * 0.125f;
      Qs[g][d0 + 4 * i + 3][r] = v.w * 0.125f;
    }
  }

  float o[4][4] = {};
  float m[4], l[4];
#pragma unroll
  for (int i = 0; i < 4; i++) { m[i] = NEG; l[i] = 0.f; }

  for (int kt = 0; kt <= qtB; kt++) {
    __syncthreads();
    {
      int r = tid & 63, d0 = ((tid >> 6) & 3) * 16;
      const float* src = base + (size_t)(kt * 64 + r) * rs + (g ? 2 * DH : DH) + d0;
      if (g == 0) {
#pragma unroll
        for (int i = 0; i < 4; i++) {
          float4 v = *(const float4*)(src + 4 * i);
          Ks[d0 + 4 * i + 0][r] = v.x;
          Ks[d0 + 4 * i + 1][r] = v.y;
          Ks[d0 + 4 * i + 2][r] = v.z;
          Ks[d0 + 4 * i + 3][r] = v.w;
        }
      } else {
#pragma unroll
        for (int i = 0; i < 4; i++) {
          float4 v = *(const float4*)(src + 4 * i);
          *(float4*)&Vs[r][(d0 + 4 * i) ^ (4 * (r & 15))] = v;
        }
      }
    }
    __syncthreads();

    bool active = g || (kt <= qtA);
    if (active) {
      float s[4][4] = {};
#pragma unroll 8
      for (int d = 0; d < 64; d++) {
        float4 qv = *(const float4*)&Qs[g][d][4 * ty];
        float4 kv = *(const float4*)&Ks[d][4 * tx];
        float qa[4] = {qv.x, qv.y, qv.z, qv.w};
        float kb[4] = {kv.x, kv.y, kv.z, kv.w};
#pragma unroll
        for (int i = 0; i < 4; i++)
#pragma unroll
          for (int j = 0; j < 4; j++) s[i][j] += qa[i] * kb[j];
      }
      if (kt == myqt) {
#pragma unroll
        for (int i = 0; i < 4; i++)
#pragma unroll
          for (int j = 0; j < 4; j++)
            if (4 * tx + j > 4 * ty + i) s[i][j] = NEG;
      }
#pragma unroll
      for (int i = 0; i < 4; i++) {
        float mx = fmaxf(fmaxf(s[i][0], s[i][1]), fmaxf(s[i][2], s[i][3]));
        mx = fmaxf(mx, __shfl_xor(mx, 1));
        mx = fmaxf(mx, __shfl_xor(mx, 2));
        mx = fmaxf(mx, __shfl_xor(mx, 4));
        mx = fmaxf(mx, __shfl_xor(mx, 8));
        float mn = fmaxf(m[i], mx);
        float sc = __expf(m[i] - mn);
        m[i] = mn;
#pragma unroll
        for (int j = 0; j < 4; j++) s[i][j] = __expf(s[i][j] - mn);
        float rsum = s[i][0] + s[i][1] + s[i][2] + s[i][3];
        rsum += __shfl_xor(rsum, 1);
        rsum += __shfl_xor(rsum, 2);
        rsum += __shfl_xor(rsum, 4);
        rsum += __shfl_xor(rsum, 8);
        l[i] = l[i] * sc + rsum;
#pragma unroll
        for (int j = 0; j < 4; j++) o[i][j] *= sc;
      }
      for (int txk = 0; txk < 16; txk++) {
        int lanesrc = (ty & 3) * 16 + txk;
#pragma unroll
        for (int j = 0; j < 4; j++) {
          int k = 4 * txk + j;
          float4 vv = *(const float4*)&Vs[k][(4 * tx) ^ (4 * (k & 15))];
          float p0 = __shfl(s[0][j], lanesrc);
          float p1 = __shfl(s[1][j], lanesrc);
          float p2 = __shfl(s[2][j], lanesrc);
          float p3 = __shfl(s[3][j], lanesrc);
          o[0][0] += p0 * vv.x; o[0][1] += p0 * vv.y; o[0][2] += p0 * vv.z; o[0][3] += p0 * vv.w;
          o[1][0] += p1 * vv.x; o[1][1] += p1 * vv.y; o[1][2] += p1 * vv.z; o[1][3] += p1 * vv.w;
          o[2][0] += p2 * vv.x; o[2][1] += p2 * vv.y; o[2][2] += p2 * vv.z; o[2][3] += p2 * vv.w;
          o[3][0] += p3 * vv.x; o[3][1] += p3 * vv.y; o[3][2] += p3 * vv.z; o[3][3] += p3 * vv.w;
        }
      }
    }
  }

  int b = bn >> 3, n = bn & 7;
#pragma unroll
  for (int i = 0; i < 4; i++) {
    int qc = q0 + 4 * ty + i;
    int trow = sel[bn * KSEL + qc];
    float inv = gates[bn * KSEL + qc] / l[i];
    size_t row = (size_t)(b * SEQ + trow);
    ushort4 r4;
    r4.x = bf16u(o[i][0] * inv); r4.y = bf16u(o[i][1] * inv);
    r4.z = bf16u(o[i][2] * inv); r4.w = bf16u(o[i][3] * inv);
    *(ushort4*)(outp + row * (NHEAD * DH) + n * DH + 4 * tx) = r4;
  }
}

// ---------------- dense flash attention, MFMA bf16 ----------------
__global__ __launch_bounds__(512) void flash_mfma(const ushort* __restrict__ qkvb,
    ushort* __restrict__ avd, int nqt) {
  __shared__ __align__(16) ushort Qs[2][64][72];
  __shared__ __align__(16) ushort Ks[64][72];
  __shared__ __align__(16) ushort Vt[64][72];
  __shared__ __align__(16) ushort Ps[2][64][72];

  int bn = blockIdx.x; int b = bn >> 3, n = bn & 7;
  int pair = blockIdx.y;
  int qtA = pair, qtB = nqt - 1 - pair;
  int tid = threadIdx.x;
  int g = tid >> 8;
  int myqt = g ? qtB : qtA;
  int t = tid & 255;
  int lane = tid & 63;
  int w = (tid >> 6) & 3;          // wave within group
  int cc = lane & 15, quad = lane >> 4;

  const int rs = NHEAD * D3;       // 1536 bf16 per token row
  const ushort* base = qkvb + ((size_t)(b * SEQ)) * rs + n * D3;

  {
    int r = t >> 2, cb = t & 3;
    const ushort* src = base + (size_t)(myqt * 64 + r) * rs;
    *(short8*)&Qs[g][r][8 * cb] = *(const short8*)(src + 8 * cb);
    *(short8*)&Qs[g][r][8 * (cb + 4)] = *(const short8*)(src + 8 * (cb + 4));
  }

  f32x4 oacc[4];
  float m_[4], l_[4];
#pragma unroll
  for (int i = 0; i < 4; i++) {
    m_[i] = NEG; l_[i] = 0.f;
#pragma unroll
    for (int r = 0; r < 4; r++) oacc[i][r] = 0.f;
  }

  for (int kt = 0; kt <= qtB; kt++) {
    __syncthreads();
    {
      int r = tid >> 3, c = tid & 7;
      const ushort* srck = base + (size_t)(kt * 64 + r) * rs + DH;
      *(short8*)&Ks[r][8 * c] = *(const short8*)(srck + 8 * c);
      int key = tid & 63, dc = tid >> 6;
      const ushort* srcv = base + (size_t)(kt * 64 + key) * rs + 2 * DH + 8 * dc;
      short8 vv = *(const short8*)srcv;
#pragma unroll
      for (int i2 = 0; i2 < 8; i2++) Vt[8 * dc + i2][key] = ((const ushort*)&vv)[i2];
    }
    __syncthreads();

    bool active = g || (kt <= qtA);
    if (active) {
      f32x4 sacc[4];
#pragma unroll
      for (int j = 0; j < 4; j++)
#pragma unroll
        for (int r = 0; r < 4; r++) sacc[j][r] = 0.f;
#pragma unroll
      for (int ks = 0; ks < 2; ks++) {
        short8 aq = *(const short8*)&Qs[g][16 * w + cc][8 * quad + 32 * ks];
#pragma unroll
        for (int j = 0; j < 4; j++) {
          short8 bk = *(const short8*)&Ks[16 * j + cc][8 * quad + 32 * ks];
          sacc[j] = __builtin_amdgcn_mfma_f32_16x16x32_bf16(aq, bk, sacc[j], 0, 0, 0);
        }
      }
      if (kt == myqt) {
#pragma unroll
        for (int j = 0; j < 4; j++)
#pragma unroll
          for (int i = 0; i < 4; i++)
            if (16 * j + cc > 16 * w + 4 * quad + i) sacc[j][i] = NEG;
      }
      float p[4][4];
#pragma unroll
      for (int i = 0; i < 4; i++) {
        float mx = fmaxf(fmaxf(sacc[0][i], sacc[1][i]), fmaxf(sacc[2][i], sacc[3][i]));
        mx = fmaxf(mx, __shfl_xor(mx, 1));
        mx = fmaxf(mx, __shfl_xor(mx, 2));
        mx = fmaxf(mx, __shfl_xor(mx, 4));
        mx = fmaxf(mx, __shfl_xor(mx, 8));
        float mn = fmaxf(m_[i], mx);
        float sc = __expf(m_[i] - mn);
        m_[i] = mn;
        float rsum = 0.f;
#pragma unroll
        for (int j = 0; j < 4; j++) { p[j][i] = __expf(sacc[j][i] - mn); rsum += p[j][i]; }
        rsum += __shfl_xor(rsum, 1);
        rsum += __shfl_xor(rsum, 2);
        rsum += __shfl_xor(rsum, 4);
        rsum += __shfl_xor(rsum, 8);
        l_[i] = l_[i] * sc + rsum;
#pragma unroll
        for (int jd = 0; jd < 4; jd++) oacc[jd][i] *= sc;
      }
#pragma unroll
      for (int j = 0; j < 4; j++)
#pragma unroll
        for (int i = 0; i < 4; i++)
          Ps[g][16 * w + 4 * quad + i][16 * j + cc] = bf16u(p[j][i]);
      __asm__ volatile("s_waitcnt lgkmcnt(0)" ::: "memory");
#pragma unroll
      for (int ks = 0; ks < 2; ks++) {
        short8 ap = *(const short8*)&Ps[g][16 * w + cc][8 * quad + 32 * ks];
#pragma unroll
        for (int jd = 0; jd < 4; jd++) {
          short8 bv = *(const short8*)&Vt[16 * jd + cc][8 * quad + 32 * ks];
          oacc[jd] = __builtin_amdgcn_mfma_f32_16x16x32_bf16(ap, bv, oacc[jd], 0, 0, 0);
        }
      }
    }
  }

#pragma unroll
  for (int i = 0; i < 4; i++) {
    float inv = 1.f / l_[i];
    int q = myqt * 64 + 16 * w + 4 * quad + i;
    ushort* orow = avd + ((size_t)(b * SEQ + q)) * (NHEAD * DH) + n * DH;
#pragma unroll
    for (int jd = 0; jd < 4; jd++)
      orow[16 * jd + cc] = bf16u(oacc[jd][i] * inv);
  }
}

// ---------------- bf16 MFMA GEMM, 128x128 tile, BK=32 ----------------
template <int MODE>
__global__ __launch_bounds__(256) void gemm_bf16(
    const ushort* __restrict__ A1, const ushort* __restrict__ B1t, int K1,
    const ushort* __restrict__ A2, const ushort* __restrict__ B2t, int K2,
    void* __restrict__ outv, int N) {
  __shared__ __align__(16) ushort As[128][32];
  __shared__ __align__(16) ushort Bs[128][32];
  int m0 = blockIdx.x * 128, n0 = blockIdx.y * 128;
  int tid = threadIdx.x;
  int lane = tid & 63, wave = tid >> 6;
  int wm = wave & 1, wn = wave >> 1;
  int cc = lane & 15, quad = lane >> 4;
  int sr = tid >> 2, sc = tid & 3;

  f32x4 acc[4][4];
#pragma unroll
  for (int i = 0; i < 4; i++)
#pragma unroll
    for (int j = 0; j < 4; j++)
#pragma unroll
      for (int r = 0; r < 4; r++) acc[i][j][r] = 0.f;

  const int npass = (MODE == 0) ? 2 : 1;
  for (int pass = 0; pass < npass; pass++) {
    const ushort* A = pass ? A2 : A1;
    const ushort* Bt = pass ? B2t : B1t;
    int K = pass ? K2 : K1;
    for (int k0 = 0; k0 < K; k0 += 32) {
      __syncthreads();
      {
        short8 a0 = *(const short8*)(A + (size_t)(m0 + sr) * K + k0 + 8 * sc);
        short8 a1 = *(const short8*)(A + (size_t)(m0 + sr + 64) * K + k0 + 8 * sc);
        short8 b0 = *(const short8*)(Bt + (size_t)(n0 + sr) * K + k0 + 8 * sc);
        short8 b1 = *(const short8*)(Bt + (size_t)(n0 + sr + 64) * K + k0 + 8 * sc);
        *(short8*)&As[sr][8 * ((sc + (sr >> 1)) & 3)] = a0;
        *(short8*)&As[sr + 64][8 * ((sc + ((sr + 64) >> 1)) & 3)] = a1;
        *(short8*)&Bs[sr][8 * ((sc + (sr >> 1)) & 3)] = b0;
        *(short8*)&Bs[sr + 64][8 * ((sc + ((sr + 64) >> 1)) & 3)] = b1;
      }
      __syncthreads();
      short8 af[4], bfr[4];
#pragma unroll
      for (int i = 0; i < 4; i++) {
        int ra = 64 * wm + 16 * i + cc;
        af[i] = *(const short8*)&As[ra][8 * ((quad + (ra >> 1)) & 3)];
      }
#pragma unroll
      for (int j = 0; j < 4; j++) {
        int rb = 64 * wn + 16 * j + cc;
        bfr[j] = *(const short8*)&Bs[rb][8 * ((quad + (rb >> 1)) & 3)];
      }
#pragma unroll
      for (int i = 0; i < 4; i++)
#pragma unroll
        for (int j = 0; j < 4; j++)
          acc[i][j] = __builtin_amdgcn_mfma_f32_16x16x32_bf16(af[i], bfr[j], acc[i][j], 0, 0, 0);
    }
  }

#pragma unroll
  for (int i = 0; i < 4; i++) {
#pragma unroll
    for (int j = 0; j < 4; j++) {
      int colg = n0 + 64 * wn + 16 * j + cc;
#pragma unroll
      for (int r = 0; r < 4; r++) {
        int row = m0 + 64 * wm + 16 * i + 4 * quad + r;
        if (MODE == 0) {
          ((float*)outv)[(size_t)row * N + colg] = acc[i][j][r];
        } else {
          float v = acc[i][j][r];
          if ((colg % 192) < 64) v *= 0.125f;
          ((ushort*)outv)[(size_t)row * N + colg] = bf16u(v);
        }
      }
    }
  }
}

extern "C" void kernel_launch(void* const* d_in, const int* in_sizes, int n_in,
                              void* d_out, int out_size, void* d_ws, size_t ws_size,
                              hipStream_t stream) {
  const float* X          = (const float*)d_in[0];
  const float* router_w   = (const float*)d_in[1];
  const float* mosa_wqkv  = (const float*)d_in[2];
  const float* mosa_wo    = (const float*)d_in[3];
  const float* dense_wqkv = (const float*)d_in[4];
  const float* dense_wo   = (const float*)d_in[5];
  float* out = (float*)d_out;
  char* ws = (char*)d_ws;

  // workspace layout (bytes)
  float*  scores  = (float*) (ws + 0);          // 131072
  int*    sel     = (int*)   (ws + 131072);     // 16384
  float*  gates   = (float*) (ws + 147456);     // 16384
  float*  qkvm    = (float*) (ws + 163840);     // 3145728  (f32 mosa qkv)
  ushort* avm     = (ushort*)(ws + 3309568);    // 4194304  (bf16)
  ushort* avd     = (ushort*)(ws + 7503872);    // 4194304  (bf16)
  ushort* Xb      = (ushort*)(ws + 11698176);   // 8388608  (bf16 X)
  ushort* qkvb    = (ushort*)(ws + 20086784);   // 12582912 (bf16 dense qkv)
  ushort* Wqkv_t  = (ushort*)(ws + 32669696);   // 3145728
  ushort* Wdo_t   = (ushort*)(ws + 35815424);   // 1048576
  ushort* Wmo_t   = (ushort*)(ws + 36864000);   // 1048576
  int*    pranks  = (int*)   (ws + 37912576);   // 16*16*2048*4 = 2097152 (end 40009728)

  hipMemsetAsync(avm, 0, (size_t)BB * SEQ * NHEAD * DH * sizeof(ushort), stream);

  // casts / transposes
  cast_bf16x4<<<4096, 256, 0, stream>>>(X, Xb, BB * SEQ * HD / 4);
  transpose_cast<<<dim3(1536 / 32, 1024 / 32), 256, 0, stream>>>(dense_wqkv, Wqkv_t, 1024, 1536);
  transpose_cast<<<dim3(1024 / 32, 512 / 32), 256, 0, stream>>>(dense_wo, Wdo_t, 512, 1024);
  transpose_cast<<<dim3(1024 / 32, 512 / 32), 256, 0, stream>>>(mosa_wo, Wmo_t, 512, 1024);

  // mosa branch
  router_kernel<<<BB * SEQ, 256, 0, stream>>>(X, router_w, scores);
  topk_partial<<<dim3(BB * NHEAD, 16), 256, 0, stream>>>(scores, pranks);
  topk_select<<<BB * NHEAD, 1024, 0, stream>>>(scores, pranks, sel, gates);
  gemm_mosa_qkv<<<dim3(BB * NHEAD, KSEL / 64, D3 / 64), 256, 0, stream>>>(X, mosa_wqkv, sel, qkvm);
  rope_mosa<<<(BB * NHEAD * KSEL * RHALF + 255) / 256, 256, 0, stream>>>(qkvm, sel);
  mosa_flash<<<dim3(BB * NHEAD, (KSEL / 64) / 2), 512, 0, stream>>>(qkvm, sel, gates, avm, KSEL / 64);

  // dense branch (bf16 MFMA)
  gemm_bf16<1><<<dim3(32, 12), 256, 0, stream>>>(Xb, Wqkv_t, 1024,
                                                 (const ushort*)nullptr, (const ushort*)nullptr, 0,
                                                 qkvb, NHEAD * D3);
  rope_dense_b<<<4096, 256, 0, stream>>>(qkvb);
  flash_mfma<<<dim3(BB * NHEAD, (SEQ / 64) / 2), 512, 0, stream>>>(qkvb, avd, SEQ / 64);

  // final: out = avm@mosa_wo + avd@dense_wo  (f32 out)
  gemm_bf16<0><<<dim3(32, 8), 256, 0, stream>>>(avm, Wmo_t, 512, avd, Wdo_t, 512, out, HD);
}

// Round 5
// 353.562 us; speedup vs baseline: 4.6887x; 1.1821x over previous
//
#include <hip/hip_runtime.h>
#include <math.h>

constexpr int BB = 2;
constexpr int SEQ = 2048;
constexpr int HD = 1024;
constexpr int DH = 64;       // head dim
constexpr int NHEAD = 8;
constexpr int D3 = 192;      // 3*DH
constexpr int KSEL = 256;    // SEQ / SPARSITY
constexpr float NEG = -1e30f;

typedef short short8 __attribute__((ext_vector_type(8)));
typedef float f32x4 __attribute__((ext_vector_type(4)));

__device__ __forceinline__ ushort bf16u(float f) {
  union { float f; unsigned u; } v; v.f = f;
  unsigned r = (v.u + 0x7FFFu + ((v.u >> 16) & 1u)) >> 16;
  return (ushort)r;
}
__device__ __forceinline__ float bf2f(ushort h) {
  union { unsigned u; float f; } v; v.u = ((unsigned)h) << 16;
  return v.f;
}

// ---------------- cast f32 -> bf16, 4 elems/thread ----------------
__global__ void cast_bf16x4(const float* __restrict__ x, ushort* __restrict__ y, int n4) {
  int i = blockIdx.x * 256 + threadIdx.x;
  if (i >= n4) return;
  float4 v = ((const float4*)x)[i];
  ushort4 r; r.x = bf16u(v.x); r.y = bf16u(v.y); r.z = bf16u(v.z); r.w = bf16u(v.w);
  ((ushort4*)y)[i] = r;
}

// ---------------- transpose + cast pair: W[K][N] f32 -> Wt[N][K] bf16 ----------------
__global__ __launch_bounds__(256) void transpose_cast2(
    const float* __restrict__ W1, ushort* __restrict__ T1,
    const float* __restrict__ W2, ushort* __restrict__ T2, int K, int N) {
  const float* W = blockIdx.z ? W2 : W1;
  ushort* Wt = blockIdx.z ? T2 : T1;
  __shared__ float tile[32][33];
  int n0 = blockIdx.x * 32, k0 = blockIdx.y * 32;
  int tx = threadIdx.x & 31, ty = threadIdx.x >> 5;   // ty 0..7
#pragma unroll
  for (int i = 0; i < 4; i++)
    tile[ty + 8 * i][tx] = W[(size_t)(k0 + ty + 8 * i) * N + n0 + tx];
  __syncthreads();
#pragma unroll
  for (int i = 0; i < 4; i++)
    Wt[(size_t)(n0 + ty + 8 * i) * K + k0 + tx] = bf16u(tile[tx][ty + 8 * i]);
}

// ---------------- router: scores[b][n][t] = X[b,t,:] . rw[:,n] ----------------
__global__ __launch_bounds__(256) void router_kernel(const float* __restrict__ X,
    const float* __restrict__ rw, float* __restrict__ scores) {
  int bt = blockIdx.x;
  __shared__ float xs[HD];
  const float* xrow = X + (size_t)bt * HD;
  for (int i = threadIdx.x; i < HD; i += 256) xs[i] = xrow[i];
  __syncthreads();
  int n = threadIdx.x >> 5;
  int lane = threadIdx.x & 31;
  float acc = 0.f;
  for (int h = lane; h < HD; h += 32) acc += xs[h] * rw[h * NHEAD + n];
  for (int off = 16; off > 0; off >>= 1) acc += __shfl_down(acc, off, 32);
  if (lane == 0) {
    int b = bt / SEQ, t = bt % SEQ;
    scores[((size_t)b * NHEAD + n) * SEQ + t] = acc;
  }
}

// ---------------- top-k stage 1: partial rank counts over j-chunks ----------------
__global__ __launch_bounds__(256) void topk_partial(const float* __restrict__ scores,
    int* __restrict__ pranks) {
  int row = blockIdx.x;
  int c = blockIdx.y;
  __shared__ float chunk[128];
  const float* sp = scores + (size_t)row * SEQ;
  if (threadIdx.x < 128) chunk[threadIdx.x] = sp[c * 128 + threadIdx.x];
  __syncthreads();
  int t = threadIdx.x;
  float v[8]; int vi[8]; int p[8];
#pragma unroll
  for (int i = 0; i < 8; i++) { vi[i] = i * 256 + t; v[i] = sp[vi[i]]; p[i] = 0; }
  int jbase = c * 128;
#pragma unroll 4
  for (int j4 = 0; j4 < 128; j4 += 4) {
    float4 s4 = *(const float4*)&chunk[j4];
    float ss[4] = {s4.x, s4.y, s4.z, s4.w};
#pragma unroll
    for (int jj = 0; jj < 4; jj++) {
      float sj = ss[jj];
      int jg = jbase + j4 + jj;
#pragma unroll
      for (int i = 0; i < 8; i++)
        p[i] += (sj > v[i]) || (sj == v[i] && jg < vi[i]);
    }
  }
#pragma unroll
  for (int i = 0; i < 8; i++)
    pranks[((size_t)row * 16 + c) * SEQ + vi[i]] = p[i];
}

// ---------------- top-k stage 2: sum partials, select, scan, emit ----------------
__global__ __launch_bounds__(1024) void topk_select(const float* __restrict__ scores,
    const int* __restrict__ pranks, int* __restrict__ sel, float* __restrict__ gates) {
  int bn = blockIdx.x;
  __shared__ int psum[1024];
  int t0 = threadIdx.x * 2;
  int r0 = 0, r1 = 0;
#pragma unroll
  for (int c = 0; c < 16; c++) {
    const int* pr = pranks + ((size_t)bn * 16 + c) * SEQ;
    r0 += pr[t0];
    r1 += pr[t0 + 1];
  }
  float v0 = scores[(size_t)bn * SEQ + t0];
  float v1 = scores[(size_t)bn * SEQ + t0 + 1];
  int f0 = r0 < KSEL, f1 = r1 < KSEL;
  psum[threadIdx.x] = f0 + f1;
  __syncthreads();
  for (int off = 1; off < 1024; off <<= 1) {
    int val = psum[threadIdx.x];
    int add = (threadIdx.x >= off) ? psum[threadIdx.x - off] : 0;
    __syncthreads();
    psum[threadIdx.x] = val + add;
    __syncthreads();
  }
  int base = psum[threadIdx.x] - (f0 + f1);
  if (f0) { sel[bn * KSEL + base] = t0;
            gates[bn * KSEL + base] = 1.f / (1.f + __expf(-v0)); base++; }
  if (f1) { sel[bn * KSEL + base] = t0 + 1;
            gates[bn * KSEL + base] = 1.f / (1.f + __expf(-v1)); }
}

// ---------------- mosa qkv: gathered-A bf16 MFMA GEMM, 64x64 tile ----------------
// qkvmb[bn][256][192] bf16, Q cols (<64) pre-scaled by 1/8.
__global__ __launch_bounds__(256) void gemm_mosa_bf16(const ushort* __restrict__ Xb,
    const ushort* __restrict__ Wt, const int* __restrict__ sel,
    ushort* __restrict__ qkvmb) {
  __shared__ __align__(16) ushort As[64][40];
  __shared__ __align__(16) ushort Bs[64][40];
  int bn = blockIdx.x; int b = bn >> 3, n = bn & 7;
  int m0 = blockIdx.y * 64, n0 = blockIdx.z * 64;
  int tid = threadIdx.x;
  int lane = tid & 63, w = tid >> 6;
  int wm = w & 1, wn = w >> 1;
  int cc = lane & 15, quad = lane >> 4;
  int sr = tid >> 2, sc4 = tid & 3;

  int grow = sel[bn * KSEL + m0 + sr];
  const ushort* arow = Xb + ((size_t)(b * SEQ) + grow) * HD;
  const ushort* brow = Wt + ((size_t)(n * D3 + n0 + sr)) * HD;

  f32x4 acc[2][2];
#pragma unroll
  for (int i = 0; i < 2; i++)
#pragma unroll
    for (int j = 0; j < 2; j++)
#pragma unroll
      for (int r = 0; r < 4; r++) acc[i][j][r] = 0.f;

  for (int k0 = 0; k0 < HD; k0 += 32) {
    __syncthreads();
    *(short8*)&As[sr][8 * sc4] = *(const short8*)(arow + k0 + 8 * sc4);
    *(short8*)&Bs[sr][8 * sc4] = *(const short8*)(brow + k0 + 8 * sc4);
    __syncthreads();
    short8 af[2], bf_[2];
#pragma unroll
    for (int i = 0; i < 2; i++) af[i] = *(const short8*)&As[32 * wm + 16 * i + cc][8 * quad];
#pragma unroll
    for (int j = 0; j < 2; j++) bf_[j] = *(const short8*)&Bs[32 * wn + 16 * j + cc][8 * quad];
#pragma unroll
    for (int i = 0; i < 2; i++)
#pragma unroll
      for (int j = 0; j < 2; j++)
        acc[i][j] = __builtin_amdgcn_mfma_f32_16x16x32_bf16(af[i], bf_[j], acc[i][j], 0, 0, 0);
  }

#pragma unroll
  for (int i = 0; i < 2; i++)
#pragma unroll
    for (int j = 0; j < 2; j++) {
      int col = n0 + 32 * wn + 16 * j + cc;
      float scale = (col < 64) ? 0.125f : 1.f;
#pragma unroll
      for (int r = 0; r < 4; r++) {
        int row = m0 + 32 * wm + 16 * i + 4 * quad + r;
        qkvmb[((size_t)bn * KSEL + row) * D3 + col] = bf16u(acc[i][j][r] * scale);
      }
    }
}

// ---------------- mosa RoPE on bf16 (pos from sel) ----------------
__global__ void rope_mosa_b(ushort* __restrict__ qkvmb, const int* __restrict__ sel) {
  int tid = blockIdx.x * 256 + threadIdx.x;   // 16*256 rows * 32
  int j = tid & 15;
  int which = (tid >> 4) & 1;                 // 0: Q, 1: K
  int row = tid >> 5;                         // bn*KSEL + r
  float pos = (float)sel[row];
  float inv = __expf((float)j * -0.5756462732485115f);
  float ang = pos * inv;
  float c = cosf(ang), sn = sinf(ang);
  ushort* p = qkvmb + (size_t)row * D3 + which * DH + j;
  float x1 = bf2f(p[0]), x2 = bf2f(p[16]);
  p[0] = bf16u(x1 * c - x2 * sn);
  p[16] = bf16u(x1 * sn + x2 * c);
}

// ---------------- dense RoPE on bf16 qkvb in place ----------------
__global__ void rope_dense_b(ushort* __restrict__ qkvb) {
  int tid = blockIdx.x * 256 + threadIdx.x;   // rows * 32
  int j = tid & 15;
  int which = (tid >> 4) & 1;                 // 0: Q, 1: K
  int row = tid >> 5;                         // (b*SEQ+t)*NHEAD + n
  int t = (row >> 3) & (SEQ - 1);
  float inv = __expf((float)j * -0.5756462732485115f);
  float ang = (float)t * inv;
  float c = cosf(ang), sn = sinf(ang);
  ushort* p = qkvb + (size_t)row * D3 + which * DH + j;
  float x1 = bf2f(p[0]), x2 = bf2f(p[16]);
  p[0] = bf16u(x1 * c - x2 * sn);
  p[16] = bf16u(x1 * sn + x2 * c);
}

// ---------------- unified MFMA flash attention (S^T form) ----------------
// One 256-thread block per 64-row q-tile; wave w owns q rows 16w..16w+15.
// S^T = K.Q^T via MFMA (Ks/Qs both natural row-major); per-lane softmax state
// (q = lane&15) needs only 2 shfl_xor per reduction; P stored [q][k] wave-locally,
// re-read as PV A-frag; V^T staged in LDS.
template <bool MOSA>
__global__ __launch_bounds__(256) void flash2(const ushort* __restrict__ qkv,
    const int* __restrict__ sel, const float* __restrict__ gates,
    ushort* __restrict__ outp, int nqt) {
  __shared__ __align__(16) ushort Qs[64][72];   // [q][d]
  __shared__ __align__(16) ushort Ks[64][72];   // [key][d]
  __shared__ __align__(16) ushort Vt[64][72];   // [d][key]
  __shared__ __align__(16) ushort Ps[64][72];   // [q][key]

  int bn = blockIdx.y; int b = bn >> 3, n = bn & 7;
  int qt = (nqt - 1) - blockIdx.x;              // heavy q-tiles dispatch first
  int tid = threadIdx.x;
  int lane = tid & 63, w = tid >> 6;
  int cc = lane & 15, quad = lane >> 4;

  const ushort* base;
  int rs;
  if (MOSA) { base = qkv + (size_t)bn * KSEL * D3; rs = D3; }
  else { base = qkv + ((size_t)b * SEQ) * (NHEAD * D3) + n * D3; rs = NHEAD * D3; }

  // stage Q tile (row-major; Q pre-scaled by 1/8 upstream)
  {
    int r = tid >> 2, c = tid & 3;
    const ushort* src = base + (size_t)(qt * 64 + r) * rs;
    *(short8*)&Qs[r][8 * c] = *(const short8*)(src + 8 * c);
    *(short8*)&Qs[r][8 * (c + 4)] = *(const short8*)(src + 8 * (c + 4));
  }

  f32x4 oacc[4];
  float m = NEG, l = 0.f;
#pragma unroll
  for (int jd = 0; jd < 4; jd++)
#pragma unroll
    for (int r = 0; r < 4; r++) oacc[jd][r] = 0.f;

  for (int kt = 0; kt <= qt; kt++) {
    __syncthreads();
    {
      int r = tid >> 2, c = tid & 3;
      const ushort* srck = base + (size_t)(kt * 64 + r) * rs + DH;
      *(short8*)&Ks[r][8 * c] = *(const short8*)(srck + 8 * c);
      *(short8*)&Ks[r][8 * (c + 4)] = *(const short8*)(srck + 8 * (c + 4));
      int key = lane, dc = w;
      const ushort* srcv = base + (size_t)(kt * 64 + key) * rs + 2 * DH;
      short8 v0 = *(const short8*)(srcv + 8 * dc);
      short8 v1 = *(const short8*)(srcv + 8 * (dc + 4));
#pragma unroll
      for (int i2 = 0; i2 < 8; i2++) {
        Vt[8 * dc + i2][key] = ((const ushort*)&v0)[i2];
        Vt[8 * (dc + 4) + i2][key] = ((const ushort*)&v1)[i2];
      }
    }
    __syncthreads();

    // S^T = K.Q^T : C rows = key(4*quad+reg within 16j), cols = q (cc)
    f32x4 sacc[4];
#pragma unroll
    for (int j = 0; j < 4; j++)
#pragma unroll
      for (int r = 0; r < 4; r++) sacc[j][r] = 0.f;
#pragma unroll
    for (int ks = 0; ks < 2; ks++) {
      short8 bq = *(const short8*)&Qs[16 * w + cc][8 * quad + 32 * ks];
#pragma unroll
      for (int j = 0; j < 4; j++) {
        short8 ak = *(const short8*)&Ks[16 * j + cc][8 * quad + 32 * ks];
        sacc[j] = __builtin_amdgcn_mfma_f32_16x16x32_bf16(ak, bq, sacc[j], 0, 0, 0);
      }
    }
    if (kt == qt) {
#pragma unroll
      for (int j = 0; j < 4; j++)
#pragma unroll
        for (int r = 0; r < 4; r++)
          if (16 * j + 4 * quad + r > 16 * w + cc) sacc[j][r] = NEG;
    }
    // per-lane online softmax for q = 16w + cc (16 key-values in-lane)
    float mx = NEG;
#pragma unroll
    for (int j = 0; j < 4; j++)
#pragma unroll
      for (int r = 0; r < 4; r++) mx = fmaxf(mx, sacc[j][r]);
    mx = fmaxf(mx, __shfl_xor(mx, 16));
    mx = fmaxf(mx, __shfl_xor(mx, 32));
    float mn = fmaxf(m, mx);
    float sc = __expf(m - mn);
    m = mn;
    float rsum = 0.f;
    float p[4][4];
#pragma unroll
    for (int j = 0; j < 4; j++)
#pragma unroll
      for (int r = 0; r < 4; r++) { p[j][r] = __expf(sacc[j][r] - mn); rsum += p[j][r]; }
    rsum += __shfl_xor(rsum, 16);
    rsum += __shfl_xor(rsum, 32);
    l = l * sc + rsum;
    // write P[q][key] (wave-local rows 16w+cc)
#pragma unroll
    for (int j = 0; j < 4; j++)
#pragma unroll
      for (int r = 0; r < 4; r++)
        Ps[16 * w + cc][16 * j + 4 * quad + r] = bf16u(p[j][r]);
    // rescale O rows (q = 4*quad + r wave-local) by that q's sc
#pragma unroll
    for (int r = 0; r < 4; r++) {
      float scr = __shfl(sc, 16 * quad + 4 * quad + r);
#pragma unroll
      for (int jd = 0; jd < 4; jd++) oacc[jd][r] *= scr;
    }
    __asm__ volatile("s_waitcnt lgkmcnt(0)" ::: "memory");
    // O += P.V : A = Ps rows [q][k], B = Vt rows [d][key]
#pragma unroll
    for (int ks = 0; ks < 2; ks++) {
      short8 ap = *(const short8*)&Ps[16 * w + cc][8 * quad + 32 * ks];
#pragma unroll
      for (int jd = 0; jd < 4; jd++) {
        short8 bv = *(const short8*)&Vt[16 * jd + cc][8 * quad + 32 * ks];
        oacc[jd] = __builtin_amdgcn_mfma_f32_16x16x32_bf16(ap, bv, oacc[jd], 0, 0, 0);
      }
    }
  }

  // epilogue: rows q = qt*64 + 16w + 4*quad + r, cols d = 16jd + cc
#pragma unroll
  for (int r = 0; r < 4; r++) {
    float lr = __shfl(l, 16 * quad + 4 * quad + r);
    int q = qt * 64 + 16 * w + 4 * quad + r;
    float scale;
    size_t row;
    if (MOSA) {
      int trow = sel[bn * KSEL + q];
      scale = gates[bn * KSEL + q] / lr;
      row = (size_t)(b * SEQ + trow);
    } else {
      scale = 1.f / lr;
      row = (size_t)(b * SEQ + q);
    }
    ushort* orow = outp + row * (NHEAD * DH) + n * DH;
#pragma unroll
    for (int jd = 0; jd < 4; jd++)
      orow[16 * jd + cc] = bf16u(oacc[jd][r] * scale);
  }
}

// ---------------- bf16 MFMA GEMM, 128x128 tile, BK=32 ----------------
template <int MODE>
__global__ __launch_bounds__(256) void gemm_bf16(
    const ushort* __restrict__ A1, const ushort* __restrict__ B1t, int K1,
    const ushort* __restrict__ A2, const ushort* __restrict__ B2t, int K2,
    void* __restrict__ outv, int N) {
  __shared__ __align__(16) ushort As[128][32];
  __shared__ __align__(16) ushort Bs[128][32];
  int m0 = blockIdx.x * 128, n0 = blockIdx.y * 128;
  int tid = threadIdx.x;
  int lane = tid & 63, wave = tid >> 6;
  int wm = wave & 1, wn = wave >> 1;
  int cc = lane & 15, quad = lane >> 4;
  int sr = tid >> 2, sc = tid & 3;

  f32x4 acc[4][4];
#pragma unroll
  for (int i = 0; i < 4; i++)
#pragma unroll
    for (int j = 0; j < 4; j++)
#pragma unroll
      for (int r = 0; r < 4; r++) acc[i][j][r] = 0.f;

  const int npass = (MODE == 0) ? 2 : 1;
  for (int pass = 0; pass < npass; pass++) {
    const ushort* A = pass ? A2 : A1;
    const ushort* Bt = pass ? B2t : B1t;
    int K = pass ? K2 : K1;
    for (int k0 = 0; k0 < K; k0 += 32) {
      __syncthreads();
      {
        short8 a0 = *(const short8*)(A + (size_t)(m0 + sr) * K + k0 + 8 * sc);
        short8 a1 = *(const short8*)(A + (size_t)(m0 + sr + 64) * K + k0 + 8 * sc);
        short8 b0 = *(const short8*)(Bt + (size_t)(n0 + sr) * K + k0 + 8 * sc);
        short8 b1 = *(const short8*)(Bt + (size_t)(n0 + sr + 64) * K + k0 + 8 * sc);
        *(short8*)&As[sr][8 * ((sc + (sr >> 1)) & 3)] = a0;
        *(short8*)&As[sr + 64][8 * ((sc + ((sr + 64) >> 1)) & 3)] = a1;
        *(short8*)&Bs[sr][8 * ((sc + (sr >> 1)) & 3)] = b0;
        *(short8*)&Bs[sr + 64][8 * ((sc + ((sr + 64) >> 1)) & 3)] = b1;
      }
      __syncthreads();
      short8 af[4], bfr[4];
#pragma unroll
      for (int i = 0; i < 4; i++) {
        int ra = 64 * wm + 16 * i + cc;
        af[i] = *(const short8*)&As[ra][8 * ((quad + (ra >> 1)) & 3)];
      }
#pragma unroll
      for (int j = 0; j < 4; j++) {
        int rb = 64 * wn + 16 * j + cc;
        bfr[j] = *(const short8*)&Bs[rb][8 * ((quad + (rb >> 1)) & 3)];
      }
#pragma unroll
      for (int i = 0; i < 4; i++)
#pragma unroll
        for (int j = 0; j < 4; j++)
          acc[i][j] = __builtin_amdgcn_mfma_f32_16x16x32_bf16(af[i], bfr[j], acc[i][j], 0, 0, 0);
    }
  }

#pragma unroll
  for (int i = 0; i < 4; i++) {
#pragma unroll
    for (int j = 0; j < 4; j++) {
      int colg = n0 + 64 * wn + 16 * j + cc;
#pragma unroll
      for (int r = 0; r < 4; r++) {
        int row = m0 + 64 * wm + 16 * i + 4 * quad + r;
        if (MODE == 0) {
          ((float*)outv)[(size_t)row * N + colg] = acc[i][j][r];
        } else {
          float v = acc[i][j][r];
          if ((colg % 192) < 64) v *= 0.125f;
          ((ushort*)outv)[(size_t)row * N + colg] = bf16u(v);
        }
      }
    }
  }
}

extern "C" void kernel_launch(void* const* d_in, const int* in_sizes, int n_in,
                              void* d_out, int out_size, void* d_ws, size_t ws_size,
                              hipStream_t stream) {
  const float* X          = (const float*)d_in[0];
  const float* router_w   = (const float*)d_in[1];
  const float* mosa_wqkv  = (const float*)d_in[2];
  const float* mosa_wo    = (const float*)d_in[3];
  const float* dense_wqkv = (const float*)d_in[4];
  const float* dense_wo   = (const float*)d_in[5];
  float* out = (float*)d_out;
  char* ws = (char*)d_ws;

  // workspace layout (bytes)
  float*  scores  = (float*) (ws + 0);          // 131072
  int*    sel     = (int*)   (ws + 131072);     // 16384
  float*  gates   = (float*) (ws + 147456);     // 16384
  ushort* qkvmb   = (ushort*)(ws + 163840);     // 1572864 (bf16 mosa qkv)
  ushort* avm     = (ushort*)(ws + 1736704);    // 4194304
  ushort* avd     = (ushort*)(ws + 5931008);    // 4194304
  ushort* Xb      = (ushort*)(ws + 10125312);   // 8388608
  ushort* qkvb    = (ushort*)(ws + 18513920);   // 12582912 (bf16 dense qkv)
  ushort* Wqkv_t  = (ushort*)(ws + 31096832);   // 3145728
  ushort* Wmq_t   = (ushort*)(ws + 34242560);   // 3145728
  ushort* Wdo_t   = (ushort*)(ws + 37388288);   // 1048576
  ushort* Wmo_t   = (ushort*)(ws + 38436864);   // 1048576
  int*    pranks  = (int*)   (ws + 39485440);   // 2097152 (end 41582592)

  hipMemsetAsync(avm, 0, (size_t)BB * SEQ * NHEAD * DH * sizeof(ushort), stream);

  // casts / transposes
  cast_bf16x4<<<4096, 256, 0, stream>>>(X, Xb, BB * SEQ * HD / 4);
  transpose_cast2<<<dim3(48, 32, 2), 256, 0, stream>>>(dense_wqkv, Wqkv_t,
                                                       mosa_wqkv, Wmq_t, 1024, 1536);
  transpose_cast2<<<dim3(32, 16, 2), 256, 0, stream>>>(dense_wo, Wdo_t,
                                                       mosa_wo, Wmo_t, 512, 1024);

  // router + top-k
  router_kernel<<<BB * SEQ, 256, 0, stream>>>(X, router_w, scores);
  topk_partial<<<dim3(BB * NHEAD, 16), 256, 0, stream>>>(scores, pranks);
  topk_select<<<BB * NHEAD, 1024, 0, stream>>>(scores, pranks, sel, gates);

  // mosa branch (bf16 MFMA)
  gemm_mosa_bf16<<<dim3(BB * NHEAD, KSEL / 64, D3 / 64), 256, 0, stream>>>(
      Xb, Wmq_t, sel, qkvmb);
  rope_mosa_b<<<(BB * NHEAD * KSEL * 32) / 256, 256, 0, stream>>>(qkvmb, sel);
  flash2<true><<<dim3(KSEL / 64, BB * NHEAD), 256, 0, stream>>>(
      qkvmb, sel, gates, avm, KSEL / 64);

  // dense branch (bf16 MFMA)
  gemm_bf16<1><<<dim3(32, 12), 256, 0, stream>>>(Xb, Wqkv_t, 1024,
                                                 (const ushort*)nullptr, (const ushort*)nullptr, 0,
                                                 qkvb, NHEAD * D3);
  rope_dense_b<<<4096, 256, 0, stream>>>(qkvb);
  flash2<false><<<dim3(SEQ / 64, BB * NHEAD), 256, 0, stream>>>(
      qkvb, (const int*)nullptr, (const float*)nullptr, avd, SEQ / 64);

  // final: out = avm@mosa_wo + avd@dense_wo  (f32 out)
  gemm_bf16<0><<<dim3(32, 8), 256, 0, stream>>>(avm, Wmo_t, 512, avd, Wdo_t, 512, out, HD);
}

// Round 6
// 324.505 us; speedup vs baseline: 5.1085x; 1.0895x over previous
//
#include <hip/hip_runtime.h>
#include <math.h>

constexpr int BB = 2;
constexpr int SEQ = 2048;
constexpr int HD = 1024;
constexpr int DH = 64;       // head dim
constexpr int NHEAD = 8;
constexpr int D3 = 192;      // 3*DH
constexpr int KSEL = 256;    // SEQ / SPARSITY
constexpr float NEG = -1e30f;

typedef short short8 __attribute__((ext_vector_type(8)));
typedef float f32x4 __attribute__((ext_vector_type(4)));

__device__ __forceinline__ ushort bf16u(float f) {
  union { float f; unsigned u; } v; v.f = f;
  unsigned r = (v.u + 0x7FFFu + ((v.u >> 16) & 1u)) >> 16;
  return (ushort)r;
}
__device__ __forceinline__ float bf2f(ushort h) {
  union { unsigned u; float f; } v; v.u = ((unsigned)h) << 16;
  return v.f;
}

// ---------------- cast f32 -> bf16, 4 elems/thread ----------------
__global__ void cast_bf16x4(const float* __restrict__ x, ushort* __restrict__ y, int n4) {
  int i = blockIdx.x * 256 + threadIdx.x;
  if (i >= n4) return;
  float4 v = ((const float4*)x)[i];
  ushort4 r; r.x = bf16u(v.x); r.y = bf16u(v.y); r.z = bf16u(v.z); r.w = bf16u(v.w);
  ((ushort4*)y)[i] = r;
}

// ---------------- transpose + cast pair: W[K][N] f32 -> Wt[N][K] bf16 ----------------
__global__ __launch_bounds__(256) void transpose_cast2(
    const float* __restrict__ W1, ushort* __restrict__ T1,
    const float* __restrict__ W2, ushort* __restrict__ T2, int K, int N) {
  const float* W = blockIdx.z ? W2 : W1;
  ushort* Wt = blockIdx.z ? T2 : T1;
  __shared__ float tile[32][33];
  int n0 = blockIdx.x * 32, k0 = blockIdx.y * 32;
  int tx = threadIdx.x & 31, ty = threadIdx.x >> 5;
#pragma unroll
  for (int i = 0; i < 4; i++)
    tile[ty + 8 * i][tx] = W[(size_t)(k0 + ty + 8 * i) * N + n0 + tx];
  __syncthreads();
#pragma unroll
  for (int i = 0; i < 4; i++)
    Wt[(size_t)(n0 + ty + 8 * i) * K + k0 + tx] = bf16u(tile[tx][ty + 8 * i]);
}

// ---------------- router ----------------
__global__ __launch_bounds__(256) void router_kernel(const float* __restrict__ X,
    const float* __restrict__ rw, float* __restrict__ scores) {
  int bt = blockIdx.x;
  __shared__ float xs[HD];
  const float* xrow = X + (size_t)bt * HD;
  for (int i = threadIdx.x; i < HD; i += 256) xs[i] = xrow[i];
  __syncthreads();
  int n = threadIdx.x >> 5;
  int lane = threadIdx.x & 31;
  float acc = 0.f;
  for (int h = lane; h < HD; h += 32) acc += xs[h] * rw[h * NHEAD + n];
  for (int off = 16; off > 0; off >>= 1) acc += __shfl_down(acc, off, 32);
  if (lane == 0) {
    int b = bt / SEQ, t = bt % SEQ;
    scores[((size_t)b * NHEAD + n) * SEQ + t] = acc;
  }
}

// ---------------- top-k stage 1: partial rank counts ----------------
__global__ __launch_bounds__(256) void topk_partial(const float* __restrict__ scores,
    int* __restrict__ pranks) {
  int row = blockIdx.x;
  int c = blockIdx.y;
  __shared__ float chunk[128];
  const float* sp = scores + (size_t)row * SEQ;
  if (threadIdx.x < 128) chunk[threadIdx.x] = sp[c * 128 + threadIdx.x];
  __syncthreads();
  int t = threadIdx.x;
  float v[8]; int vi[8]; int p[8];
#pragma unroll
  for (int i = 0; i < 8; i++) { vi[i] = i * 256 + t; v[i] = sp[vi[i]]; p[i] = 0; }
  int jbase = c * 128;
#pragma unroll 4
  for (int j4 = 0; j4 < 128; j4 += 4) {
    float4 s4 = *(const float4*)&chunk[j4];
    float ss[4] = {s4.x, s4.y, s4.z, s4.w};
#pragma unroll
    for (int jj = 0; jj < 4; jj++) {
      float sj = ss[jj];
      int jg = jbase + j4 + jj;
#pragma unroll
      for (int i = 0; i < 8; i++)
        p[i] += (sj > v[i]) || (sj == v[i] && jg < vi[i]);
    }
  }
#pragma unroll
  for (int i = 0; i < 8; i++)
    pranks[((size_t)row * 16 + c) * SEQ + vi[i]] = p[i];
}

// ---------------- top-k stage 2 ----------------
__global__ __launch_bounds__(1024) void topk_select(const float* __restrict__ scores,
    const int* __restrict__ pranks, int* __restrict__ sel, float* __restrict__ gates) {
  int bn = blockIdx.x;
  __shared__ int psum[1024];
  int t0 = threadIdx.x * 2;
  int r0 = 0, r1 = 0;
#pragma unroll
  for (int c = 0; c < 16; c++) {
    const int* pr = pranks + ((size_t)bn * 16 + c) * SEQ;
    r0 += pr[t0];
    r1 += pr[t0 + 1];
  }
  float v0 = scores[(size_t)bn * SEQ + t0];
  float v1 = scores[(size_t)bn * SEQ + t0 + 1];
  int f0 = r0 < KSEL, f1 = r1 < KSEL;
  psum[threadIdx.x] = f0 + f1;
  __syncthreads();
  for (int off = 1; off < 1024; off <<= 1) {
    int val = psum[threadIdx.x];
    int add = (threadIdx.x >= off) ? psum[threadIdx.x - off] : 0;
    __syncthreads();
    psum[threadIdx.x] = val + add;
    __syncthreads();
  }
  int base = psum[threadIdx.x] - (f0 + f1);
  if (f0) { sel[bn * KSEL + base] = t0;
            gates[bn * KSEL + base] = 1.f / (1.f + __expf(-v0)); base++; }
  if (f1) { sel[bn * KSEL + base] = t0 + 1;
            gates[bn * KSEL + base] = 1.f / (1.f + __expf(-v1)); }
}

// ---------------- mosa qkv: gathered-A bf16 MFMA GEMM -> split Q/K/V^T layouts ----------
__global__ __launch_bounds__(256) void gemm_mosa_bf16(const ushort* __restrict__ Xb,
    const ushort* __restrict__ Wt, const int* __restrict__ sel,
    ushort* __restrict__ Qmg, ushort* __restrict__ Kmg, ushort* __restrict__ Vtmg) {
  __shared__ __align__(16) ushort As[64][40];
  __shared__ __align__(16) ushort Bs[64][40];
  int bn = blockIdx.x; int b = bn >> 3, n = bn & 7;
  int m0 = blockIdx.y * 64, n0 = blockIdx.z * 64;
  int tid = threadIdx.x;
  int lane = tid & 63, w = tid >> 6;
  int wm = w & 1, wn = w >> 1;
  int cc = lane & 15, quad = lane >> 4;
  int sr = tid >> 2, sc4 = tid & 3;

  int grow = sel[bn * KSEL + m0 + sr];
  const ushort* arow = Xb + ((size_t)(b * SEQ) + grow) * HD;
  const ushort* brow = Wt + ((size_t)(n * D3 + n0 + sr)) * HD;

  f32x4 acc[2][2];
#pragma unroll
  for (int i = 0; i < 2; i++)
#pragma unroll
    for (int j = 0; j < 2; j++)
#pragma unroll
      for (int r = 0; r < 4; r++) acc[i][j][r] = 0.f;

  for (int k0 = 0; k0 < HD; k0 += 32) {
    __syncthreads();
    *(short8*)&As[sr][8 * sc4] = *(const short8*)(arow + k0 + 8 * sc4);
    *(short8*)&Bs[sr][8 * sc4] = *(const short8*)(brow + k0 + 8 * sc4);
    __syncthreads();
    short8 af[2], bf_[2];
#pragma unroll
    for (int i = 0; i < 2; i++) af[i] = *(const short8*)&As[32 * wm + 16 * i + cc][8 * quad];
#pragma unroll
    for (int j = 0; j < 2; j++) bf_[j] = *(const short8*)&Bs[32 * wn + 16 * j + cc][8 * quad];
#pragma unroll
    for (int i = 0; i < 2; i++)
#pragma unroll
      for (int j = 0; j < 2; j++)
        acc[i][j] = __builtin_amdgcn_mfma_f32_16x16x32_bf16(af[i], bf_[j], acc[i][j], 0, 0, 0);
  }

#pragma unroll
  for (int i = 0; i < 2; i++)
#pragma unroll
    for (int j = 0; j < 2; j++) {
      int col = n0 + 32 * wn + 16 * j + cc;   // 0..191, segment = n0 (uniform)
      int row0 = m0 + 32 * wm + 16 * i + 4 * quad;
      if (col < 64) {
#pragma unroll
        for (int r = 0; r < 4; r++)
          Qmg[((size_t)bn * KSEL + row0 + r) * 64 + col] = bf16u(acc[i][j][r] * 0.125f);
      } else if (col < 128) {
#pragma unroll
        for (int r = 0; r < 4; r++)
          Kmg[((size_t)bn * KSEL + row0 + r) * 64 + (col - 64)] = bf16u(acc[i][j][r]);
      } else {
        ushort4 pk;
        pk.x = bf16u(acc[i][j][0]); pk.y = bf16u(acc[i][j][1]);
        pk.z = bf16u(acc[i][j][2]); pk.w = bf16u(acc[i][j][3]);
        *(ushort4*)&Vtmg[((size_t)bn * 64 + (col - 128)) * KSEL + row0] = pk;
      }
    }
}

// ---------------- RoPE on split Q/K layouts (rows of 64) ----------------
__global__ void rope_split(ushort* __restrict__ Qb, ushort* __restrict__ Kb,
                           const int* __restrict__ sel, int mosa) {
  int tid = blockIdx.x * 256 + threadIdx.x;
  int j = tid & 15;
  int which = (tid >> 4) & 1;                 // 0: Q, 1: K
  int row = tid >> 5;
  float pos = mosa ? (float)sel[row] : (float)(row & (SEQ - 1));
  float inv = __expf((float)j * -0.5756462732485115f);
  float ang = pos * inv;
  float c = cosf(ang), sn = sinf(ang);
  ushort* p = (which ? Kb : Qb) + (size_t)row * 64 + j;
  float x1 = bf2f(p[0]), x2 = bf2f(p[16]);
  p[0] = bf16u(x1 * c - x2 * sn);
  p[16] = bf16u(x1 * sn + x2 * c);
}

// ---------------- flash4: paired q-tiles, shared K/V staging, S^T softmax ----------------
// 512 thr = 2 groups x 4 waves. Group g handles q-tile (g? nqt-1-pair : pair).
// All threads stage shared Ks/Vt (V^T comes pre-transposed from global).
// XOR-swizzled LDS (stride 64, chunk c^(r&7)) -> 2-way-floor b128 access.
template <bool MOSA>
__global__ __launch_bounds__(512) void flash4(
    const ushort* __restrict__ Qg, const ushort* __restrict__ Kg,
    const ushort* __restrict__ Vtg, const int* __restrict__ sel,
    const float* __restrict__ gates, ushort* __restrict__ outp, int nqt) {
  __shared__ __align__(16) ushort Qs[2][64][64];
  __shared__ __align__(16) ushort Ks[64][64];
  __shared__ __align__(16) ushort Vt[64][64];
  __shared__ __align__(16) ushort Ps[2][64][64];

  const int T = MOSA ? KSEL : SEQ;
  int bn = blockIdx.y; int b = bn >> 3, n = bn & 7;
  int pair = blockIdx.x;
  int qtA = pair, qtB = nqt - 1 - pair;
  int tid = threadIdx.x;
  int g = tid >> 8;
  int myqt = g ? qtB : qtA;
  int t = tid & 255;
  int lane = tid & 63, w = (tid >> 6) & 3;
  int cc = lane & 15, quad = lane >> 4;

  const ushort* Qb = Qg + (size_t)bn * T * 64;
  const ushort* Kb = Kg + (size_t)bn * T * 64;
  const ushort* Vb = Vtg + (size_t)bn * 64 * T;

  // stage group's Q tile (2 b128/thread, swizzled)
  {
    int r = t >> 2, c = t & 3;
    const ushort* src = Qb + (size_t)(myqt * 64 + r) * 64;
    *(short8*)&Qs[g][r][8 * (c ^ (r & 7))] = *(const short8*)(src + 8 * c);
    int c2 = c + 4;
    *(short8*)&Qs[g][r][8 * (c2 ^ (r & 7))] = *(const short8*)(src + 8 * c2);
  }

  f32x4 oacc[4];
  float m = NEG, l = 0.f;
#pragma unroll
  for (int jd = 0; jd < 4; jd++)
#pragma unroll
    for (int r = 0; r < 4; r++) oacc[jd][r] = 0.f;

  for (int kt = 0; kt <= qtB; kt++) {
    __syncthreads();
    {
      int r = tid >> 3, c = tid & 7;
      *(short8*)&Ks[r][8 * (c ^ (r & 7))] =
          *(const short8*)(Kb + (size_t)(kt * 64 + r) * 64 + 8 * c);
      *(short8*)&Vt[r][8 * (c ^ (r & 7))] =
          *(const short8*)(Vb + (size_t)r * T + kt * 64 + 8 * c);
    }
    __syncthreads();

    if (g || (kt <= qtA)) {
      // S^T = K.Q^T : C col = q (cc), row = key (16j + 4quad + r)
      f32x4 sacc[4];
#pragma unroll
      for (int j = 0; j < 4; j++)
#pragma unroll
        for (int r = 0; r < 4; r++) sacc[j][r] = 0.f;
      int qrow = 16 * w + cc;
#pragma unroll
      for (int ks = 0; ks < 2; ks++) {
        short8 bq = *(const short8*)&Qs[g][qrow][8 * ((quad + 4 * ks) ^ (qrow & 7))];
#pragma unroll
        for (int j = 0; j < 4; j++) {
          int krow = 16 * j + cc;
          short8 ak = *(const short8*)&Ks[krow][8 * ((quad + 4 * ks) ^ (krow & 7))];
          sacc[j] = __builtin_amdgcn_mfma_f32_16x16x32_bf16(ak, bq, sacc[j], 0, 0, 0);
        }
      }
      if (kt == myqt) {
#pragma unroll
        for (int j = 0; j < 4; j++)
#pragma unroll
          for (int r = 0; r < 4; r++)
            if (16 * j + 4 * quad + r > 16 * w + cc) sacc[j][r] = NEG;
      }
      // per-lane online softmax (q = 16w+cc fixed per lane)
      float mx = NEG;
#pragma unroll
      for (int j = 0; j < 4; j++)
#pragma unroll
        for (int r = 0; r < 4; r++) mx = fmaxf(mx, sacc[j][r]);
      mx = fmaxf(mx, __shfl_xor(mx, 16));
      mx = fmaxf(mx, __shfl_xor(mx, 32));
      float mn = fmaxf(m, mx);
      float sc = __expf(m - mn);
      m = mn;
      float rsum = 0.f;
      float p[4][4];
#pragma unroll
      for (int j = 0; j < 4; j++)
#pragma unroll
        for (int r = 0; r < 4; r++) { p[j][r] = __expf(sacc[j][r] - mn); rsum += p[j][r]; }
      rsum += __shfl_xor(rsum, 16);
      rsum += __shfl_xor(rsum, 32);
      l = l * sc + rsum;
      // Ps[q][key] packed b64 (wave-local rows)
#pragma unroll
      for (int j = 0; j < 4; j++) {
        ushort4 pk;
        pk.x = bf16u(p[j][0]); pk.y = bf16u(p[j][1]);
        pk.z = bf16u(p[j][2]); pk.w = bf16u(p[j][3]);
        int phys = (2 * j + (quad >> 1)) ^ (qrow & 7);
        *(ushort4*)&Ps[g][qrow][phys * 8 + 4 * (quad & 1)] = pk;
      }
      // rescale O rows (q-local = 4quad+r) by that q's sc
#pragma unroll
      for (int r = 0; r < 4; r++) {
        float scr = __shfl(sc, 16 * quad + 4 * quad + r);
#pragma unroll
        for (int jd = 0; jd < 4; jd++) oacc[jd][r] *= scr;
      }
      __asm__ volatile("s_waitcnt lgkmcnt(0)" ::: "memory");
      // O += P.V
#pragma unroll
      for (int ks = 0; ks < 2; ks++) {
        short8 ap = *(const short8*)&Ps[g][qrow][8 * ((quad + 4 * ks) ^ (qrow & 7))];
#pragma unroll
        for (int jd = 0; jd < 4; jd++) {
          int vrow = 16 * jd + cc;
          short8 bv = *(const short8*)&Vt[vrow][8 * ((quad + 4 * ks) ^ (vrow & 7))];
          oacc[jd] = __builtin_amdgcn_mfma_f32_16x16x32_bf16(ap, bv, oacc[jd], 0, 0, 0);
        }
      }
    }
  }

  // epilogue: q = myqt*64 + 16w + 4quad + r, d = 16jd + cc
#pragma unroll
  for (int r = 0; r < 4; r++) {
    float lr = __shfl(l, 16 * quad + 4 * quad + r);
    int q = myqt * 64 + 16 * w + 4 * quad + r;
    float scale;
    size_t row;
    if (MOSA) {
      int trow = sel[bn * KSEL + q];
      scale = gates[bn * KSEL + q] / lr;
      row = (size_t)(b * SEQ + trow);
    } else {
      scale = 1.f / lr;
      row = (size_t)(b * SEQ + q);
    }
    ushort* orow = outp + row * (NHEAD * DH) + n * DH;
#pragma unroll
    for (int jd = 0; jd < 4; jd++)
      orow[16 * jd + cc] = bf16u(oacc[jd][r] * scale);
  }
}

// ---------------- bf16 MFMA GEMM, 128x128 tile, BK=32 ----------------
// MODE 0: out f32 = A1@B1 + A2@B2.  MODE 1: dense-qkv scatter into Qg/Kg/Vtg.
template <int MODE>
__global__ __launch_bounds__(256) void gemm_bf16(
    const ushort* __restrict__ A1, const ushort* __restrict__ B1t, int K1,
    const ushort* __restrict__ A2, const ushort* __restrict__ B2t, int K2,
    void* __restrict__ outv, int N,
    ushort* __restrict__ Qo, ushort* __restrict__ Ko, ushort* __restrict__ Vto) {
  __shared__ __align__(16) ushort As[128][32];
  __shared__ __align__(16) ushort Bs[128][32];
  int m0 = blockIdx.x * 128, n0 = blockIdx.y * 128;
  int tid = threadIdx.x;
  int lane = tid & 63, wave = tid >> 6;
  int wm = wave & 1, wn = wave >> 1;
  int cc = lane & 15, quad = lane >> 4;
  int sr = tid >> 2, sc = tid & 3;

  f32x4 acc[4][4];
#pragma unroll
  for (int i = 0; i < 4; i++)
#pragma unroll
    for (int j = 0; j < 4; j++)
#pragma unroll
      for (int r = 0; r < 4; r++) acc[i][j][r] = 0.f;

  const int npass = (MODE == 0) ? 2 : 1;
  for (int pass = 0; pass < npass; pass++) {
    const ushort* A = pass ? A2 : A1;
    const ushort* Bt = pass ? B2t : B1t;
    int K = pass ? K2 : K1;
    for (int k0 = 0; k0 < K; k0 += 32) {
      __syncthreads();
      {
        short8 a0 = *(const short8*)(A + (size_t)(m0 + sr) * K + k0 + 8 * sc);
        short8 a1 = *(const short8*)(A + (size_t)(m0 + sr + 64) * K + k0 + 8 * sc);
        short8 b0 = *(const short8*)(Bt + (size_t)(n0 + sr) * K + k0 + 8 * sc);
        short8 b1 = *(const short8*)(Bt + (size_t)(n0 + sr + 64) * K + k0 + 8 * sc);
        *(short8*)&As[sr][8 * ((sc + (sr >> 1)) & 3)] = a0;
        *(short8*)&As[sr + 64][8 * ((sc + ((sr + 64) >> 1)) & 3)] = a1;
        *(short8*)&Bs[sr][8 * ((sc + (sr >> 1)) & 3)] = b0;
        *(short8*)&Bs[sr + 64][8 * ((sc + ((sr + 64) >> 1)) & 3)] = b1;
      }
      __syncthreads();
      short8 af[4], bfr[4];
#pragma unroll
      for (int i = 0; i < 4; i++) {
        int ra = 64 * wm + 16 * i + cc;
        af[i] = *(const short8*)&As[ra][8 * ((quad + (ra >> 1)) & 3)];
      }
#pragma unroll
      for (int j = 0; j < 4; j++) {
        int rb = 64 * wn + 16 * j + cc;
        bfr[j] = *(const short8*)&Bs[rb][8 * ((quad + (rb >> 1)) & 3)];
      }
#pragma unroll
      for (int i = 0; i < 4; i++)
#pragma unroll
        for (int j = 0; j < 4; j++)
          acc[i][j] = __builtin_amdgcn_mfma_f32_16x16x32_bf16(af[i], bfr[j], acc[i][j], 0, 0, 0);
    }
  }

#pragma unroll
  for (int i = 0; i < 4; i++) {
#pragma unroll
    for (int j = 0; j < 4; j++) {
      int colg = n0 + 64 * wn + 16 * j + cc;
      int row0 = m0 + 64 * wm + 16 * i + 4 * quad;
      if (MODE == 0) {
#pragma unroll
        for (int r = 0; r < 4; r++)
          ((float*)outv)[(size_t)(row0 + r) * N + colg] = acc[i][j][r];
      } else {
        int nn = colg / 192, c = colg % 192;     // uniform across lanes per j
        int b2 = row0 >> 11, t2 = row0 & 2047;
        int bn2 = b2 * 8 + nn;
        if (c < 64) {
#pragma unroll
          for (int r = 0; r < 4; r++)
            Qo[((size_t)bn2 * SEQ + t2 + r) * 64 + c] = bf16u(acc[i][j][r] * 0.125f);
        } else if (c < 128) {
#pragma unroll
          for (int r = 0; r < 4; r++)
            Ko[((size_t)bn2 * SEQ + t2 + r) * 64 + (c - 64)] = bf16u(acc[i][j][r]);
        } else {
          ushort4 pk;
          pk.x = bf16u(acc[i][j][0]); pk.y = bf16u(acc[i][j][1]);
          pk.z = bf16u(acc[i][j][2]); pk.w = bf16u(acc[i][j][3]);
          *(ushort4*)&Vto[((size_t)bn2 * 64 + (c - 128)) * SEQ + t2] = pk;
        }
      }
    }
  }
}

extern "C" void kernel_launch(void* const* d_in, const int* in_sizes, int n_in,
                              void* d_out, int out_size, void* d_ws, size_t ws_size,
                              hipStream_t stream) {
  const float* X          = (const float*)d_in[0];
  const float* router_w   = (const float*)d_in[1];
  const float* mosa_wqkv  = (const float*)d_in[2];
  const float* mosa_wo    = (const float*)d_in[3];
  const float* dense_wqkv = (const float*)d_in[4];
  const float* dense_wo   = (const float*)d_in[5];
  float* out = (float*)d_out;
  char* ws = (char*)d_ws;

  // workspace layout (bytes)
  float*  scores  = (float*) (ws + 0);          // 131072
  int*    sel     = (int*)   (ws + 131072);     // 16384
  float*  gates   = (float*) (ws + 147456);     // 16384
  ushort* avm     = (ushort*)(ws + 163840);     // 4194304
  ushort* avd     = (ushort*)(ws + 4358144);    // 4194304
  ushort* Xb      = (ushort*)(ws + 8552448);    // 8388608
  ushort* Wqkv_t  = (ushort*)(ws + 16941056);   // 3145728
  ushort* Wmq_t   = (ushort*)(ws + 20086784);   // 3145728
  ushort* Wdo_t   = (ushort*)(ws + 23232512);   // 1048576
  ushort* Wmo_t   = (ushort*)(ws + 24281088);   // 1048576
  int*    pranks  = (int*)   (ws + 25329664);   // 2097152
  ushort* Qg      = (ushort*)(ws + 27426816);   // 4194304  (16 bn x 2048 x 64)
  ushort* Kg      = (ushort*)(ws + 31621120);   // 4194304
  ushort* Vtg     = (ushort*)(ws + 35815424);   // 4194304  (16 bn x 64 x 2048)
  ushort* Qmg     = (ushort*)(ws + 40009728);   // 524288   (16 bn x 256 x 64)
  ushort* Kmg     = (ushort*)(ws + 40534016);   // 524288
  ushort* Vtmg    = (ushort*)(ws + 41058304);   // 524288   (end 41582592)

  hipMemsetAsync(avm, 0, (size_t)BB * SEQ * NHEAD * DH * sizeof(ushort), stream);

  // casts / transposes
  cast_bf16x4<<<4096, 256, 0, stream>>>(X, Xb, BB * SEQ * HD / 4);
  transpose_cast2<<<dim3(48, 32, 2), 256, 0, stream>>>(dense_wqkv, Wqkv_t,
                                                       mosa_wqkv, Wmq_t, 1024, 1536);
  transpose_cast2<<<dim3(32, 16, 2), 256, 0, stream>>>(dense_wo, Wdo_t,
                                                       mosa_wo, Wmo_t, 512, 1024);

  // router + top-k
  router_kernel<<<BB * SEQ, 256, 0, stream>>>(X, router_w, scores);
  topk_partial<<<dim3(BB * NHEAD, 16), 256, 0, stream>>>(scores, pranks);
  topk_select<<<BB * NHEAD, 1024, 0, stream>>>(scores, pranks, sel, gates);

  // mosa branch
  gemm_mosa_bf16<<<dim3(BB * NHEAD, KSEL / 64, D3 / 64), 256, 0, stream>>>(
      Xb, Wmq_t, sel, Qmg, Kmg, Vtmg);
  rope_split<<<(BB * NHEAD * KSEL * 32) / 256, 256, 0, stream>>>(Qmg, Kmg, sel, 1);
  flash4<true><<<dim3((KSEL / 64) / 2, BB * NHEAD), 512, 0, stream>>>(
      Qmg, Kmg, Vtmg, sel, gates, avm, KSEL / 64);

  // dense branch
  gemm_bf16<1><<<dim3(32, 12), 256, 0, stream>>>(Xb, Wqkv_t, 1024,
      (const ushort*)nullptr, (const ushort*)nullptr, 0, nullptr, NHEAD * D3,
      Qg, Kg, Vtg);
  rope_split<<<(BB * NHEAD * SEQ * 32) / 256, 256, 0, stream>>>(Qg, Kg, nullptr, 0);
  flash4<false><<<dim3((SEQ / 64) / 2, BB * NHEAD), 512, 0, stream>>>(
      Qg, Kg, Vtg, (const int*)nullptr, (const float*)nullptr, avd, SEQ / 64);

  // final: out = avm@mosa_wo + avd@dense_wo  (f32 out)
  gemm_bf16<0><<<dim3(32, 8), 256, 0, stream>>>(avm, Wmo_t, 512, avd, Wdo_t, 512, out, HD,
                                                nullptr, nullptr, nullptr);
}

// Round 7
// 280.099 us; speedup vs baseline: 5.9184x; 1.1585x over previous
//
#include <hip/hip_runtime.h>
#include <math.h>

constexpr int BB = 2;
constexpr int SEQ = 2048;
constexpr int HD = 1024;
constexpr int DH = 64;       // head dim
constexpr int NHEAD = 8;
constexpr int D3 = 192;      // 3*DH
constexpr int KSEL = 256;    // SEQ / SPARSITY
constexpr float NEG = -1e30f;

typedef short short8 __attribute__((ext_vector_type(8)));
typedef float f32x4 __attribute__((ext_vector_type(4)));

__device__ __forceinline__ ushort bf16u(float f) {
  union { float f; unsigned u; } v; v.f = f;
  unsigned r = (v.u + 0x7FFFu + ((v.u >> 16) & 1u)) >> 16;
  return (ushort)r;
}
__device__ __forceinline__ float bf2f(ushort h) {
  union { unsigned u; float f; } v; v.u = ((unsigned)h) << 16;
  return v.f;
}

// ---------------- cast f32 -> bf16, 4 elems/thread ----------------
__global__ void cast_bf16x4(const float* __restrict__ x, ushort* __restrict__ y, int n4) {
  int i = blockIdx.x * 256 + threadIdx.x;
  if (i >= n4) return;
  float4 v = ((const float4*)x)[i];
  ushort4 r; r.x = bf16u(v.x); r.y = bf16u(v.y); r.z = bf16u(v.z); r.w = bf16u(v.w);
  ((ushort4*)y)[i] = r;
}

// ---------------- transpose + cast pair: W[K][N] f32 -> Wt[N][K] bf16 ----------------
__global__ __launch_bounds__(256) void transpose_cast2(
    const float* __restrict__ W1, ushort* __restrict__ T1,
    const float* __restrict__ W2, ushort* __restrict__ T2, int K, int N) {
  const float* W = blockIdx.z ? W2 : W1;
  ushort* Wt = blockIdx.z ? T2 : T1;
  __shared__ float tile[32][33];
  int n0 = blockIdx.x * 32, k0 = blockIdx.y * 32;
  int tx = threadIdx.x & 31, ty = threadIdx.x >> 5;
#pragma unroll
  for (int i = 0; i < 4; i++)
    tile[ty + 8 * i][tx] = W[(size_t)(k0 + ty + 8 * i) * N + n0 + tx];
  __syncthreads();
#pragma unroll
  for (int i = 0; i < 4; i++)
    Wt[(size_t)(n0 + ty + 8 * i) * K + k0 + tx] = bf16u(tile[tx][ty + 8 * i]);
}

// ---------------- router v2: register-blocked, 32 rows/block ----------------
// scores[b][n][t] = X[b,t,:] . rw[:,n]; rw staged transposed+seg-padded in LDS.
__global__ __launch_bounds__(256) void router2(const float* __restrict__ X,
    const float* __restrict__ rw, float* __restrict__ scores) {
  __shared__ float rwT[8][8][132];          // [n][seg][128+4pad]
  int tid = threadIdx.x;
  // stage: idx -> h = idx&1023, n = idx>>10 (conflict-free LDS writes)
  for (int idx = tid; idx < 8192; idx += 256) {
    int h = idx & 1023, n = idx >> 10;
    rwT[n][h >> 7][h & 127] = rw[h * 8 + n];
  }
  __syncthreads();
  int row = blockIdx.x * 32 + (tid >> 3);   // bt row
  int seg = tid & 7;
  const float* xrow = X + (size_t)row * HD + seg * 128;
  float acc[8] = {};
#pragma unroll 8
  for (int it = 0; it < 32; it++) {
    float4 xv = *(const float4*)(xrow + 4 * it);
#pragma unroll
    for (int n = 0; n < 8; n++) {
      float4 rv = *(const float4*)&rwT[n][seg][4 * it];
      acc[n] += xv.x * rv.x + xv.y * rv.y + xv.z * rv.z + xv.w * rv.w;
    }
  }
#pragma unroll
  for (int n = 0; n < 8; n++) {
    acc[n] += __shfl_xor(acc[n], 1);
    acc[n] += __shfl_xor(acc[n], 2);
    acc[n] += __shfl_xor(acc[n], 4);
  }
  int b = row >> 11, t2 = row & (SEQ - 1);
  scores[((size_t)b * NHEAD + seg) * SEQ + t2] = acc[seg];
}

// ---------------- top-k stage 1: partial rank counts ----------------
__global__ __launch_bounds__(256) void topk_partial(const float* __restrict__ scores,
    int* __restrict__ pranks) {
  int row = blockIdx.x;
  int c = blockIdx.y;
  __shared__ float chunk[128];
  const float* sp = scores + (size_t)row * SEQ;
  if (threadIdx.x < 128) chunk[threadIdx.x] = sp[c * 128 + threadIdx.x];
  __syncthreads();
  int t = threadIdx.x;
  float v[8]; int vi[8]; int p[8];
#pragma unroll
  for (int i = 0; i < 8; i++) { vi[i] = i * 256 + t; v[i] = sp[vi[i]]; p[i] = 0; }
  int jbase = c * 128;
#pragma unroll 4
  for (int j4 = 0; j4 < 128; j4 += 4) {
    float4 s4 = *(const float4*)&chunk[j4];
    float ss[4] = {s4.x, s4.y, s4.z, s4.w};
#pragma unroll
    for (int jj = 0; jj < 4; jj++) {
      float sj = ss[jj];
      int jg = jbase + j4 + jj;
#pragma unroll
      for (int i = 0; i < 8; i++)
        p[i] += (sj > v[i]) || (sj == v[i] && jg < vi[i]);
    }
  }
#pragma unroll
  for (int i = 0; i < 8; i++)
    pranks[((size_t)row * 16 + c) * SEQ + vi[i]] = p[i];
}

// ---------------- top-k stage 2 ----------------
__global__ __launch_bounds__(1024) void topk_select(const float* __restrict__ scores,
    const int* __restrict__ pranks, int* __restrict__ sel, float* __restrict__ gates) {
  int bn = blockIdx.x;
  __shared__ int psum[1024];
  int t0 = threadIdx.x * 2;
  int r0 = 0, r1 = 0;
#pragma unroll
  for (int c = 0; c < 16; c++) {
    const int* pr = pranks + ((size_t)bn * 16 + c) * SEQ;
    r0 += pr[t0];
    r1 += pr[t0 + 1];
  }
  float v0 = scores[(size_t)bn * SEQ + t0];
  float v1 = scores[(size_t)bn * SEQ + t0 + 1];
  int f0 = r0 < KSEL, f1 = r1 < KSEL;
  psum[threadIdx.x] = f0 + f1;
  __syncthreads();
  for (int off = 1; off < 1024; off <<= 1) {
    int val = psum[threadIdx.x];
    int add = (threadIdx.x >= off) ? psum[threadIdx.x - off] : 0;
    __syncthreads();
    psum[threadIdx.x] = val + add;
    __syncthreads();
  }
  int base = psum[threadIdx.x] - (f0 + f1);
  if (f0) { sel[bn * KSEL + base] = t0;
            gates[bn * KSEL + base] = 1.f / (1.f + __expf(-v0)); base++; }
  if (f1) { sel[bn * KSEL + base] = t0 + 1;
            gates[bn * KSEL + base] = 1.f / (1.f + __expf(-v1)); }
}

// ---------------- mosa qkv: gathered-A bf16 MFMA GEMM -> split Q/K/V^T layouts ----------
__global__ __launch_bounds__(256) void gemm_mosa_bf16(const ushort* __restrict__ Xb,
    const ushort* __restrict__ Wt, const int* __restrict__ sel,
    ushort* __restrict__ Qmg, ushort* __restrict__ Kmg, ushort* __restrict__ Vtmg) {
  __shared__ __align__(16) ushort As[64][40];
  __shared__ __align__(16) ushort Bs[64][40];
  int bn = blockIdx.x; int b = bn >> 3, n = bn & 7;
  int m0 = blockIdx.y * 64, n0 = blockIdx.z * 64;
  int tid = threadIdx.x;
  int lane = tid & 63, w = tid >> 6;
  int wm = w & 1, wn = w >> 1;
  int cc = lane & 15, quad = lane >> 4;
  int sr = tid >> 2, sc4 = tid & 3;

  int grow = sel[bn * KSEL + m0 + sr];
  const ushort* arow = Xb + ((size_t)(b * SEQ) + grow) * HD;
  const ushort* brow = Wt + ((size_t)(n * D3 + n0 + sr)) * HD;

  f32x4 acc[2][2];
#pragma unroll
  for (int i = 0; i < 2; i++)
#pragma unroll
    for (int j = 0; j < 2; j++)
#pragma unroll
      for (int r = 0; r < 4; r++) acc[i][j][r] = 0.f;

  for (int k0 = 0; k0 < HD; k0 += 32) {
    __syncthreads();
    *(short8*)&As[sr][8 * sc4] = *(const short8*)(arow + k0 + 8 * sc4);
    *(short8*)&Bs[sr][8 * sc4] = *(const short8*)(brow + k0 + 8 * sc4);
    __syncthreads();
    short8 af[2], bf_[2];
#pragma unroll
    for (int i = 0; i < 2; i++) af[i] = *(const short8*)&As[32 * wm + 16 * i + cc][8 * quad];
#pragma unroll
    for (int j = 0; j < 2; j++) bf_[j] = *(const short8*)&Bs[32 * wn + 16 * j + cc][8 * quad];
#pragma unroll
    for (int i = 0; i < 2; i++)
#pragma unroll
      for (int j = 0; j < 2; j++)
        acc[i][j] = __builtin_amdgcn_mfma_f32_16x16x32_bf16(af[i], bf_[j], acc[i][j], 0, 0, 0);
  }

#pragma unroll
  for (int i = 0; i < 2; i++)
#pragma unroll
    for (int j = 0; j < 2; j++) {
      int col = n0 + 32 * wn + 16 * j + cc;   // 0..191, segment = n0 (uniform)
      int row0 = m0 + 32 * wm + 16 * i + 4 * quad;
      if (col < 64) {
#pragma unroll
        for (int r = 0; r < 4; r++)
          Qmg[((size_t)bn * KSEL + row0 + r) * 64 + col] = bf16u(acc[i][j][r] * 0.125f);
      } else if (col < 128) {
#pragma unroll
        for (int r = 0; r < 4; r++)
          Kmg[((size_t)bn * KSEL + row0 + r) * 64 + (col - 64)] = bf16u(acc[i][j][r]);
      } else {
        ushort4 pk;
        pk.x = bf16u(acc[i][j][0]); pk.y = bf16u(acc[i][j][1]);
        pk.z = bf16u(acc[i][j][2]); pk.w = bf16u(acc[i][j][3]);
        *(ushort4*)&Vtmg[((size_t)bn * 64 + (col - 128)) * KSEL + row0] = pk;
      }
    }
}

// ---------------- RoPE on split Q/K layouts (rows of 64) ----------------
__global__ void rope_split(ushort* __restrict__ Qb, ushort* __restrict__ Kb,
                           const int* __restrict__ sel, int mosa) {
  int tid = blockIdx.x * 256 + threadIdx.x;
  int j = tid & 15;
  int which = (tid >> 4) & 1;                 // 0: Q, 1: K
  int row = tid >> 5;
  float pos = mosa ? (float)sel[row] : (float)(row & (SEQ - 1));
  float inv = __expf((float)j * -0.5756462732485115f);
  float ang = pos * inv;
  float c = cosf(ang), sn = sinf(ang);
  ushort* p = (which ? Kb : Qb) + (size_t)row * 64 + j;
  float x1 = bf2f(p[0]), x2 = bf2f(p[16]);
  p[0] = bf16u(x1 * c - x2 * sn);
  p[16] = bf16u(x1 * sn + x2 * c);
}

// ---------------- flash4: paired q-tiles, shared K/V staging, S^T softmax ----------------
template <bool MOSA>
__global__ __launch_bounds__(512) void flash4(
    const ushort* __restrict__ Qg, const ushort* __restrict__ Kg,
    const ushort* __restrict__ Vtg, const int* __restrict__ sel,
    const float* __restrict__ gates, ushort* __restrict__ outp, int nqt) {
  __shared__ __align__(16) ushort Qs[2][64][64];
  __shared__ __align__(16) ushort Ks[64][64];
  __shared__ __align__(16) ushort Vt[64][64];
  __shared__ __align__(16) ushort Ps[2][64][64];

  const int T = MOSA ? KSEL : SEQ;
  int bn = blockIdx.y; int b = bn >> 3, n = bn & 7;
  int pair = blockIdx.x;
  int qtA = pair, qtB = nqt - 1 - pair;
  int tid = threadIdx.x;
  int g = tid >> 8;
  int myqt = g ? qtB : qtA;
  int t = tid & 255;
  int lane = tid & 63, w = (tid >> 6) & 3;
  int cc = lane & 15, quad = lane >> 4;

  const ushort* Qb = Qg + (size_t)bn * T * 64;
  const ushort* Kb = Kg + (size_t)bn * T * 64;
  const ushort* Vb = Vtg + (size_t)bn * 64 * T;

  // stage group's Q tile (2 b128/thread, swizzled)
  {
    int r = t >> 2, c = t & 3;
    const ushort* src = Qb + (size_t)(myqt * 64 + r) * 64;
    *(short8*)&Qs[g][r][8 * (c ^ (r & 7))] = *(const short8*)(src + 8 * c);
    int c2 = c + 4;
    *(short8*)&Qs[g][r][8 * (c2 ^ (r & 7))] = *(const short8*)(src + 8 * c2);
  }

  f32x4 oacc[4];
  float m = NEG, l = 0.f;
#pragma unroll
  for (int jd = 0; jd < 4; jd++)
#pragma unroll
    for (int r = 0; r < 4; r++) oacc[jd][r] = 0.f;

  for (int kt = 0; kt <= qtB; kt++) {
    __syncthreads();
    {
      int r = tid >> 3, c = tid & 7;
      *(short8*)&Ks[r][8 * (c ^ (r & 7))] =
          *(const short8*)(Kb + (size_t)(kt * 64 + r) * 64 + 8 * c);
      *(short8*)&Vt[r][8 * (c ^ (r & 7))] =
          *(const short8*)(Vb + (size_t)r * T + kt * 64 + 8 * c);
    }
    __syncthreads();

    if (g || (kt <= qtA)) {
      // S^T = K.Q^T : C col = q (cc), row = key (16j + 4quad + r)
      f32x4 sacc[4];
#pragma unroll
      for (int j = 0; j < 4; j++)
#pragma unroll
        for (int r = 0; r < 4; r++) sacc[j][r] = 0.f;
      int qrow = 16 * w + cc;
#pragma unroll
      for (int ks = 0; ks < 2; ks++) {
        short8 bq = *(const short8*)&Qs[g][qrow][8 * ((quad + 4 * ks) ^ (qrow & 7))];
#pragma unroll
        for (int j = 0; j < 4; j++) {
          int krow = 16 * j + cc;
          short8 ak = *(const short8*)&Ks[krow][8 * ((quad + 4 * ks) ^ (krow & 7))];
          sacc[j] = __builtin_amdgcn_mfma_f32_16x16x32_bf16(ak, bq, sacc[j], 0, 0, 0);
        }
      }
      if (kt == myqt) {
#pragma unroll
        for (int j = 0; j < 4; j++)
#pragma unroll
          for (int r = 0; r < 4; r++)
            if (16 * j + 4 * quad + r > 16 * w + cc) sacc[j][r] = NEG;
      }
      // per-lane online softmax (q = 16w+cc fixed per lane)
      float mx = NEG;
#pragma unroll
      for (int j = 0; j < 4; j++)
#pragma unroll
        for (int r = 0; r < 4; r++) mx = fmaxf(mx, sacc[j][r]);
      mx = fmaxf(mx, __shfl_xor(mx, 16));
      mx = fmaxf(mx, __shfl_xor(mx, 32));
      float mn = fmaxf(m, mx);
      float sc = __expf(m - mn);
      m = mn;
      float rsum = 0.f;
      float p[4][4];
#pragma unroll
      for (int j = 0; j < 4; j++)
#pragma unroll
        for (int r = 0; r < 4; r++) { p[j][r] = __expf(sacc[j][r] - mn); rsum += p[j][r]; }
      rsum += __shfl_xor(rsum, 16);
      rsum += __shfl_xor(rsum, 32);
      l = l * sc + rsum;
      // Ps[q][key] packed b64 (wave-local rows)
#pragma unroll
      for (int j = 0; j < 4; j++) {
        ushort4 pk;
        pk.x = bf16u(p[j][0]); pk.y = bf16u(p[j][1]);
        pk.z = bf16u(p[j][2]); pk.w = bf16u(p[j][3]);
        int phys = (2 * j + (quad >> 1)) ^ (qrow & 7);
        *(ushort4*)&Ps[g][qrow][phys * 8 + 4 * (quad & 1)] = pk;
      }
      // rescale O rows (q-local = 4quad+r) by that q's sc
#pragma unroll
      for (int r = 0; r < 4; r++) {
        float scr = __shfl(sc, 16 * quad + 4 * quad + r);
#pragma unroll
        for (int jd = 0; jd < 4; jd++) oacc[jd][r] *= scr;
      }
      __asm__ volatile("s_waitcnt lgkmcnt(0)" ::: "memory");
      // O += P.V
#pragma unroll
      for (int ks = 0; ks < 2; ks++) {
        short8 ap = *(const short8*)&Ps[g][qrow][8 * ((quad + 4 * ks) ^ (qrow & 7))];
#pragma unroll
        for (int jd = 0; jd < 4; jd++) {
          int vrow = 16 * jd + cc;
          short8 bv = *(const short8*)&Vt[vrow][8 * ((quad + 4 * ks) ^ (vrow & 7))];
          oacc[jd] = __builtin_amdgcn_mfma_f32_16x16x32_bf16(ap, bv, oacc[jd], 0, 0, 0);
        }
      }
    }
  }

  // epilogue: q = myqt*64 + 16w + 4quad + r, d = 16jd + cc
#pragma unroll
  for (int r = 0; r < 4; r++) {
    float lr = __shfl(l, 16 * quad + 4 * quad + r);
    int q = myqt * 64 + 16 * w + 4 * quad + r;
    float scale;
    size_t row;
    if (MOSA) {
      int trow = sel[bn * KSEL + q];
      scale = gates[bn * KSEL + q] / lr;
      row = (size_t)(b * SEQ + trow);
    } else {
      scale = 1.f / lr;
      row = (size_t)(b * SEQ + q);
    }
    ushort* orow = outp + row * (NHEAD * DH) + n * DH;
#pragma unroll
    for (int jd = 0; jd < 4; jd++)
      orow[16 * jd + cc] = bf16u(oacc[jd][r] * scale);
  }
}

// ---------------- bf16 MFMA GEMM, 128x128 tile, BK=32 ----------------
// MODE 0: out f32 = A1@B1 + A2@B2.  MODE 1: dense-qkv scatter into Qg/Kg/Vtg.
template <int MODE>
__global__ __launch_bounds__(256) void gemm_bf16(
    const ushort* __restrict__ A1, const ushort* __restrict__ B1t, int K1,
    const ushort* __restrict__ A2, const ushort* __restrict__ B2t, int K2,
    void* __restrict__ outv, int N,
    ushort* __restrict__ Qo, ushort* __restrict__ Ko, ushort* __restrict__ Vto) {
  __shared__ __align__(16) ushort As[128][32];
  __shared__ __align__(16) ushort Bs[128][32];
  int m0 = blockIdx.x * 128, n0 = blockIdx.y * 128;
  int tid = threadIdx.x;
  int lane = tid & 63, wave = tid >> 6;
  int wm = wave & 1, wn = wave >> 1;
  int cc = lane & 15, quad = lane >> 4;
  int sr = tid >> 2, sc = tid & 3;

  f32x4 acc[4][4];
#pragma unroll
  for (int i = 0; i < 4; i++)
#pragma unroll
    for (int j = 0; j < 4; j++)
#pragma unroll
      for (int r = 0; r < 4; r++) acc[i][j][r] = 0.f;

  const int npass = (MODE == 0) ? 2 : 1;
  for (int pass = 0; pass < npass; pass++) {
    const ushort* A = pass ? A2 : A1;
    const ushort* Bt = pass ? B2t : B1t;
    int K = pass ? K2 : K1;
    for (int k0 = 0; k0 < K; k0 += 32) {
      __syncthreads();
      {
        short8 a0 = *(const short8*)(A + (size_t)(m0 + sr) * K + k0 + 8 * sc);
        short8 a1 = *(const short8*)(A + (size_t)(m0 + sr + 64) * K + k0 + 8 * sc);
        short8 b0 = *(const short8*)(Bt + (size_t)(n0 + sr) * K + k0 + 8 * sc);
        short8 b1 = *(const short8*)(Bt + (size_t)(n0 + sr + 64) * K + k0 + 8 * sc);
        *(short8*)&As[sr][8 * ((sc + (sr >> 1)) & 3)] = a0;
        *(short8*)&As[sr + 64][8 * ((sc + ((sr + 64) >> 1)) & 3)] = a1;
        *(short8*)&Bs[sr][8 * ((sc + (sr >> 1)) & 3)] = b0;
        *(short8*)&Bs[sr + 64][8 * ((sc + ((sr + 64) >> 1)) & 3)] = b1;
      }
      __syncthreads();
      short8 af[4], bfr[4];
#pragma unroll
      for (int i = 0; i < 4; i++) {
        int ra = 64 * wm + 16 * i + cc;
        af[i] = *(const short8*)&As[ra][8 * ((quad + (ra >> 1)) & 3)];
      }
#pragma unroll
      for (int j = 0; j < 4; j++) {
        int rb = 64 * wn + 16 * j + cc;
        bfr[j] = *(const short8*)&Bs[rb][8 * ((quad + (rb >> 1)) & 3)];
      }
#pragma unroll
      for (int i = 0; i < 4; i++)
#pragma unroll
        for (int j = 0; j < 4; j++)
          acc[i][j] = __builtin_amdgcn_mfma_f32_16x16x32_bf16(af[i], bfr[j], acc[i][j], 0, 0, 0);
    }
  }

#pragma unroll
  for (int i = 0; i < 4; i++) {
#pragma unroll
    for (int j = 0; j < 4; j++) {
      int colg = n0 + 64 * wn + 16 * j + cc;
      int row0 = m0 + 64 * wm + 16 * i + 4 * quad;
      if (MODE == 0) {
#pragma unroll
        for (int r = 0; r < 4; r++)
          ((float*)outv)[(size_t)(row0 + r) * N + colg] = acc[i][j][r];
      } else {
        int nn = colg / 192, c = colg % 192;     // uniform across lanes per j
        int b2 = row0 >> 11, t2 = row0 & 2047;
        int bn2 = b2 * 8 + nn;
        if (c < 64) {
#pragma unroll
          for (int r = 0; r < 4; r++)
            Qo[((size_t)bn2 * SEQ + t2 + r) * 64 + c] = bf16u(acc[i][j][r] * 0.125f);
        } else if (c < 128) {
#pragma unroll
          for (int r = 0; r < 4; r++)
            Ko[((size_t)bn2 * SEQ + t2 + r) * 64 + (c - 64)] = bf16u(acc[i][j][r]);
        } else {
          ushort4 pk;
          pk.x = bf16u(acc[i][j][0]); pk.y = bf16u(acc[i][j][1]);
          pk.z = bf16u(acc[i][j][2]); pk.w = bf16u(acc[i][j][3]);
          *(ushort4*)&Vto[((size_t)bn2 * 64 + (c - 128)) * SEQ + t2] = pk;
        }
      }
    }
  }
}

extern "C" void kernel_launch(void* const* d_in, const int* in_sizes, int n_in,
                              void* d_out, int out_size, void* d_ws, size_t ws_size,
                              hipStream_t stream) {
  const float* X          = (const float*)d_in[0];
  const float* router_w   = (const float*)d_in[1];
  const float* mosa_wqkv  = (const float*)d_in[2];
  const float* mosa_wo    = (const float*)d_in[3];
  const float* dense_wqkv = (const float*)d_in[4];
  const float* dense_wo   = (const float*)d_in[5];
  float* out = (float*)d_out;
  char* ws = (char*)d_ws;

  // workspace layout (bytes)
  float*  scores  = (float*) (ws + 0);          // 131072
  int*    sel     = (int*)   (ws + 131072);     // 16384
  float*  gates   = (float*) (ws + 147456);     // 16384
  ushort* avm     = (ushort*)(ws + 163840);     // 4194304
  ushort* avd     = (ushort*)(ws + 4358144);    // 4194304
  ushort* Xb      = (ushort*)(ws + 8552448);    // 8388608
  ushort* Wqkv_t  = (ushort*)(ws + 16941056);   // 3145728
  ushort* Wmq_t   = (ushort*)(ws + 20086784);   // 3145728
  ushort* Wdo_t   = (ushort*)(ws + 23232512);   // 1048576
  ushort* Wmo_t   = (ushort*)(ws + 24281088);   // 1048576
  int*    pranks  = (int*)   (ws + 25329664);   // 2097152
  ushort* Qg      = (ushort*)(ws + 27426816);   // 4194304  (16 bn x 2048 x 64)
  ushort* Kg      = (ushort*)(ws + 31621120);   // 4194304
  ushort* Vtg     = (ushort*)(ws + 35815424);   // 4194304  (16 bn x 64 x 2048)
  ushort* Qmg     = (ushort*)(ws + 40009728);   // 524288   (16 bn x 256 x 64)
  ushort* Kmg     = (ushort*)(ws + 40534016);   // 524288
  ushort* Vtmg    = (ushort*)(ws + 41058304);   // 524288   (end 41582592)

  hipMemsetAsync(avm, 0, (size_t)BB * SEQ * NHEAD * DH * sizeof(ushort), stream);

  // casts / transposes
  cast_bf16x4<<<4096, 256, 0, stream>>>(X, Xb, BB * SEQ * HD / 4);
  transpose_cast2<<<dim3(48, 32, 2), 256, 0, stream>>>(dense_wqkv, Wqkv_t,
                                                       mosa_wqkv, Wmq_t, 1024, 1536);
  transpose_cast2<<<dim3(32, 16, 2), 256, 0, stream>>>(dense_wo, Wdo_t,
                                                       mosa_wo, Wmo_t, 512, 1024);

  // router + top-k
  router2<<<BB * SEQ / 32, 256, 0, stream>>>(X, router_w, scores);
  topk_partial<<<dim3(BB * NHEAD, 16), 256, 0, stream>>>(scores, pranks);
  topk_select<<<BB * NHEAD, 1024, 0, stream>>>(scores, pranks, sel, gates);

  // mosa branch
  gemm_mosa_bf16<<<dim3(BB * NHEAD, KSEL / 64, D3 / 64), 256, 0, stream>>>(
      Xb, Wmq_t, sel, Qmg, Kmg, Vtmg);
  rope_split<<<(BB * NHEAD * KSEL * 32) / 256, 256, 0, stream>>>(Qmg, Kmg, sel, 1);
  flash4<true><<<dim3((KSEL / 64) / 2, BB * NHEAD), 512, 0, stream>>>(
      Qmg, Kmg, Vtmg, sel, gates, avm, KSEL / 64);

  // dense branch
  gemm_bf16<1><<<dim3(32, 12), 256, 0, stream>>>(Xb, Wqkv_t, 1024,
      (const ushort*)nullptr, (const ushort*)nullptr, 0, nullptr, NHEAD * D3,
      Qg, Kg, Vtg);
  rope_split<<<(BB * NHEAD * SEQ * 32) / 256, 256, 0, stream>>>(Qg, Kg, nullptr, 0);
  flash4<false><<<dim3((SEQ / 64) / 2, BB * NHEAD), 512, 0, stream>>>(
      Qg, Kg, Vtg, (const int*)nullptr, (const float*)nullptr, avd, SEQ / 64);

  // final: out = avm@mosa_wo + avd@dense_wo  (f32 out)
  gemm_bf16<0><<<dim3(32, 8), 256, 0, stream>>>(avm, Wmo_t, 512, avd, Wdo_t, 512, out, HD,
                                                nullptr, nullptr, nullptr);
}

// Round 8
// 246.709 us; speedup vs baseline: 6.7194x; 1.1353x over previous
//
#include <hip/hip_runtime.h>
#include <math.h>

constexpr int BB = 2;
constexpr int SEQ = 2048;
constexpr int HD = 1024;
constexpr int DH = 64;       // head dim
constexpr int NHEAD = 8;
constexpr int D3 = 192;      // 3*DH
constexpr int KSEL = 256;    // SEQ / SPARSITY
constexpr float NEG = -1e30f;

typedef short short8 __attribute__((ext_vector_type(8)));
typedef float f32x4 __attribute__((ext_vector_type(4)));

__device__ __forceinline__ ushort bf16u(float f) {
  union { float f; unsigned u; } v; v.f = f;
  unsigned r = (v.u + 0x7FFFu + ((v.u >> 16) & 1u)) >> 16;
  return (ushort)r;
}
__device__ __forceinline__ float bf2f(ushort h) {
  union { unsigned u; float f; } v; v.u = ((unsigned)h) << 16;
  return v.f;
}

// order-preserving composite key: rank predicate (s_j > s_i) || (s_j==s_i && j<i)
// becomes key_j > key_i  (single u64 compare)
__device__ __forceinline__ unsigned long long rankkey(float s, int idx) {
  union { float f; unsigned u; } v; v.f = s;
  unsigned o = (v.u & 0x80000000u) ? ~v.u : (v.u | 0x80000000u);
  return ((unsigned long long)o << 11) | (unsigned)(2047 - idx);
}

// ---------------- cast f32 -> bf16, 4 elems/thread ----------------
__global__ void cast_bf16x4(const float* __restrict__ x, ushort* __restrict__ y, int n4) {
  int i = blockIdx.x * 256 + threadIdx.x;
  if (i >= n4) return;
  float4 v = ((const float4*)x)[i];
  ushort4 r; r.x = bf16u(v.x); r.y = bf16u(v.y); r.z = bf16u(v.z); r.w = bf16u(v.w);
  ((ushort4*)y)[i] = r;
}

// ---------------- transpose + cast pair: W[K][N] f32 -> Wt[N][K] bf16 ----------------
__global__ __launch_bounds__(256) void transpose_cast2(
    const float* __restrict__ W1, ushort* __restrict__ T1,
    const float* __restrict__ W2, ushort* __restrict__ T2, int K, int N) {
  const float* W = blockIdx.z ? W2 : W1;
  ushort* Wt = blockIdx.z ? T2 : T1;
  __shared__ float tile[32][33];
  int n0 = blockIdx.x * 32, k0 = blockIdx.y * 32;
  int tx = threadIdx.x & 31, ty = threadIdx.x >> 5;
#pragma unroll
  for (int i = 0; i < 4; i++)
    tile[ty + 8 * i][tx] = W[(size_t)(k0 + ty + 8 * i) * N + n0 + tx];
  __syncthreads();
#pragma unroll
  for (int i = 0; i < 4; i++)
    Wt[(size_t)(n0 + ty + 8 * i) * K + k0 + tx] = bf16u(tile[tx][ty + 8 * i]);
}

// ---------------- router v2: register-blocked, 32 rows/block ----------------
__global__ __launch_bounds__(256) void router2(const float* __restrict__ X,
    const float* __restrict__ rw, float* __restrict__ scores) {
  __shared__ float rwT[8][8][132];          // [n][seg][128+4pad]
  int tid = threadIdx.x;
  for (int idx = tid; idx < 8192; idx += 256) {
    int h = idx & 1023, n = idx >> 10;
    rwT[n][h >> 7][h & 127] = rw[h * 8 + n];
  }
  __syncthreads();
  int row = blockIdx.x * 32 + (tid >> 3);   // bt row
  int seg = tid & 7;
  const float* xrow = X + (size_t)row * HD + seg * 128;
  float acc[8] = {};
#pragma unroll 8
  for (int it = 0; it < 32; it++) {
    float4 xv = *(const float4*)(xrow + 4 * it);
#pragma unroll
    for (int n = 0; n < 8; n++) {
      float4 rv = *(const float4*)&rwT[n][seg][4 * it];
      acc[n] += xv.x * rv.x + xv.y * rv.y + xv.z * rv.z + xv.w * rv.w;
    }
  }
#pragma unroll
  for (int n = 0; n < 8; n++) {
    acc[n] += __shfl_xor(acc[n], 1);
    acc[n] += __shfl_xor(acc[n], 2);
    acc[n] += __shfl_xor(acc[n], 4);
  }
  int b = row >> 11, t2 = row & (SEQ - 1);
  scores[((size_t)b * NHEAD + seg) * SEQ + t2] = acc[seg];
}

// ---------------- top-k stage 1: u64-key partial rank counts (32 chunks of 64) ----------
__global__ __launch_bounds__(256) void topk_partial(const float* __restrict__ scores,
    int* __restrict__ pranks) {
  int row = blockIdx.x;                      // 16
  int c = blockIdx.y;                        // 32 chunks of 64 j
  __shared__ unsigned long long ck[64];
  const float* sp = scores + (size_t)row * SEQ;
  int tid = threadIdx.x;
  if (tid < 64) ck[tid] = rankkey(sp[c * 64 + tid], c * 64 + tid);
  __syncthreads();
  unsigned long long kv[8]; int p[8];
#pragma unroll
  for (int i = 0; i < 8; i++) {
    int vi = i * 256 + tid;
    kv[i] = rankkey(sp[vi], vi);
    p[i] = 0;
  }
#pragma unroll 8
  for (int j = 0; j < 64; j += 2) {
    unsigned long long k0 = ck[j], k1 = ck[j + 1];
#pragma unroll
    for (int i = 0; i < 8; i++) {
      p[i] += (k0 > kv[i]);
      p[i] += (k1 > kv[i]);
    }
  }
#pragma unroll
  for (int i = 0; i < 8; i++)
    pranks[((size_t)row * 32 + c) * SEQ + i * 256 + tid] = p[i];
}

// ---------------- top-k stage 2: sum partials, ballot-scan, emit ----------------
__global__ __launch_bounds__(1024) void topk_select(const float* __restrict__ scores,
    const int* __restrict__ pranks, int* __restrict__ sel, float* __restrict__ gates) {
  int bn = blockIdx.x;
  __shared__ int wsum[16];
  int tid = threadIdx.x;
  int t0 = tid * 2;
  int r0 = 0, r1 = 0;
#pragma unroll
  for (int c = 0; c < 32; c++) {
    const int2 pp = *(const int2*)&pranks[((size_t)bn * 32 + c) * SEQ + t0];
    r0 += pp.x; r1 += pp.y;
  }
  int f0 = r0 < KSEL, f1 = r1 < KSEL;
  unsigned long long b0 = __ballot(f0), b1 = __ballot(f1);
  int lane = tid & 63, wv = tid >> 6;
  unsigned long long lower = (1ULL << lane) - 1ULL;
  int before = __popcll(b0 & lower) + __popcll(b1 & lower);
  int wtotal = __popcll(b0) + __popcll(b1);
  if (lane == 0) wsum[wv] = wtotal;
  __syncthreads();
  int woff = 0;
#pragma unroll
  for (int i2 = 0; i2 < 16; i2++) woff += (i2 < wv) ? wsum[i2] : 0;
  int base = woff + before;
  if (f0) { sel[bn * KSEL + base] = t0;
            gates[bn * KSEL + base] = 1.f / (1.f + __expf(-scores[(size_t)bn * SEQ + t0]));
            base++; }
  if (f1) { sel[bn * KSEL + base] = t0 + 1;
            gates[bn * KSEL + base] = 1.f / (1.f + __expf(-scores[(size_t)bn * SEQ + t0 + 1])); }
}

// ---------------- mosa qkv: gathered-A bf16 MFMA GEMM -> split Q/K/V^T layouts ----------
__global__ __launch_bounds__(256) void gemm_mosa_bf16(const ushort* __restrict__ Xb,
    const ushort* __restrict__ Wt, const int* __restrict__ sel,
    ushort* __restrict__ Qmg, ushort* __restrict__ Kmg, ushort* __restrict__ Vtmg) {
  __shared__ __align__(16) ushort As[64][40];
  __shared__ __align__(16) ushort Bs[64][40];
  int bn = blockIdx.x; int b = bn >> 3, n = bn & 7;
  int m0 = blockIdx.y * 64, n0 = blockIdx.z * 64;
  int tid = threadIdx.x;
  int lane = tid & 63, w = tid >> 6;
  int wm = w & 1, wn = w >> 1;
  int cc = lane & 15, quad = lane >> 4;
  int sr = tid >> 2, sc4 = tid & 3;

  int grow = sel[bn * KSEL + m0 + sr];
  const ushort* arow = Xb + ((size_t)(b * SEQ) + grow) * HD;
  const ushort* brow = Wt + ((size_t)(n * D3 + n0 + sr)) * HD;

  f32x4 acc[2][2];
#pragma unroll
  for (int i = 0; i < 2; i++)
#pragma unroll
    for (int j = 0; j < 2; j++)
#pragma unroll
      for (int r = 0; r < 4; r++) acc[i][j][r] = 0.f;

  for (int k0 = 0; k0 < HD; k0 += 32) {
    __syncthreads();
    *(short8*)&As[sr][8 * sc4] = *(const short8*)(arow + k0 + 8 * sc4);
    *(short8*)&Bs[sr][8 * sc4] = *(const short8*)(brow + k0 + 8 * sc4);
    __syncthreads();
    short8 af[2], bf_[2];
#pragma unroll
    for (int i = 0; i < 2; i++) af[i] = *(const short8*)&As[32 * wm + 16 * i + cc][8 * quad];
#pragma unroll
    for (int j = 0; j < 2; j++) bf_[j] = *(const short8*)&Bs[32 * wn + 16 * j + cc][8 * quad];
#pragma unroll
    for (int i = 0; i < 2; i++)
#pragma unroll
      for (int j = 0; j < 2; j++)
        acc[i][j] = __builtin_amdgcn_mfma_f32_16x16x32_bf16(af[i], bf_[j], acc[i][j], 0, 0, 0);
  }

#pragma unroll
  for (int i = 0; i < 2; i++)
#pragma unroll
    for (int j = 0; j < 2; j++) {
      int col = n0 + 32 * wn + 16 * j + cc;   // 0..191, segment = n0 (uniform)
      int row0 = m0 + 32 * wm + 16 * i + 4 * quad;
      if (col < 64) {
#pragma unroll
        for (int r = 0; r < 4; r++)
          Qmg[((size_t)bn * KSEL + row0 + r) * 64 + col] = bf16u(acc[i][j][r] * 0.125f);
      } else if (col < 128) {
#pragma unroll
        for (int r = 0; r < 4; r++)
          Kmg[((size_t)bn * KSEL + row0 + r) * 64 + (col - 64)] = bf16u(acc[i][j][r]);
      } else {
        ushort4 pk;
        pk.x = bf16u(acc[i][j][0]); pk.y = bf16u(acc[i][j][1]);
        pk.z = bf16u(acc[i][j][2]); pk.w = bf16u(acc[i][j][3]);
        *(ushort4*)&Vtmg[((size_t)bn * 64 + (col - 128)) * KSEL + row0] = pk;
      }
    }
}

// ---------------- RoPE on split Q/K layouts (rows of 64) ----------------
__global__ void rope_split(ushort* __restrict__ Qb, ushort* __restrict__ Kb,
                           const int* __restrict__ sel, int mosa) {
  int tid = blockIdx.x * 256 + threadIdx.x;
  int j = tid & 15;
  int which = (tid >> 4) & 1;                 // 0: Q, 1: K
  int row = tid >> 5;
  float pos = mosa ? (float)sel[row] : (float)(row & (SEQ - 1));
  float inv = __expf((float)j * -0.5756462732485115f);
  float ang = pos * inv;
  float c = cosf(ang), sn = sinf(ang);
  ushort* p = (which ? Kb : Qb) + (size_t)row * 64 + j;
  float x1 = bf2f(p[0]), x2 = bf2f(p[16]);
  p[0] = bf16u(x1 * c - x2 * sn);
  p[16] = bf16u(x1 * sn + x2 * c);
}

// ---------------- flash4: paired q-tiles, shared K/V staging, S^T softmax ----------------
template <bool MOSA>
__global__ __launch_bounds__(512) void flash4(
    const ushort* __restrict__ Qg, const ushort* __restrict__ Kg,
    const ushort* __restrict__ Vtg, const int* __restrict__ sel,
    const float* __restrict__ gates, ushort* __restrict__ outp, int nqt) {
  __shared__ __align__(16) ushort Qs[2][64][64];
  __shared__ __align__(16) ushort Ks[64][64];
  __shared__ __align__(16) ushort Vt[64][64];
  __shared__ __align__(16) ushort Ps[2][64][64];

  const int T = MOSA ? KSEL : SEQ;
  int bn = blockIdx.y; int b = bn >> 3, n = bn & 7;
  int pair = blockIdx.x;
  int qtA = pair, qtB = nqt - 1 - pair;
  int tid = threadIdx.x;
  int g = tid >> 8;
  int myqt = g ? qtB : qtA;
  int t = tid & 255;
  int lane = tid & 63, w = (tid >> 6) & 3;
  int cc = lane & 15, quad = lane >> 4;

  const ushort* Qb = Qg + (size_t)bn * T * 64;
  const ushort* Kb = Kg + (size_t)bn * T * 64;
  const ushort* Vb = Vtg + (size_t)bn * 64 * T;

  // stage group's Q tile (2 b128/thread, swizzled)
  {
    int r = t >> 2, c = t & 3;
    const ushort* src = Qb + (size_t)(myqt * 64 + r) * 64;
    *(short8*)&Qs[g][r][8 * (c ^ (r & 7))] = *(const short8*)(src + 8 * c);
    int c2 = c + 4;
    *(short8*)&Qs[g][r][8 * (c2 ^ (r & 7))] = *(const short8*)(src + 8 * c2);
  }

  f32x4 oacc[4];
  float m = NEG, l = 0.f;
#pragma unroll
  for (int jd = 0; jd < 4; jd++)
#pragma unroll
    for (int r = 0; r < 4; r++) oacc[jd][r] = 0.f;

  for (int kt = 0; kt <= qtB; kt++) {
    __syncthreads();
    {
      int r = tid >> 3, c = tid & 7;
      *(short8*)&Ks[r][8 * (c ^ (r & 7))] =
          *(const short8*)(Kb + (size_t)(kt * 64 + r) * 64 + 8 * c);
      *(short8*)&Vt[r][8 * (c ^ (r & 7))] =
          *(const short8*)(Vb + (size_t)r * T + kt * 64 + 8 * c);
    }
    __syncthreads();

    if (g || (kt <= qtA)) {
      // S^T = K.Q^T : C col = q (cc), row = key (16j + 4quad + r)
      f32x4 sacc[4];
#pragma unroll
      for (int j = 0; j < 4; j++)
#pragma unroll
        for (int r = 0; r < 4; r++) sacc[j][r] = 0.f;
      int qrow = 16 * w + cc;
#pragma unroll
      for (int ks = 0; ks < 2; ks++) {
        short8 bq = *(const short8*)&Qs[g][qrow][8 * ((quad + 4 * ks) ^ (qrow & 7))];
#pragma unroll
        for (int j = 0; j < 4; j++) {
          int krow = 16 * j + cc;
          short8 ak = *(const short8*)&Ks[krow][8 * ((quad + 4 * ks) ^ (krow & 7))];
          sacc[j] = __builtin_amdgcn_mfma_f32_16x16x32_bf16(ak, bq, sacc[j], 0, 0, 0);
        }
      }
      if (kt == myqt) {
#pragma unroll
        for (int j = 0; j < 4; j++)
#pragma unroll
          for (int r = 0; r < 4; r++)
            if (16 * j + 4 * quad + r > 16 * w + cc) sacc[j][r] = NEG;
      }
      // per-lane online softmax (q = 16w+cc fixed per lane)
      float mx = NEG;
#pragma unroll
      for (int j = 0; j < 4; j++)
#pragma unroll
        for (int r = 0; r < 4; r++) mx = fmaxf(mx, sacc[j][r]);
      mx = fmaxf(mx, __shfl_xor(mx, 16));
      mx = fmaxf(mx, __shfl_xor(mx, 32));
      float mn = fmaxf(m, mx);
      float sc = __expf(m - mn);
      m = mn;
      float rsum = 0.f;
      float p[4][4];
#pragma unroll
      for (int j = 0; j < 4; j++)
#pragma unroll
        for (int r = 0; r < 4; r++) { p[j][r] = __expf(sacc[j][r] - mn); rsum += p[j][r]; }
      rsum += __shfl_xor(rsum, 16);
      rsum += __shfl_xor(rsum, 32);
      l = l * sc + rsum;
      // Ps[q][key] packed b64 (wave-local rows)
#pragma unroll
      for (int j = 0; j < 4; j++) {
        ushort4 pk;
        pk.x = bf16u(p[j][0]); pk.y = bf16u(p[j][1]);
        pk.z = bf16u(p[j][2]); pk.w = bf16u(p[j][3]);
        int phys = (2 * j + (quad >> 1)) ^ (qrow & 7);
        *(ushort4*)&Ps[g][qrow][phys * 8 + 4 * (quad & 1)] = pk;
      }
      // rescale O rows (q-local = 4quad+r) by that q's sc
#pragma unroll
      for (int r = 0; r < 4; r++) {
        float scr = __shfl(sc, 16 * quad + 4 * quad + r);
#pragma unroll
        for (int jd = 0; jd < 4; jd++) oacc[jd][r] *= scr;
      }
      __asm__ volatile("s_waitcnt lgkmcnt(0)" ::: "memory");
      // O += P.V
#pragma unroll
      for (int ks = 0; ks < 2; ks++) {
        short8 ap = *(const short8*)&Ps[g][qrow][8 * ((quad + 4 * ks) ^ (qrow & 7))];
#pragma unroll
        for (int jd = 0; jd < 4; jd++) {
          int vrow = 16 * jd + cc;
          short8 bv = *(const short8*)&Vt[vrow][8 * ((quad + 4 * ks) ^ (vrow & 7))];
          oacc[jd] = __builtin_amdgcn_mfma_f32_16x16x32_bf16(ap, bv, oacc[jd], 0, 0, 0);
        }
      }
    }
  }

  // epilogue: q = myqt*64 + 16w + 4quad + r, d = 16jd + cc
#pragma unroll
  for (int r = 0; r < 4; r++) {
    float lr = __shfl(l, 16 * quad + 4 * quad + r);
    int q = myqt * 64 + 16 * w + 4 * quad + r;
    float scale;
    size_t row;
    if (MOSA) {
      int trow = sel[bn * KSEL + q];
      scale = gates[bn * KSEL + q] / lr;
      row = (size_t)(b * SEQ + trow);
    } else {
      scale = 1.f / lr;
      row = (size_t)(b * SEQ + q);
    }
    ushort* orow = outp + row * (NHEAD * DH) + n * DH;
#pragma unroll
    for (int jd = 0; jd < 4; jd++)
      orow[16 * jd + cc] = bf16u(oacc[jd][r] * scale);
  }
}

// ---------------- bf16 MFMA GEMM, 128x128 tile, BK=32 ----------------
// MODE 0: out f32 = A1@B1 + A2@B2.  MODE 1: dense-qkv scatter into Qg/Kg/Vtg.
template <int MODE>
__global__ __launch_bounds__(256) void gemm_bf16(
    const ushort* __restrict__ A1, const ushort* __restrict__ B1t, int K1,
    const ushort* __restrict__ A2, const ushort* __restrict__ B2t, int K2,
    void* __restrict__ outv, int N,
    ushort* __restrict__ Qo, ushort* __restrict__ Ko, ushort* __restrict__ Vto) {
  __shared__ __align__(16) ushort As[128][32];
  __shared__ __align__(16) ushort Bs[128][32];
  int m0 = blockIdx.x * 128, n0 = blockIdx.y * 128;
  int tid = threadIdx.x;
  int lane = tid & 63, wave = tid >> 6;
  int wm = wave & 1, wn = wave >> 1;
  int cc = lane & 15, quad = lane >> 4;
  int sr = tid >> 2, sc = tid & 3;

  f32x4 acc[4][4];
#pragma unroll
  for (int i = 0; i < 4; i++)
#pragma unroll
    for (int j = 0; j < 4; j++)
#pragma unroll
      for (int r = 0; r < 4; r++) acc[i][j][r] = 0.f;

  const int npass = (MODE == 0) ? 2 : 1;
  for (int pass = 0; pass < npass; pass++) {
    const ushort* A = pass ? A2 : A1;
    const ushort* Bt = pass ? B2t : B1t;
    int K = pass ? K2 : K1;
    for (int k0 = 0; k0 < K; k0 += 32) {
      __syncthreads();
      {
        short8 a0 = *(const short8*)(A + (size_t)(m0 + sr) * K + k0 + 8 * sc);
        short8 a1 = *(const short8*)(A + (size_t)(m0 + sr + 64) * K + k0 + 8 * sc);
        short8 b0 = *(const short8*)(Bt + (size_t)(n0 + sr) * K + k0 + 8 * sc);
        short8 b1 = *(const short8*)(Bt + (size_t)(n0 + sr + 64) * K + k0 + 8 * sc);
        *(short8*)&As[sr][8 * ((sc + (sr >> 1)) & 3)] = a0;
        *(short8*)&As[sr + 64][8 * ((sc + ((sr + 64) >> 1)) & 3)] = a1;
        *(short8*)&Bs[sr][8 * ((sc + (sr >> 1)) & 3)] = b0;
        *(short8*)&Bs[sr + 64][8 * ((sc + ((sr + 64) >> 1)) & 3)] = b1;
      }
      __syncthreads();
      short8 af[4], bfr[4];
#pragma unroll
      for (int i = 0; i < 4; i++) {
        int ra = 64 * wm + 16 * i + cc;
        af[i] = *(const short8*)&As[ra][8 * ((quad + (ra >> 1)) & 3)];
      }
#pragma unroll
      for (int j = 0; j < 4; j++) {
        int rb = 64 * wn + 16 * j + cc;
        bfr[j] = *(const short8*)&Bs[rb][8 * ((quad + (rb >> 1)) & 3)];
      }
#pragma unroll
      for (int i = 0; i < 4; i++)
#pragma unroll
        for (int j = 0; j < 4; j++)
          acc[i][j] = __builtin_amdgcn_mfma_f32_16x16x32_bf16(af[i], bfr[j], acc[i][j], 0, 0, 0);
    }
  }

#pragma unroll
  for (int i = 0; i < 4; i++) {
#pragma unroll
    for (int j = 0; j < 4; j++) {
      int colg = n0 + 64 * wn + 16 * j + cc;
      int row0 = m0 + 64 * wm + 16 * i + 4 * quad;
      if (MODE == 0) {
#pragma unroll
        for (int r = 0; r < 4; r++)
          ((float*)outv)[(size_t)(row0 + r) * N + colg] = acc[i][j][r];
      } else {
        int nn = colg / 192, c = colg % 192;     // uniform across lanes per j
        int b2 = row0 >> 11, t2 = row0 & 2047;
        int bn2 = b2 * 8 + nn;
        if (c < 64) {
#pragma unroll
          for (int r = 0; r < 4; r++)
            Qo[((size_t)bn2 * SEQ + t2 + r) * 64 + c] = bf16u(acc[i][j][r] * 0.125f);
        } else if (c < 128) {
#pragma unroll
          for (int r = 0; r < 4; r++)
            Ko[((size_t)bn2 * SEQ + t2 + r) * 64 + (c - 64)] = bf16u(acc[i][j][r]);
        } else {
          ushort4 pk;
          pk.x = bf16u(acc[i][j][0]); pk.y = bf16u(acc[i][j][1]);
          pk.z = bf16u(acc[i][j][2]); pk.w = bf16u(acc[i][j][3]);
          *(ushort4*)&Vto[((size_t)bn2 * 64 + (c - 128)) * SEQ + t2] = pk;
        }
      }
    }
  }
}

extern "C" void kernel_launch(void* const* d_in, const int* in_sizes, int n_in,
                              void* d_out, int out_size, void* d_ws, size_t ws_size,
                              hipStream_t stream) {
  const float* X          = (const float*)d_in[0];
  const float* router_w   = (const float*)d_in[1];
  const float* mosa_wqkv  = (const float*)d_in[2];
  const float* mosa_wo    = (const float*)d_in[3];
  const float* dense_wqkv = (const float*)d_in[4];
  const float* dense_wo   = (const float*)d_in[5];
  float* out = (float*)d_out;
  char* ws = (char*)d_ws;

  // workspace layout (bytes)
  float*  scores  = (float*) (ws + 0);          // 131072
  int*    sel     = (int*)   (ws + 131072);     // 16384
  float*  gates   = (float*) (ws + 147456);     // 16384
  ushort* avm     = (ushort*)(ws + 163840);     // 4194304
  ushort* avd     = (ushort*)(ws + 4358144);    // 4194304
  ushort* Xb      = (ushort*)(ws + 8552448);    // 8388608
  ushort* Wqkv_t  = (ushort*)(ws + 16941056);   // 3145728
  ushort* Wmq_t   = (ushort*)(ws + 20086784);   // 3145728
  ushort* Wdo_t   = (ushort*)(ws + 23232512);   // 1048576
  ushort* Wmo_t   = (ushort*)(ws + 24281088);   // 1048576
  ushort* Qg      = (ushort*)(ws + 25329664);   // 4194304  (16 bn x 2048 x 64)
  ushort* Kg      = (ushort*)(ws + 29523968);   // 4194304
  ushort* Vtg     = (ushort*)(ws + 33718272);   // 4194304  (16 bn x 64 x 2048)
  ushort* Qmg     = (ushort*)(ws + 37912576);   // 524288   (16 bn x 256 x 64)
  ushort* Kmg     = (ushort*)(ws + 38436864);   // 524288
  ushort* Vtmg    = (ushort*)(ws + 38961152);   // 524288
  int*    pranks  = (int*)   (ws + 39485440);   // 16*32*2048*4 = 4194304 (end 43679744)

  hipMemsetAsync(avm, 0, (size_t)BB * SEQ * NHEAD * DH * sizeof(ushort), stream);

  // casts / transposes
  cast_bf16x4<<<4096, 256, 0, stream>>>(X, Xb, BB * SEQ * HD / 4);
  transpose_cast2<<<dim3(48, 32, 2), 256, 0, stream>>>(dense_wqkv, Wqkv_t,
                                                       mosa_wqkv, Wmq_t, 1024, 1536);
  transpose_cast2<<<dim3(32, 16, 2), 256, 0, stream>>>(dense_wo, Wdo_t,
                                                       mosa_wo, Wmo_t, 512, 1024);

  // router + top-k
  router2<<<BB * SEQ / 32, 256, 0, stream>>>(X, router_w, scores);
  topk_partial<<<dim3(BB * NHEAD, 32), 256, 0, stream>>>(scores, pranks);
  topk_select<<<BB * NHEAD, 1024, 0, stream>>>(scores, pranks, sel, gates);

  // mosa branch
  gemm_mosa_bf16<<<dim3(BB * NHEAD, KSEL / 64, D3 / 64), 256, 0, stream>>>(
      Xb, Wmq_t, sel, Qmg, Kmg, Vtmg);
  rope_split<<<(BB * NHEAD * KSEL * 32) / 256, 256, 0, stream>>>(Qmg, Kmg, sel, 1);
  flash4<true><<<dim3((KSEL / 64) / 2, BB * NHEAD), 512, 0, stream>>>(
      Qmg, Kmg, Vtmg, sel, gates, avm, KSEL / 64);

  // dense branch
  gemm_bf16<1><<<dim3(32, 12), 256, 0, stream>>>(Xb, Wqkv_t, 1024,
      (const ushort*)nullptr, (const ushort*)nullptr, 0, nullptr, NHEAD * D3,
      Qg, Kg, Vtg);
  rope_split<<<(BB * NHEAD * SEQ * 32) / 256, 256, 0, stream>>>(Qg, Kg, nullptr, 0);
  flash4<false><<<dim3((SEQ / 64) / 2, BB * NHEAD), 512, 0, stream>>>(
      Qg, Kg, Vtg, (const int*)nullptr, (const float*)nullptr, avd, SEQ / 64);

  // final: out = avm@mosa_wo + avd@dense_wo  (f32 out)
  gemm_bf16<0><<<dim3(32, 8), 256, 0, stream>>>(avm, Wmo_t, 512, avd, Wdo_t, 512, out, HD,
                                                nullptr, nullptr, nullptr);
}

// Round 9
// 238.838 us; speedup vs baseline: 6.9409x; 1.0330x over previous
//
#include <hip/hip_runtime.h>
#include <math.h>

constexpr int BB = 2;
constexpr int SEQ = 2048;
constexpr int HD = 1024;
constexpr int DH = 64;       // head dim
constexpr int NHEAD = 8;
constexpr int D3 = 192;      // 3*DH
constexpr int KSEL = 256;    // SEQ / SPARSITY
constexpr float NEG = -1e30f;

typedef short short8 __attribute__((ext_vector_type(8)));
typedef float f32x4 __attribute__((ext_vector_type(4)));

__device__ __forceinline__ ushort bf16u(float f) {
  union { float f; unsigned u; } v; v.f = f;
  unsigned r = (v.u + 0x7FFFu + ((v.u >> 16) & 1u)) >> 16;
  return (ushort)r;
}
__device__ __forceinline__ float bf2f(ushort h) {
  union { unsigned u; float f; } v; v.u = ((unsigned)h) << 16;
  return v.f;
}

// async global->LDS, 16B per lane; LDS dest = wave-uniform base + lane*16
__device__ __forceinline__ void gl_lds16(const ushort* g, ushort* l) {
  __builtin_amdgcn_global_load_lds(
      (const __attribute__((address_space(1))) unsigned int*)g,
      (__attribute__((address_space(3))) unsigned int*)l, 16, 0, 0);
}

// order-preserving composite key: rank predicate (s_j > s_i) || (s_j==s_i && j<i)
// becomes key_j > key_i  (single u64 compare)
__device__ __forceinline__ unsigned long long rankkey(float s, int idx) {
  union { float f; unsigned u; } v; v.f = s;
  unsigned o = (v.u & 0x80000000u) ? ~v.u : (v.u | 0x80000000u);
  return ((unsigned long long)o << 11) | (unsigned)(2047 - idx);
}

// ---------------- cast f32 -> bf16, 4 elems/thread ----------------
__global__ void cast_bf16x4(const float* __restrict__ x, ushort* __restrict__ y, int n4) {
  int i = blockIdx.x * 256 + threadIdx.x;
  if (i >= n4) return;
  float4 v = ((const float4*)x)[i];
  ushort4 r; r.x = bf16u(v.x); r.y = bf16u(v.y); r.z = bf16u(v.z); r.w = bf16u(v.w);
  ((ushort4*)y)[i] = r;
}

// ---------------- transpose + cast pair: W[K][N] f32 -> Wt[N][K] bf16 ----------------
__global__ __launch_bounds__(256) void transpose_cast2(
    const float* __restrict__ W1, ushort* __restrict__ T1,
    const float* __restrict__ W2, ushort* __restrict__ T2, int K, int N) {
  const float* W = blockIdx.z ? W2 : W1;
  ushort* Wt = blockIdx.z ? T2 : T1;
  __shared__ float tile[32][33];
  int n0 = blockIdx.x * 32, k0 = blockIdx.y * 32;
  int tx = threadIdx.x & 31, ty = threadIdx.x >> 5;
#pragma unroll
  for (int i = 0; i < 4; i++)
    tile[ty + 8 * i][tx] = W[(size_t)(k0 + ty + 8 * i) * N + n0 + tx];
  __syncthreads();
#pragma unroll
  for (int i = 0; i < 4; i++)
    Wt[(size_t)(n0 + ty + 8 * i) * K + k0 + tx] = bf16u(tile[tx][ty + 8 * i]);
}

// ---------------- router v2: register-blocked, 32 rows/block ----------------
__global__ __launch_bounds__(256) void router2(const float* __restrict__ X,
    const float* __restrict__ rw, float* __restrict__ scores) {
  __shared__ float rwT[8][8][132];          // [n][seg][128+4pad]
  int tid = threadIdx.x;
  for (int idx = tid; idx < 8192; idx += 256) {
    int h = idx & 1023, n = idx >> 10;
    rwT[n][h >> 7][h & 127] = rw[h * 8 + n];
  }
  __syncthreads();
  int row = blockIdx.x * 32 + (tid >> 3);   // bt row
  int seg = tid & 7;
  const float* xrow = X + (size_t)row * HD + seg * 128;
  float acc[8] = {};
#pragma unroll 8
  for (int it = 0; it < 32; it++) {
    float4 xv = *(const float4*)(xrow + 4 * it);
#pragma unroll
    for (int n = 0; n < 8; n++) {
      float4 rv = *(const float4*)&rwT[n][seg][4 * it];
      acc[n] += xv.x * rv.x + xv.y * rv.y + xv.z * rv.z + xv.w * rv.w;
    }
  }
#pragma unroll
  for (int n = 0; n < 8; n++) {
    acc[n] += __shfl_xor(acc[n], 1);
    acc[n] += __shfl_xor(acc[n], 2);
    acc[n] += __shfl_xor(acc[n], 4);
  }
  int b = row >> 11, t2 = row & (SEQ - 1);
  scores[((size_t)b * NHEAD + seg) * SEQ + t2] = acc[seg];
}

// ---------------- top-k stage 1: u64-key partial rank counts (32 chunks of 64) ----------
__global__ __launch_bounds__(256) void topk_partial(const float* __restrict__ scores,
    int* __restrict__ pranks) {
  int row = blockIdx.x;                      // 16
  int c = blockIdx.y;                        // 32 chunks of 64 j
  __shared__ unsigned long long ck[64];
  const float* sp = scores + (size_t)row * SEQ;
  int tid = threadIdx.x;
  if (tid < 64) ck[tid] = rankkey(sp[c * 64 + tid], c * 64 + tid);
  __syncthreads();
  unsigned long long kv[8]; int p[8];
#pragma unroll
  for (int i = 0; i < 8; i++) {
    int vi = i * 256 + tid;
    kv[i] = rankkey(sp[vi], vi);
    p[i] = 0;
  }
#pragma unroll 8
  for (int j = 0; j < 64; j += 2) {
    unsigned long long k0 = ck[j], k1 = ck[j + 1];
#pragma unroll
    for (int i = 0; i < 8; i++) {
      p[i] += (k0 > kv[i]);
      p[i] += (k1 > kv[i]);
    }
  }
#pragma unroll
  for (int i = 0; i < 8; i++)
    pranks[((size_t)row * 32 + c) * SEQ + i * 256 + tid] = p[i];
}

// ---------------- top-k stage 2: sum partials, ballot-scan, emit ----------------
__global__ __launch_bounds__(1024) void topk_select(const float* __restrict__ scores,
    const int* __restrict__ pranks, int* __restrict__ sel, float* __restrict__ gates) {
  int bn = blockIdx.x;
  __shared__ int wsum[16];
  int tid = threadIdx.x;
  int t0 = tid * 2;
  int r0 = 0, r1 = 0;
#pragma unroll
  for (int c = 0; c < 32; c++) {
    const int2 pp = *(const int2*)&pranks[((size_t)bn * 32 + c) * SEQ + t0];
    r0 += pp.x; r1 += pp.y;
  }
  int f0 = r0 < KSEL, f1 = r1 < KSEL;
  unsigned long long b0 = __ballot(f0), b1 = __ballot(f1);
  int lane = tid & 63, wv = tid >> 6;
  unsigned long long lower = (1ULL << lane) - 1ULL;
  int before = __popcll(b0 & lower) + __popcll(b1 & lower);
  int wtotal = __popcll(b0) + __popcll(b1);
  if (lane == 0) wsum[wv] = wtotal;
  __syncthreads();
  int woff = 0;
#pragma unroll
  for (int i2 = 0; i2 < 16; i2++) woff += (i2 < wv) ? wsum[i2] : 0;
  int base = woff + before;
  if (f0) { sel[bn * KSEL + base] = t0;
            gates[bn * KSEL + base] = 1.f / (1.f + __expf(-scores[(size_t)bn * SEQ + t0]));
            base++; }
  if (f1) { sel[bn * KSEL + base] = t0 + 1;
            gates[bn * KSEL + base] = 1.f / (1.f + __expf(-scores[(size_t)bn * SEQ + t0 + 1])); }
}

// ---------------- mosa qkv: gathered-A bf16 MFMA GEMM -> split Q/K/V^T layouts ----------
__global__ __launch_bounds__(256) void gemm_mosa_bf16(const ushort* __restrict__ Xb,
    const ushort* __restrict__ Wt, const int* __restrict__ sel,
    ushort* __restrict__ Qmg, ushort* __restrict__ Kmg, ushort* __restrict__ Vtmg) {
  __shared__ __align__(16) ushort As[64][40];
  __shared__ __align__(16) ushort Bs[64][40];
  int bn = blockIdx.x; int b = bn >> 3, n = bn & 7;
  int m0 = blockIdx.y * 64, n0 = blockIdx.z * 64;
  int tid = threadIdx.x;
  int lane = tid & 63, w = tid >> 6;
  int wm = w & 1, wn = w >> 1;
  int cc = lane & 15, quad = lane >> 4;
  int sr = tid >> 2, sc4 = tid & 3;

  int grow = sel[bn * KSEL + m0 + sr];
  const ushort* arow = Xb + ((size_t)(b * SEQ) + grow) * HD;
  const ushort* brow = Wt + ((size_t)(n * D3 + n0 + sr)) * HD;

  f32x4 acc[2][2];
#pragma unroll
  for (int i = 0; i < 2; i++)
#pragma unroll
    for (int j = 0; j < 2; j++)
#pragma unroll
      for (int r = 0; r < 4; r++) acc[i][j][r] = 0.f;

  for (int k0 = 0; k0 < HD; k0 += 32) {
    __syncthreads();
    *(short8*)&As[sr][8 * sc4] = *(const short8*)(arow + k0 + 8 * sc4);
    *(short8*)&Bs[sr][8 * sc4] = *(const short8*)(brow + k0 + 8 * sc4);
    __syncthreads();
    short8 af[2], bf_[2];
#pragma unroll
    for (int i = 0; i < 2; i++) af[i] = *(const short8*)&As[32 * wm + 16 * i + cc][8 * quad];
#pragma unroll
    for (int j = 0; j < 2; j++) bf_[j] = *(const short8*)&Bs[32 * wn + 16 * j + cc][8 * quad];
#pragma unroll
    for (int i = 0; i < 2; i++)
#pragma unroll
      for (int j = 0; j < 2; j++)
        acc[i][j] = __builtin_amdgcn_mfma_f32_16x16x32_bf16(af[i], bf_[j], acc[i][j], 0, 0, 0);
  }

#pragma unroll
  for (int i = 0; i < 2; i++)
#pragma unroll
    for (int j = 0; j < 2; j++) {
      int col = n0 + 32 * wn + 16 * j + cc;   // 0..191, segment = n0 (uniform)
      int row0 = m0 + 32 * wm + 16 * i + 4 * quad;
      if (col < 64) {
#pragma unroll
        for (int r = 0; r < 4; r++)
          Qmg[((size_t)bn * KSEL + row0 + r) * 64 + col] = bf16u(acc[i][j][r] * 0.125f);
      } else if (col < 128) {
#pragma unroll
        for (int r = 0; r < 4; r++)
          Kmg[((size_t)bn * KSEL + row0 + r) * 64 + (col - 64)] = bf16u(acc[i][j][r]);
      } else {
        ushort4 pk;
        pk.x = bf16u(acc[i][j][0]); pk.y = bf16u(acc[i][j][1]);
        pk.z = bf16u(acc[i][j][2]); pk.w = bf16u(acc[i][j][3]);
        *(ushort4*)&Vtmg[((size_t)bn * 64 + (col - 128)) * KSEL + row0] = pk;
      }
    }
}

// ---------------- RoPE on split Q/K layouts (rows of 64) ----------------
__global__ void rope_split(ushort* __restrict__ Qb, ushort* __restrict__ Kb,
                           const int* __restrict__ sel, int mosa) {
  int tid = blockIdx.x * 256 + threadIdx.x;
  int j = tid & 15;
  int which = (tid >> 4) & 1;                 // 0: Q, 1: K
  int row = tid >> 5;
  float pos = mosa ? (float)sel[row] : (float)(row & (SEQ - 1));
  float inv = __expf((float)j * -0.5756462732485115f);
  float ang = pos * inv;
  float c = cosf(ang), sn = sinf(ang);
  ushort* p = (which ? Kb : Qb) + (size_t)row * 64 + j;
  float x1 = bf2f(p[0]), x2 = bf2f(p[16]);
  p[0] = bf16u(x1 * c - x2 * sn);
  p[16] = bf16u(x1 * sn + x2 * c);
}

// ---------------- flash5: 256-thr blocks, Q-in-regs, async dbuf staging ----------------
// blockIdx.x: [0,512) dense (qt = 31 - bx/16 descending, bn = bx&15); [512,576) mosa.
// Wave w owns q rows 16w..16w+15. K/V tiles double-buffered in LDS, staged via
// global_load_lds (swizzle-inverse in the per-lane source address). One barrier/tile:
// prefetch kt+1 issues right after it and drains during tile-kt compute.
__global__ __launch_bounds__(256) void flash5(
    const ushort* __restrict__ Qg, const ushort* __restrict__ Kg,
    const ushort* __restrict__ Vtg,
    const ushort* __restrict__ Qmg, const ushort* __restrict__ Kmg,
    const ushort* __restrict__ Vtmg,
    const int* __restrict__ sel, const float* __restrict__ gates,
    ushort* __restrict__ avd, ushort* __restrict__ avm) {
  __shared__ __align__(16) ushort Ks[2][64][64];
  __shared__ __align__(16) ushort Vt[2][64][64];
  __shared__ __align__(16) ushort Ps[64][64];

  int bx = blockIdx.x;
  bool mosa = bx >= 512;
  int bn, qt, T;
  const ushort *Qb, *Kb, *Vb;
  ushort* outp;
  if (!mosa) {
    bn = bx & 15; qt = 31 - (bx >> 4); T = SEQ;
    Qb = Qg + (size_t)bn * SEQ * 64;
    Kb = Kg + (size_t)bn * SEQ * 64;
    Vb = Vtg + (size_t)bn * 64 * SEQ;
    outp = avd;
  } else {
    int rr = bx - 512;
    bn = rr & 15; qt = 3 - (rr >> 4); T = KSEL;
    Qb = Qmg + (size_t)bn * KSEL * 64;
    Kb = Kmg + (size_t)bn * KSEL * 64;
    Vb = Vtmg + (size_t)bn * 64 * KSEL;
    outp = avm;
  }
  int b = bn >> 3, n = bn & 7;
  int tid = threadIdx.x;
  int lane = tid & 63, w = tid >> 6;
  int cc = lane & 15, quad = lane >> 4;
  int qrow = 16 * w + cc;

  // Q fragments straight from global (pre-scaled by 1/8 upstream); loop-invariant
  short8 bq[2];
  {
    const ushort* qsrc = Qb + (size_t)(qt * 64 + qrow) * 64;
    bq[0] = *(const short8*)(qsrc + 8 * quad);
    bq[1] = *(const short8*)(qsrc + 8 * (quad + 4));
  }

  // staging addresses: slice = 8 rows x 128B per wave-instr; lane l -> row +(l>>3),
  // phys chunk l&7 holds logical chunk (l&7)^(row&7)  (xor swizzle inverse)
  int rloc = lane >> 3;
  int c_log = (lane & 7) ^ rloc;
  int row0 = 16 * w + rloc, row1 = row0 + 8;
  const ushort* pK0 = Kb + (size_t)row0 * 64 + 8 * c_log;
  const ushort* pK1 = Kb + (size_t)row1 * 64 + 8 * c_log;
  const ushort* pV0 = Vb + (size_t)row0 * T + 8 * c_log;
  const ushort* pV1 = Vb + (size_t)row1 * T + 8 * c_log;

  f32x4 oacc[4];
  float m = NEG, l = 0.f;
#pragma unroll
  for (int jd = 0; jd < 4; jd++)
#pragma unroll
    for (int r = 0; r < 4; r++) oacc[jd][r] = 0.f;

  // prefetch tile 0 into buf 0
  gl_lds16(pK0, &Ks[0][16 * w][0]);
  gl_lds16(pK1, &Ks[0][16 * w + 8][0]);
  gl_lds16(pV0, &Vt[0][16 * w][0]);
  gl_lds16(pV1, &Vt[0][16 * w + 8][0]);

  for (int kt = 0; kt <= qt; kt++) {
    int buf = kt & 1;
    __syncthreads();          // implicit vmcnt(0): buf's loads complete; prev buf free
    if (kt < qt) {
      int nk = kt + 1, nb = buf ^ 1;
      gl_lds16(pK0 + (size_t)nk * 4096, &Ks[nb][16 * w][0]);
      gl_lds16(pK1 + (size_t)nk * 4096, &Ks[nb][16 * w + 8][0]);
      gl_lds16(pV0 + nk * 64, &Vt[nb][16 * w][0]);
      gl_lds16(pV1 + nk * 64, &Vt[nb][16 * w + 8][0]);
    }

    // S^T = K.Q^T : C col = q (cc), row = key (16j + 4quad + r)
    f32x4 sacc[4];
#pragma unroll
    for (int j = 0; j < 4; j++)
#pragma unroll
      for (int r = 0; r < 4; r++) sacc[j][r] = 0.f;
#pragma unroll
    for (int ks = 0; ks < 2; ks++) {
#pragma unroll
      for (int j = 0; j < 4; j++) {
        int krow = 16 * j + cc;
        short8 ak = *(const short8*)&Ks[buf][krow][8 * ((quad + 4 * ks) ^ (krow & 7))];
        sacc[j] = __builtin_amdgcn_mfma_f32_16x16x32_bf16(ak, bq[ks], sacc[j], 0, 0, 0);
      }
    }
    if (kt == qt) {
#pragma unroll
      for (int j = 0; j < 4; j++)
#pragma unroll
        for (int r = 0; r < 4; r++)
          if (16 * j + 4 * quad + r > qrow) sacc[j][r] = NEG;
    }
    // per-lane online softmax (q = 16w+cc fixed per lane)
    float mx = NEG;
#pragma unroll
    for (int j = 0; j < 4; j++)
#pragma unroll
      for (int r = 0; r < 4; r++) mx = fmaxf(mx, sacc[j][r]);
    mx = fmaxf(mx, __shfl_xor(mx, 16));
    mx = fmaxf(mx, __shfl_xor(mx, 32));
    float mn = fmaxf(m, mx);
    float sc = __expf(m - mn);
    m = mn;
    float rsum = 0.f;
    float p[4][4];
#pragma unroll
    for (int j = 0; j < 4; j++)
#pragma unroll
      for (int r = 0; r < 4; r++) { p[j][r] = __expf(sacc[j][r] - mn); rsum += p[j][r]; }
    rsum += __shfl_xor(rsum, 16);
    rsum += __shfl_xor(rsum, 32);
    l = l * sc + rsum;
    // Ps[q][key] packed b64 (wave-local rows)
#pragma unroll
    for (int j = 0; j < 4; j++) {
      ushort4 pk;
      pk.x = bf16u(p[j][0]); pk.y = bf16u(p[j][1]);
      pk.z = bf16u(p[j][2]); pk.w = bf16u(p[j][3]);
      int phys = (2 * j + (quad >> 1)) ^ (qrow & 7);
      *(ushort4*)&Ps[qrow][phys * 8 + 4 * (quad & 1)] = pk;
    }
    // rescale O rows (q-local = 4quad+r) by that q's sc
#pragma unroll
    for (int r = 0; r < 4; r++) {
      float scr = __shfl(sc, 16 * quad + 4 * quad + r);
#pragma unroll
      for (int jd = 0; jd < 4; jd++) oacc[jd][r] *= scr;
    }
    __asm__ volatile("s_waitcnt lgkmcnt(0)" ::: "memory");
    // O += P.V
#pragma unroll
    for (int ks = 0; ks < 2; ks++) {
      short8 ap = *(const short8*)&Ps[qrow][8 * ((quad + 4 * ks) ^ (qrow & 7))];
#pragma unroll
      for (int jd = 0; jd < 4; jd++) {
        int vrow = 16 * jd + cc;
        short8 bv = *(const short8*)&Vt[buf][vrow][8 * ((quad + 4 * ks) ^ (vrow & 7))];
        oacc[jd] = __builtin_amdgcn_mfma_f32_16x16x32_bf16(ap, bv, oacc[jd], 0, 0, 0);
      }
    }
  }

  // epilogue: q = qt*64 + 16w + 4quad + r, d = 16jd + cc
#pragma unroll
  for (int r = 0; r < 4; r++) {
    float lr = __shfl(l, 16 * quad + 4 * quad + r);
    int q = qt * 64 + 16 * w + 4 * quad + r;
    float scale;
    size_t row;
    if (mosa) {
      int trow = sel[bn * KSEL + q];
      scale = gates[bn * KSEL + q] / lr;
      row = (size_t)(b * SEQ + trow);
    } else {
      scale = 1.f / lr;
      row = (size_t)(b * SEQ + q);
    }
    ushort* orow = outp + row * (NHEAD * DH) + n * DH;
#pragma unroll
    for (int jd = 0; jd < 4; jd++)
      orow[16 * jd + cc] = bf16u(oacc[jd][r] * scale);
  }
}

// ---------------- bf16 MFMA GEMM, 128x128 tile, BK=32 ----------------
// MODE 0: out f32 = A1@B1 + A2@B2.  MODE 1: dense-qkv scatter into Qg/Kg/Vtg.
template <int MODE>
__global__ __launch_bounds__(256) void gemm_bf16(
    const ushort* __restrict__ A1, const ushort* __restrict__ B1t, int K1,
    const ushort* __restrict__ A2, const ushort* __restrict__ B2t, int K2,
    void* __restrict__ outv, int N,
    ushort* __restrict__ Qo, ushort* __restrict__ Ko, ushort* __restrict__ Vto) {
  __shared__ __align__(16) ushort As[128][32];
  __shared__ __align__(16) ushort Bs[128][32];
  int m0 = blockIdx.x * 128, n0 = blockIdx.y * 128;
  int tid = threadIdx.x;
  int lane = tid & 63, wave = tid >> 6;
  int wm = wave & 1, wn = wave >> 1;
  int cc = lane & 15, quad = lane >> 4;
  int sr = tid >> 2, sc = tid & 3;

  f32x4 acc[4][4];
#pragma unroll
  for (int i = 0; i < 4; i++)
#pragma unroll
    for (int j = 0; j < 4; j++)
#pragma unroll
      for (int r = 0; r < 4; r++) acc[i][j][r] = 0.f;

  const int npass = (MODE == 0) ? 2 : 1;
  for (int pass = 0; pass < npass; pass++) {
    const ushort* A = pass ? A2 : A1;
    const ushort* Bt = pass ? B2t : B1t;
    int K = pass ? K2 : K1;
    for (int k0 = 0; k0 < K; k0 += 32) {
      __syncthreads();
      {
        short8 a0 = *(const short8*)(A + (size_t)(m0 + sr) * K + k0 + 8 * sc);
        short8 a1 = *(const short8*)(A + (size_t)(m0 + sr + 64) * K + k0 + 8 * sc);
        short8 b0 = *(const short8*)(Bt + (size_t)(n0 + sr) * K + k0 + 8 * sc);
        short8 b1 = *(const short8*)(Bt + (size_t)(n0 + sr + 64) * K + k0 + 8 * sc);
        *(short8*)&As[sr][8 * ((sc + (sr >> 1)) & 3)] = a0;
        *(short8*)&As[sr + 64][8 * ((sc + ((sr + 64) >> 1)) & 3)] = a1;
        *(short8*)&Bs[sr][8 * ((sc + (sr >> 1)) & 3)] = b0;
        *(short8*)&Bs[sr + 64][8 * ((sc + ((sr + 64) >> 1)) & 3)] = b1;
      }
      __syncthreads();
      short8 af[4], bfr[4];
#pragma unroll
      for (int i = 0; i < 4; i++) {
        int ra = 64 * wm + 16 * i + cc;
        af[i] = *(const short8*)&As[ra][8 * ((quad + (ra >> 1)) & 3)];
      }
#pragma unroll
      for (int j = 0; j < 4; j++) {
        int rb = 64 * wn + 16 * j + cc;
        bfr[j] = *(const short8*)&Bs[rb][8 * ((quad + (rb >> 1)) & 3)];
      }
#pragma unroll
      for (int i = 0; i < 4; i++)
#pragma unroll
        for (int j = 0; j < 4; j++)
          acc[i][j] = __builtin_amdgcn_mfma_f32_16x16x32_bf16(af[i], bfr[j], acc[i][j], 0, 0, 0);
    }
  }

#pragma unroll
  for (int i = 0; i < 4; i++) {
#pragma unroll
    for (int j = 0; j < 4; j++) {
      int colg = n0 + 64 * wn + 16 * j + cc;
      int row0 = m0 + 64 * wm + 16 * i + 4 * quad;
      if (MODE == 0) {
#pragma unroll
        for (int r = 0; r < 4; r++)
          ((float*)outv)[(size_t)(row0 + r) * N + colg] = acc[i][j][r];
      } else {
        int nn = colg / 192, c = colg % 192;     // uniform across lanes per j
        int b2 = row0 >> 11, t2 = row0 & 2047;
        int bn2 = b2 * 8 + nn;
        if (c < 64) {
#pragma unroll
          for (int r = 0; r < 4; r++)
            Qo[((size_t)bn2 * SEQ + t2 + r) * 64 + c] = bf16u(acc[i][j][r] * 0.125f);
        } else if (c < 128) {
#pragma unroll
          for (int r = 0; r < 4; r++)
            Ko[((size_t)bn2 * SEQ + t2 + r) * 64 + (c - 64)] = bf16u(acc[i][j][r]);
        } else {
          ushort4 pk;
          pk.x = bf16u(acc[i][j][0]); pk.y = bf16u(acc[i][j][1]);
          pk.z = bf16u(acc[i][j][2]); pk.w = bf16u(acc[i][j][3]);
          *(ushort4*)&Vto[((size_t)bn2 * 64 + (c - 128)) * SEQ + t2] = pk;
        }
      }
    }
  }
}

extern "C" void kernel_launch(void* const* d_in, const int* in_sizes, int n_in,
                              void* d_out, int out_size, void* d_ws, size_t ws_size,
                              hipStream_t stream) {
  const float* X          = (const float*)d_in[0];
  const float* router_w   = (const float*)d_in[1];
  const float* mosa_wqkv  = (const float*)d_in[2];
  const float* mosa_wo    = (const float*)d_in[3];
  const float* dense_wqkv = (const float*)d_in[4];
  const float* dense_wo   = (const float*)d_in[5];
  float* out = (float*)d_out;
  char* ws = (char*)d_ws;

  // workspace layout (bytes)
  float*  scores  = (float*) (ws + 0);          // 131072
  int*    sel     = (int*)   (ws + 131072);     // 16384
  float*  gates   = (float*) (ws + 147456);     // 16384
  ushort* avm     = (ushort*)(ws + 163840);     // 4194304
  ushort* avd     = (ushort*)(ws + 4358144);    // 4194304
  ushort* Xb      = (ushort*)(ws + 8552448);    // 8388608
  ushort* Wqkv_t  = (ushort*)(ws + 16941056);   // 3145728
  ushort* Wmq_t   = (ushort*)(ws + 20086784);   // 3145728
  ushort* Wdo_t   = (ushort*)(ws + 23232512);   // 1048576
  ushort* Wmo_t   = (ushort*)(ws + 24281088);   // 1048576
  ushort* Qg      = (ushort*)(ws + 25329664);   // 4194304  (16 bn x 2048 x 64)
  ushort* Kg      = (ushort*)(ws + 29523968);   // 4194304
  ushort* Vtg     = (ushort*)(ws + 33718272);   // 4194304  (16 bn x 64 x 2048)
  ushort* Qmg     = (ushort*)(ws + 37912576);   // 524288   (16 bn x 256 x 64)
  ushort* Kmg     = (ushort*)(ws + 38436864);   // 524288
  ushort* Vtmg    = (ushort*)(ws + 38961152);   // 524288
  int*    pranks  = (int*)   (ws + 39485440);   // 16*32*2048*4 = 4194304 (end 43679744)

  hipMemsetAsync(avm, 0, (size_t)BB * SEQ * NHEAD * DH * sizeof(ushort), stream);

  // casts / transposes
  cast_bf16x4<<<4096, 256, 0, stream>>>(X, Xb, BB * SEQ * HD / 4);
  transpose_cast2<<<dim3(48, 32, 2), 256, 0, stream>>>(dense_wqkv, Wqkv_t,
                                                       mosa_wqkv, Wmq_t, 1024, 1536);
  transpose_cast2<<<dim3(32, 16, 2), 256, 0, stream>>>(dense_wo, Wdo_t,
                                                       mosa_wo, Wmo_t, 512, 1024);

  // router + top-k
  router2<<<BB * SEQ / 32, 256, 0, stream>>>(X, router_w, scores);
  topk_partial<<<dim3(BB * NHEAD, 32), 256, 0, stream>>>(scores, pranks);
  topk_select<<<BB * NHEAD, 1024, 0, stream>>>(scores, pranks, sel, gates);

  // qkv projections (mosa gathered + dense)
  gemm_mosa_bf16<<<dim3(BB * NHEAD, KSEL / 64, D3 / 64), 256, 0, stream>>>(
      Xb, Wmq_t, sel, Qmg, Kmg, Vtmg);
  rope_split<<<(BB * NHEAD * KSEL * 32) / 256, 256, 0, stream>>>(Qmg, Kmg, sel, 1);
  gemm_bf16<1><<<dim3(32, 12), 256, 0, stream>>>(Xb, Wqkv_t, 1024,
      (const ushort*)nullptr, (const ushort*)nullptr, 0, nullptr, NHEAD * D3,
      Qg, Kg, Vtg);
  rope_split<<<(BB * NHEAD * SEQ * 32) / 256, 256, 0, stream>>>(Qg, Kg, nullptr, 0);

  // combined flash attention (dense 512 blocks longest-first + mosa 64 blocks)
  flash5<<<576, 256, 0, stream>>>(Qg, Kg, Vtg, Qmg, Kmg, Vtmg, sel, gates, avd, avm);

  // final: out = avm@mosa_wo + avd@dense_wo  (f32 out)
  gemm_bf16<0><<<dim3(32, 8), 256, 0, stream>>>(avm, Wmo_t, 512, avd, Wdo_t, 512, out, HD,
                                                nullptr, nullptr, nullptr);
}

// Round 10
// 234.557 us; speedup vs baseline: 7.0675x; 1.0183x over previous
//
#include <hip/hip_runtime.h>
#include <math.h>

constexpr int BB = 2;
constexpr int SEQ = 2048;
constexpr int HD = 1024;
constexpr int DH = 64;       // head dim
constexpr int NHEAD = 8;
constexpr int D3 = 192;      // 3*DH
constexpr int KSEL = 256;    // SEQ / SPARSITY
constexpr float NEG = -1e30f;

typedef short short8 __attribute__((ext_vector_type(8)));
typedef float f32x4 __attribute__((ext_vector_type(4)));

__device__ __forceinline__ ushort bf16u(float f) {
  union { float f; unsigned u; } v; v.f = f;
  unsigned r = (v.u + 0x7FFFu + ((v.u >> 16) & 1u)) >> 16;
  return (ushort)r;
}
__device__ __forceinline__ float bf2f(ushort h) {
  union { unsigned u; float f; } v; v.u = ((unsigned)h) << 16;
  return v.f;
}

// async global->LDS, 16B per lane; LDS dest = wave-uniform base + lane*16
__device__ __forceinline__ void gl_lds16(const ushort* g, ushort* l) {
  __builtin_amdgcn_global_load_lds(
      (const __attribute__((address_space(1))) unsigned int*)g,
      (__attribute__((address_space(3))) unsigned int*)l, 16, 0, 0);
}

// order-preserving composite key: rank predicate (s_j > s_i) || (s_j==s_i && j<i)
// becomes key_j > key_i  (single u64 compare)
__device__ __forceinline__ unsigned long long rankkey(float s, int idx) {
  union { float f; unsigned u; } v; v.f = s;
  unsigned o = (v.u & 0x80000000u) ? ~v.u : (v.u | 0x80000000u);
  return ((unsigned long long)o << 11) | (unsigned)(2047 - idx);
}

// ---------------- cast f32 -> bf16, 4 elems/thread ----------------
__global__ void cast_bf16x4(const float* __restrict__ x, ushort* __restrict__ y, int n4) {
  int i = blockIdx.x * 256 + threadIdx.x;
  if (i >= n4) return;
  float4 v = ((const float4*)x)[i];
  ushort4 r; r.x = bf16u(v.x); r.y = bf16u(v.y); r.z = bf16u(v.z); r.w = bf16u(v.w);
  ((ushort4*)y)[i] = r;
}

// ---------------- transpose + cast pair: W[K][N] f32 -> Wt[N][K] bf16 ----------------
__global__ __launch_bounds__(256) void transpose_cast2(
    const float* __restrict__ W1, ushort* __restrict__ T1,
    const float* __restrict__ W2, ushort* __restrict__ T2, int K, int N) {
  const float* W = blockIdx.z ? W2 : W1;
  ushort* Wt = blockIdx.z ? T2 : T1;
  __shared__ float tile[32][33];
  int n0 = blockIdx.x * 32, k0 = blockIdx.y * 32;
  int tx = threadIdx.x & 31, ty = threadIdx.x >> 5;
#pragma unroll
  for (int i = 0; i < 4; i++)
    tile[ty + 8 * i][tx] = W[(size_t)(k0 + ty + 8 * i) * N + n0 + tx];
  __syncthreads();
#pragma unroll
  for (int i = 0; i < 4; i++)
    Wt[(size_t)(n0 + ty + 8 * i) * K + k0 + tx] = bf16u(tile[tx][ty + 8 * i]);
}

// ---------------- router v2: register-blocked, 32 rows/block ----------------
__global__ __launch_bounds__(256) void router2(const float* __restrict__ X,
    const float* __restrict__ rw, float* __restrict__ scores) {
  __shared__ float rwT[8][8][132];          // [n][seg][128+4pad]
  int tid = threadIdx.x;
  for (int idx = tid; idx < 8192; idx += 256) {
    int h = idx & 1023, n = idx >> 10;
    rwT[n][h >> 7][h & 127] = rw[h * 8 + n];
  }
  __syncthreads();
  int row = blockIdx.x * 32 + (tid >> 3);   // bt row
  int seg = tid & 7;
  const float* xrow = X + (size_t)row * HD + seg * 128;
  float acc[8] = {};
#pragma unroll 8
  for (int it = 0; it < 32; it++) {
    float4 xv = *(const float4*)(xrow + 4 * it);
#pragma unroll
    for (int n = 0; n < 8; n++) {
      float4 rv = *(const float4*)&rwT[n][seg][4 * it];
      acc[n] += xv.x * rv.x + xv.y * rv.y + xv.z * rv.z + xv.w * rv.w;
    }
  }
#pragma unroll
  for (int n = 0; n < 8; n++) {
    acc[n] += __shfl_xor(acc[n], 1);
    acc[n] += __shfl_xor(acc[n], 2);
    acc[n] += __shfl_xor(acc[n], 4);
  }
  int b = row >> 11, t2 = row & (SEQ - 1);
  scores[((size_t)b * NHEAD + seg) * SEQ + t2] = acc[seg];
}

// ---------------- top-k stage 1: u64-key partial rank counts (32 chunks of 64) ----------
__global__ __launch_bounds__(256) void topk_partial(const float* __restrict__ scores,
    int* __restrict__ pranks) {
  int row = blockIdx.x;                      // 16
  int c = blockIdx.y;                        // 32 chunks of 64 j
  __shared__ unsigned long long ck[64];
  const float* sp = scores + (size_t)row * SEQ;
  int tid = threadIdx.x;
  if (tid < 64) ck[tid] = rankkey(sp[c * 64 + tid], c * 64 + tid);
  __syncthreads();
  unsigned long long kv[8]; int p[8];
#pragma unroll
  for (int i = 0; i < 8; i++) {
    int vi = i * 256 + tid;
    kv[i] = rankkey(sp[vi], vi);
    p[i] = 0;
  }
#pragma unroll 8
  for (int j = 0; j < 64; j += 2) {
    unsigned long long k0 = ck[j], k1 = ck[j + 1];
#pragma unroll
    for (int i = 0; i < 8; i++) {
      p[i] += (k0 > kv[i]);
      p[i] += (k1 > kv[i]);
    }
  }
#pragma unroll
  for (int i = 0; i < 8; i++)
    pranks[((size_t)row * 32 + c) * SEQ + i * 256 + tid] = p[i];
}

// ---------------- top-k stage 2: sum partials, ballot-scan, emit ----------------
__global__ __launch_bounds__(1024) void topk_select(const float* __restrict__ scores,
    const int* __restrict__ pranks, int* __restrict__ sel, float* __restrict__ gates) {
  int bn = blockIdx.x;
  __shared__ int wsum[16];
  int tid = threadIdx.x;
  int t0 = tid * 2;
  int r0 = 0, r1 = 0;
#pragma unroll
  for (int c = 0; c < 32; c++) {
    const int2 pp = *(const int2*)&pranks[((size_t)bn * 32 + c) * SEQ + t0];
    r0 += pp.x; r1 += pp.y;
  }
  int f0 = r0 < KSEL, f1 = r1 < KSEL;
  unsigned long long b0 = __ballot(f0), b1 = __ballot(f1);
  int lane = tid & 63, wv = tid >> 6;
  unsigned long long lower = (1ULL << lane) - 1ULL;
  int before = __popcll(b0 & lower) + __popcll(b1 & lower);
  int wtotal = __popcll(b0) + __popcll(b1);
  if (lane == 0) wsum[wv] = wtotal;
  __syncthreads();
  int woff = 0;
#pragma unroll
  for (int i2 = 0; i2 < 16; i2++) woff += (i2 < wv) ? wsum[i2] : 0;
  int base = woff + before;
  if (f0) { sel[bn * KSEL + base] = t0;
            gates[bn * KSEL + base] = 1.f / (1.f + __expf(-scores[(size_t)bn * SEQ + t0]));
            base++; }
  if (f1) { sel[bn * KSEL + base] = t0 + 1;
            gates[bn * KSEL + base] = 1.f / (1.f + __expf(-scores[(size_t)bn * SEQ + t0 + 1])); }
}

// ---------------- mosa qkv: gathered-A bf16 MFMA GEMM -> split Q/K/V^T layouts ----------
__global__ __launch_bounds__(256) void gemm_mosa_bf16(const ushort* __restrict__ Xb,
    const ushort* __restrict__ Wt, const int* __restrict__ sel,
    ushort* __restrict__ Qmg, ushort* __restrict__ Kmg, ushort* __restrict__ Vtmg) {
  __shared__ __align__(16) ushort As[64][40];
  __shared__ __align__(16) ushort Bs[64][40];
  int bn = blockIdx.x; int b = bn >> 3, n = bn & 7;
  int m0 = blockIdx.y * 64, n0 = blockIdx.z * 64;
  int tid = threadIdx.x;
  int lane = tid & 63, w = tid >> 6;
  int wm = w & 1, wn = w >> 1;
  int cc = lane & 15, quad = lane >> 4;
  int sr = tid >> 2, sc4 = tid & 3;

  int grow = sel[bn * KSEL + m0 + sr];
  const ushort* arow = Xb + ((size_t)(b * SEQ) + grow) * HD;
  const ushort* brow = Wt + ((size_t)(n * D3 + n0 + sr)) * HD;

  f32x4 acc[2][2];
#pragma unroll
  for (int i = 0; i < 2; i++)
#pragma unroll
    for (int j = 0; j < 2; j++)
#pragma unroll
      for (int r = 0; r < 4; r++) acc[i][j][r] = 0.f;

  for (int k0 = 0; k0 < HD; k0 += 32) {
    __syncthreads();
    *(short8*)&As[sr][8 * sc4] = *(const short8*)(arow + k0 + 8 * sc4);
    *(short8*)&Bs[sr][8 * sc4] = *(const short8*)(brow + k0 + 8 * sc4);
    __syncthreads();
    short8 af[2], bf_[2];
#pragma unroll
    for (int i = 0; i < 2; i++) af[i] = *(const short8*)&As[32 * wm + 16 * i + cc][8 * quad];
#pragma unroll
    for (int j = 0; j < 2; j++) bf_[j] = *(const short8*)&Bs[32 * wn + 16 * j + cc][8 * quad];
#pragma unroll
    for (int i = 0; i < 2; i++)
#pragma unroll
      for (int j = 0; j < 2; j++)
        acc[i][j] = __builtin_amdgcn_mfma_f32_16x16x32_bf16(af[i], bf_[j], acc[i][j], 0, 0, 0);
  }

#pragma unroll
  for (int i = 0; i < 2; i++)
#pragma unroll
    for (int j = 0; j < 2; j++) {
      int col = n0 + 32 * wn + 16 * j + cc;   // 0..191, segment = n0 (uniform)
      int row0 = m0 + 32 * wm + 16 * i + 4 * quad;
      if (col < 64) {
#pragma unroll
        for (int r = 0; r < 4; r++)
          Qmg[((size_t)bn * KSEL + row0 + r) * 64 + col] = bf16u(acc[i][j][r] * 0.125f);
      } else if (col < 128) {
#pragma unroll
        for (int r = 0; r < 4; r++)
          Kmg[((size_t)bn * KSEL + row0 + r) * 64 + (col - 64)] = bf16u(acc[i][j][r]);
      } else {
        ushort4 pk;
        pk.x = bf16u(acc[i][j][0]); pk.y = bf16u(acc[i][j][1]);
        pk.z = bf16u(acc[i][j][2]); pk.w = bf16u(acc[i][j][3]);
        *(ushort4*)&Vtmg[((size_t)bn * 64 + (col - 128)) * KSEL + row0] = pk;
      }
    }
}

// ---------------- RoPE on split Q/K layouts (rows of 64) ----------------
__global__ void rope_split(ushort* __restrict__ Qb, ushort* __restrict__ Kb,
                           const int* __restrict__ sel, int mosa) {
  int tid = blockIdx.x * 256 + threadIdx.x;
  int j = tid & 15;
  int which = (tid >> 4) & 1;                 // 0: Q, 1: K
  int row = tid >> 5;
  float pos = mosa ? (float)sel[row] : (float)(row & (SEQ - 1));
  float inv = __expf((float)j * -0.5756462732485115f);
  float ang = pos * inv;
  float c = cosf(ang), sn = sinf(ang);
  ushort* p = (which ? Kb : Qb) + (size_t)row * 64 + j;
  float x1 = bf2f(p[0]), x2 = bf2f(p[16]);
  p[0] = bf16u(x1 * c - x2 * sn);
  p[16] = bf16u(x1 * sn + x2 * c);
}

// ---------------- flash5: 256-thr blocks, Q-in-regs, async dbuf staging ----------------
// Dense qt remap pairs (31-pr) with (pr-16) at bx and bx+256 so every CU gets ~33
// tile-units under round-robin block->CU assignment (fixes R9's 52-vs-18 imbalance).
__global__ __launch_bounds__(256) void flash5(
    const ushort* __restrict__ Qg, const ushort* __restrict__ Kg,
    const ushort* __restrict__ Vtg,
    const ushort* __restrict__ Qmg, const ushort* __restrict__ Kmg,
    const ushort* __restrict__ Vtmg,
    const int* __restrict__ sel, const float* __restrict__ gates,
    ushort* __restrict__ avd, ushort* __restrict__ avm) {
  __shared__ __align__(16) ushort Ks[2][64][64];
  __shared__ __align__(16) ushort Vt[2][64][64];
  __shared__ __align__(16) ushort Ps[64][64];

  int bx = blockIdx.x;
  bool mosa = bx >= 512;
  int bn, qt, T;
  const ushort *Qb, *Kb, *Vb;
  ushort* outp;
  if (!mosa) {
    bn = bx & 15;
    int pr = bx >> 4;                    // 0..31
    qt = (pr < 16) ? (31 - pr) : (pr - 16);   // balanced pairing across CUs
    T = SEQ;
    Qb = Qg + (size_t)bn * SEQ * 64;
    Kb = Kg + (size_t)bn * SEQ * 64;
    Vb = Vtg + (size_t)bn * 64 * SEQ;
    outp = avd;
  } else {
    int rr = bx - 512;
    bn = rr & 15; qt = 3 - (rr >> 4); T = KSEL;
    Qb = Qmg + (size_t)bn * KSEL * 64;
    Kb = Kmg + (size_t)bn * KSEL * 64;
    Vb = Vtmg + (size_t)bn * 64 * KSEL;
    outp = avm;
  }
  int b = bn >> 3, n = bn & 7;
  int tid = threadIdx.x;
  int lane = tid & 63, w = tid >> 6;
  int cc = lane & 15, quad = lane >> 4;
  int qrow = 16 * w + cc;

  // Q fragments straight from global (pre-scaled by 1/8 upstream); loop-invariant
  short8 bq[2];
  {
    const ushort* qsrc = Qb + (size_t)(qt * 64 + qrow) * 64;
    bq[0] = *(const short8*)(qsrc + 8 * quad);
    bq[1] = *(const short8*)(qsrc + 8 * (quad + 4));
  }

  // staging addresses: slice = 8 rows x 128B per wave-instr; lane l -> row +(l>>3),
  // phys chunk l&7 holds logical chunk (l&7)^(row&7)  (xor swizzle inverse)
  int rloc = lane >> 3;
  int c_log = (lane & 7) ^ rloc;
  int row0 = 16 * w + rloc, row1 = row0 + 8;
  const ushort* pK0 = Kb + (size_t)row0 * 64 + 8 * c_log;
  const ushort* pK1 = Kb + (size_t)row1 * 64 + 8 * c_log;
  const ushort* pV0 = Vb + (size_t)row0 * T + 8 * c_log;
  const ushort* pV1 = Vb + (size_t)row1 * T + 8 * c_log;

  f32x4 oacc[4];
  float m = NEG, l = 0.f;
#pragma unroll
  for (int jd = 0; jd < 4; jd++)
#pragma unroll
    for (int r = 0; r < 4; r++) oacc[jd][r] = 0.f;

  // prefetch tile 0 into buf 0
  gl_lds16(pK0, &Ks[0][16 * w][0]);
  gl_lds16(pK1, &Ks[0][16 * w + 8][0]);
  gl_lds16(pV0, &Vt[0][16 * w][0]);
  gl_lds16(pV1, &Vt[0][16 * w + 8][0]);

  for (int kt = 0; kt <= qt; kt++) {
    int buf = kt & 1;
    __syncthreads();          // implicit vmcnt(0): buf's loads complete; prev buf free
    if (kt < qt) {
      int nk = kt + 1, nb = buf ^ 1;
      gl_lds16(pK0 + (size_t)nk * 4096, &Ks[nb][16 * w][0]);
      gl_lds16(pK1 + (size_t)nk * 4096, &Ks[nb][16 * w + 8][0]);
      gl_lds16(pV0 + nk * 64, &Vt[nb][16 * w][0]);
      gl_lds16(pV1 + nk * 64, &Vt[nb][16 * w + 8][0]);
    }

    // S^T = K.Q^T : C col = q (cc), row = key (16j + 4quad + r)
    f32x4 sacc[4];
#pragma unroll
    for (int j = 0; j < 4; j++)
#pragma unroll
      for (int r = 0; r < 4; r++) sacc[j][r] = 0.f;
#pragma unroll
    for (int ks = 0; ks < 2; ks++) {
#pragma unroll
      for (int j = 0; j < 4; j++) {
        int krow = 16 * j + cc;
        short8 ak = *(const short8*)&Ks[buf][krow][8 * ((quad + 4 * ks) ^ (krow & 7))];
        sacc[j] = __builtin_amdgcn_mfma_f32_16x16x32_bf16(ak, bq[ks], sacc[j], 0, 0, 0);
      }
    }
    if (kt == qt) {
#pragma unroll
      for (int j = 0; j < 4; j++)
#pragma unroll
        for (int r = 0; r < 4; r++)
          if (16 * j + 4 * quad + r > qrow) sacc[j][r] = NEG;
    }
    // per-lane online softmax (q = 16w+cc fixed per lane)
    float mx = NEG;
#pragma unroll
    for (int j = 0; j < 4; j++)
#pragma unroll
      for (int r = 0; r < 4; r++) mx = fmaxf(mx, sacc[j][r]);
    mx = fmaxf(mx, __shfl_xor(mx, 16));
    mx = fmaxf(mx, __shfl_xor(mx, 32));
    float mn = fmaxf(m, mx);
    float sc = __expf(m - mn);
    m = mn;
    float rsum = 0.f;
    float p[4][4];
#pragma unroll
    for (int j = 0; j < 4; j++)
#pragma unroll
      for (int r = 0; r < 4; r++) { p[j][r] = __expf(sacc[j][r] - mn); rsum += p[j][r]; }
    rsum += __shfl_xor(rsum, 16);
    rsum += __shfl_xor(rsum, 32);
    l = l * sc + rsum;
    // Ps[q][key] packed b64 (wave-local rows)
#pragma unroll
    for (int j = 0; j < 4; j++) {
      ushort4 pk;
      pk.x = bf16u(p[j][0]); pk.y = bf16u(p[j][1]);
      pk.z = bf16u(p[j][2]); pk.w = bf16u(p[j][3]);
      int phys = (2 * j + (quad >> 1)) ^ (qrow & 7);
      *(ushort4*)&Ps[qrow][phys * 8 + 4 * (quad & 1)] = pk;
    }
    // rescale O rows (q-local = 4quad+r) by that q's sc
#pragma unroll
    for (int r = 0; r < 4; r++) {
      float scr = __shfl(sc, 16 * quad + 4 * quad + r);
#pragma unroll
      for (int jd = 0; jd < 4; jd++) oacc[jd][r] *= scr;
    }
    __asm__ volatile("s_waitcnt lgkmcnt(0)" ::: "memory");
    // O += P.V
#pragma unroll
    for (int ks = 0; ks < 2; ks++) {
      short8 ap = *(const short8*)&Ps[qrow][8 * ((quad + 4 * ks) ^ (qrow & 7))];
#pragma unroll
      for (int jd = 0; jd < 4; jd++) {
        int vrow = 16 * jd + cc;
        short8 bv = *(const short8*)&Vt[buf][vrow][8 * ((quad + 4 * ks) ^ (vrow & 7))];
        oacc[jd] = __builtin_amdgcn_mfma_f32_16x16x32_bf16(ap, bv, oacc[jd], 0, 0, 0);
      }
    }
  }

  // epilogue: q = qt*64 + 16w + 4quad + r, d = 16jd + cc
#pragma unroll
  for (int r = 0; r < 4; r++) {
    float lr = __shfl(l, 16 * quad + 4 * quad + r);
    int q = qt * 64 + 16 * w + 4 * quad + r;
    float scale;
    size_t row;
    if (mosa) {
      int trow = sel[bn * KSEL + q];
      scale = gates[bn * KSEL + q] / lr;
      row = (size_t)(b * SEQ + trow);
    } else {
      scale = 1.f / lr;
      row = (size_t)(b * SEQ + q);
    }
    ushort* orow = outp + row * (NHEAD * DH) + n * DH;
#pragma unroll
    for (int jd = 0; jd < 4; jd++)
      orow[16 * jd + cc] = bf16u(oacc[jd][r] * scale);
  }
}

// ---------------- bf16 MFMA GEMM, 128x128 tile, BK=32, async gl_lds staging ----------
// MODE 0: out f32 = A1@B1 + A2@B2.  MODE 1: dense-qkv scatter into Qg/Kg/Vtg.
// Staging via global_load_lds: wave w fills rows 16w..16w+15 (and +64); lane l loads
// logical chunk ((l&3)-(l>>3))&3 so the LDS swizzle ((c + row/2)&3) lands at l&3.
template <int MODE>
__global__ __launch_bounds__(256) void gemm_bf16(
    const ushort* __restrict__ A1, const ushort* __restrict__ B1t, int K1,
    const ushort* __restrict__ A2, const ushort* __restrict__ B2t, int K2,
    void* __restrict__ outv, int N,
    ushort* __restrict__ Qo, ushort* __restrict__ Ko, ushort* __restrict__ Vto) {
  __shared__ __align__(16) ushort As[128][32];
  __shared__ __align__(16) ushort Bs[128][32];
  int m0 = blockIdx.x * 128, n0 = blockIdx.y * 128;
  int tid = threadIdx.x;
  int lane = tid & 63, wave = tid >> 6;
  int wm = wave & 1, wn = wave >> 1;
  int cc = lane & 15, quad = lane >> 4;

  // gl_lds staging geometry
  int srow = 16 * wave + (lane >> 2);              // row within 0..63 half
  int c_log = ((lane & 3) - (lane >> 3)) & 3;      // swizzle-inverse chunk

  f32x4 acc[4][4];
#pragma unroll
  for (int i = 0; i < 4; i++)
#pragma unroll
    for (int j = 0; j < 4; j++)
#pragma unroll
      for (int r = 0; r < 4; r++) acc[i][j][r] = 0.f;

  const int npass = (MODE == 0) ? 2 : 1;
  for (int pass = 0; pass < npass; pass++) {
    const ushort* A = pass ? A2 : A1;
    const ushort* Bt = pass ? B2t : B1t;
    int K = pass ? K2 : K1;
    const ushort* pA0 = A + (size_t)(m0 + srow) * K + 8 * c_log;
    const ushort* pA1 = A + (size_t)(m0 + srow + 64) * K + 8 * c_log;
    const ushort* pB0 = Bt + (size_t)(n0 + srow) * K + 8 * c_log;
    const ushort* pB1 = Bt + (size_t)(n0 + srow + 64) * K + 8 * c_log;
    for (int k0 = 0; k0 < K; k0 += 32) {
      __syncthreads();                      // prev iter's frags consumed
      gl_lds16(pA0 + k0, &As[16 * wave][0]);
      gl_lds16(pA1 + k0, &As[16 * wave + 64][0]);
      gl_lds16(pB0 + k0, &Bs[16 * wave][0]);
      gl_lds16(pB1 + k0, &Bs[16 * wave + 64][0]);
      __syncthreads();                      // implicit vmcnt(0): tiles ready
      short8 af[4], bfr[4];
#pragma unroll
      for (int i = 0; i < 4; i++) {
        int ra = 64 * wm + 16 * i + cc;
        af[i] = *(const short8*)&As[ra][8 * ((quad + (ra >> 1)) & 3)];
      }
#pragma unroll
      for (int j = 0; j < 4; j++) {
        int rb = 64 * wn + 16 * j + cc;
        bfr[j] = *(const short8*)&Bs[rb][8 * ((quad + (rb >> 1)) & 3)];
      }
#pragma unroll
      for (int i = 0; i < 4; i++)
#pragma unroll
        for (int j = 0; j < 4; j++)
          acc[i][j] = __builtin_amdgcn_mfma_f32_16x16x32_bf16(af[i], bfr[j], acc[i][j], 0, 0, 0);
    }
  }

#pragma unroll
  for (int i = 0; i < 4; i++) {
#pragma unroll
    for (int j = 0; j < 4; j++) {
      int colg = n0 + 64 * wn + 16 * j + cc;
      int row0 = m0 + 64 * wm + 16 * i + 4 * quad;
      if (MODE == 0) {
#pragma unroll
        for (int r = 0; r < 4; r++)
          ((float*)outv)[(size_t)(row0 + r) * N + colg] = acc[i][j][r];
      } else {
        int nn = colg / 192, c = colg % 192;     // uniform across lanes per j
        int b2 = row0 >> 11, t2 = row0 & 2047;
        int bn2 = b2 * 8 + nn;
        if (c < 64) {
#pragma unroll
          for (int r = 0; r < 4; r++)
            Qo[((size_t)bn2 * SEQ + t2 + r) * 64 + c] = bf16u(acc[i][j][r] * 0.125f);
        } else if (c < 128) {
#pragma unroll
          for (int r = 0; r < 4; r++)
            Ko[((size_t)bn2 * SEQ + t2 + r) * 64 + (c - 64)] = bf16u(acc[i][j][r]);
        } else {
          ushort4 pk;
          pk.x = bf16u(acc[i][j][0]); pk.y = bf16u(acc[i][j][1]);
          pk.z = bf16u(acc[i][j][2]); pk.w = bf16u(acc[i][j][3]);
          *(ushort4*)&Vto[((size_t)bn2 * 64 + (c - 128)) * SEQ + t2] = pk;
        }
      }
    }
  }
}

extern "C" void kernel_launch(void* const* d_in, const int* in_sizes, int n_in,
                              void* d_out, int out_size, void* d_ws, size_t ws_size,
                              hipStream_t stream) {
  const float* X          = (const float*)d_in[0];
  const float* router_w   = (const float*)d_in[1];
  const float* mosa_wqkv  = (const float*)d_in[2];
  const float* mosa_wo    = (const float*)d_in[3];
  const float* dense_wqkv = (const float*)d_in[4];
  const float* dense_wo   = (const float*)d_in[5];
  float* out = (float*)d_out;
  char* ws = (char*)d_ws;

  // workspace layout (bytes)
  float*  scores  = (float*) (ws + 0);          // 131072
  int*    sel     = (int*)   (ws + 131072);     // 16384
  float*  gates   = (float*) (ws + 147456);     // 16384
  ushort* avm     = (ushort*)(ws + 163840);     // 4194304
  ushort* avd     = (ushort*)(ws + 4358144);    // 4194304
  ushort* Xb      = (ushort*)(ws + 8552448);    // 8388608
  ushort* Wqkv_t  = (ushort*)(ws + 16941056);   // 3145728
  ushort* Wmq_t   = (ushort*)(ws + 20086784);   // 3145728
  ushort* Wdo_t   = (ushort*)(ws + 23232512);   // 1048576
  ushort* Wmo_t   = (ushort*)(ws + 24281088);   // 1048576
  ushort* Qg      = (ushort*)(ws + 25329664);   // 4194304  (16 bn x 2048 x 64)
  ushort* Kg      = (ushort*)(ws + 29523968);   // 4194304
  ushort* Vtg     = (ushort*)(ws + 33718272);   // 4194304  (16 bn x 64 x 2048)
  ushort* Qmg     = (ushort*)(ws + 37912576);   // 524288   (16 bn x 256 x 64)
  ushort* Kmg     = (ushort*)(ws + 38436864);   // 524288
  ushort* Vtmg    = (ushort*)(ws + 38961152);   // 524288
  int*    pranks  = (int*)   (ws + 39485440);   // 16*32*2048*4 = 4194304 (end 43679744)

  hipMemsetAsync(avm, 0, (size_t)BB * SEQ * NHEAD * DH * sizeof(ushort), stream);

  // casts / transposes
  cast_bf16x4<<<4096, 256, 0, stream>>>(X, Xb, BB * SEQ * HD / 4);
  transpose_cast2<<<dim3(48, 32, 2), 256, 0, stream>>>(dense_wqkv, Wqkv_t,
                                                       mosa_wqkv, Wmq_t, 1024, 1536);
  transpose_cast2<<<dim3(32, 16, 2), 256, 0, stream>>>(dense_wo, Wdo_t,
                                                       mosa_wo, Wmo_t, 512, 1024);

  // router + top-k
  router2<<<BB * SEQ / 32, 256, 0, stream>>>(X, router_w, scores);
  topk_partial<<<dim3(BB * NHEAD, 32), 256, 0, stream>>>(scores, pranks);
  topk_select<<<BB * NHEAD, 1024, 0, stream>>>(scores, pranks, sel, gates);

  // qkv projections (mosa gathered + dense)
  gemm_mosa_bf16<<<dim3(BB * NHEAD, KSEL / 64, D3 / 64), 256, 0, stream>>>(
      Xb, Wmq_t, sel, Qmg, Kmg, Vtmg);
  rope_split<<<(BB * NHEAD * KSEL * 32) / 256, 256, 0, stream>>>(Qmg, Kmg, sel, 1);
  gemm_bf16<1><<<dim3(32, 12), 256, 0, stream>>>(Xb, Wqkv_t, 1024,
      (const ushort*)nullptr, (const ushort*)nullptr, 0, nullptr, NHEAD * D3,
      Qg, Kg, Vtg);
  rope_split<<<(BB * NHEAD * SEQ * 32) / 256, 256, 0, stream>>>(Qg, Kg, nullptr, 0);

  // combined flash attention (dense 512 blocks CU-balanced + mosa 64 blocks)
  flash5<<<576, 256, 0, stream>>>(Qg, Kg, Vtg, Qmg, Kmg, Vtmg, sel, gates, avd, avm);

  // final: out = avm@mosa_wo + avd@dense_wo  (f32 out)
  gemm_bf16<0><<<dim3(32, 8), 256, 0, stream>>>(avm, Wmo_t, 512, avd, Wdo_t, 512, out, HD,
                                                nullptr, nullptr, nullptr);
}

// Round 11
// 224.784 us; speedup vs baseline: 7.3748x; 1.0435x over previous
//
#include <hip/hip_runtime.h>
#include <math.h>

constexpr int BB = 2;
constexpr int SEQ = 2048;
constexpr int HD = 1024;
constexpr int DH = 64;       // head dim
constexpr int NHEAD = 8;
constexpr int D3 = 192;      // 3*DH
constexpr int KSEL = 256;    // SEQ / SPARSITY
constexpr float NEG = -1e30f;

typedef short short8 __attribute__((ext_vector_type(8)));
typedef float f32x4 __attribute__((ext_vector_type(4)));

__device__ __forceinline__ ushort bf16u(float f) {
  union { float f; unsigned u; } v; v.f = f;
  unsigned r = (v.u + 0x7FFFu + ((v.u >> 16) & 1u)) >> 16;
  return (ushort)r;
}
__device__ __forceinline__ float bf2f(ushort h) {
  union { unsigned u; float f; } v; v.u = ((unsigned)h) << 16;
  return v.f;
}

// async global->LDS, 16B per lane; LDS dest = wave-uniform base + lane*16
__device__ __forceinline__ void gl_lds16(const ushort* g, ushort* l) {
  __builtin_amdgcn_global_load_lds(
      (const __attribute__((address_space(1))) unsigned int*)g,
      (__attribute__((address_space(3))) unsigned int*)l, 16, 0, 0);
}

// order-preserving composite key: rank predicate (s_j > s_i) || (s_j==s_i && j<i)
// becomes key_j > key_i  (single u64 compare)
__device__ __forceinline__ unsigned long long rankkey(float s, int idx) {
  union { float f; unsigned u; } v; v.f = s;
  unsigned o = (v.u & 0x80000000u) ? ~v.u : (v.u | 0x80000000u);
  return ((unsigned long long)o << 11) | (unsigned)(2047 - idx);
}

// ---------------- cast f32 -> bf16, 4 elems/thread ----------------
__global__ void cast_bf16x4(const float* __restrict__ x, ushort* __restrict__ y, int n4) {
  int i = blockIdx.x * 256 + threadIdx.x;
  if (i >= n4) return;
  float4 v = ((const float4*)x)[i];
  ushort4 r; r.x = bf16u(v.x); r.y = bf16u(v.y); r.z = bf16u(v.z); r.w = bf16u(v.w);
  ((ushort4*)y)[i] = r;
}

// ---------------- transpose + cast pair: W[K][N] f32 -> Wt[N][K] bf16 ----------------
__global__ __launch_bounds__(256) void transpose_cast2(
    const float* __restrict__ W1, ushort* __restrict__ T1,
    const float* __restrict__ W2, ushort* __restrict__ T2, int K, int N) {
  const float* W = blockIdx.z ? W2 : W1;
  ushort* Wt = blockIdx.z ? T2 : T1;
  __shared__ float tile[32][33];
  int n0 = blockIdx.x * 32, k0 = blockIdx.y * 32;
  int tx = threadIdx.x & 31, ty = threadIdx.x >> 5;
#pragma unroll
  for (int i = 0; i < 4; i++)
    tile[ty + 8 * i][tx] = W[(size_t)(k0 + ty + 8 * i) * N + n0 + tx];
  __syncthreads();
#pragma unroll
  for (int i = 0; i < 4; i++)
    Wt[(size_t)(n0 + ty + 8 * i) * K + k0 + tx] = bf16u(tile[tx][ty + 8 * i]);
}

// ---------------- router v2: register-blocked, 32 rows/block ----------------
__global__ __launch_bounds__(256) void router2(const float* __restrict__ X,
    const float* __restrict__ rw, float* __restrict__ scores) {
  __shared__ float rwT[8][8][132];          // [n][seg][128+4pad]
  int tid = threadIdx.x;
  for (int idx = tid; idx < 8192; idx += 256) {
    int h = idx & 1023, n = idx >> 10;
    rwT[n][h >> 7][h & 127] = rw[h * 8 + n];
  }
  __syncthreads();
  int row = blockIdx.x * 32 + (tid >> 3);   // bt row
  int seg = tid & 7;
  const float* xrow = X + (size_t)row * HD + seg * 128;
  float acc[8] = {};
#pragma unroll 8
  for (int it = 0; it < 32; it++) {
    float4 xv = *(const float4*)(xrow + 4 * it);
#pragma unroll
    for (int n = 0; n < 8; n++) {
      float4 rv = *(const float4*)&rwT[n][seg][4 * it];
      acc[n] += xv.x * rv.x + xv.y * rv.y + xv.z * rv.z + xv.w * rv.w;
    }
  }
#pragma unroll
  for (int n = 0; n < 8; n++) {
    acc[n] += __shfl_xor(acc[n], 1);
    acc[n] += __shfl_xor(acc[n], 2);
    acc[n] += __shfl_xor(acc[n], 4);
  }
  int b = row >> 11, t2 = row & (SEQ - 1);
  scores[((size_t)b * NHEAD + seg) * SEQ + t2] = acc[seg];
}

// ---------------- top-k stage 1: u64-key partial rank counts (32 chunks of 64) ----------
__global__ __launch_bounds__(256) void topk_partial(const float* __restrict__ scores,
    int* __restrict__ pranks) {
  int row = blockIdx.x;                      // 16
  int c = blockIdx.y;                        // 32 chunks of 64 j
  __shared__ unsigned long long ck[64];
  const float* sp = scores + (size_t)row * SEQ;
  int tid = threadIdx.x;
  if (tid < 64) ck[tid] = rankkey(sp[c * 64 + tid], c * 64 + tid);
  __syncthreads();
  unsigned long long kv[8]; int p[8];
#pragma unroll
  for (int i = 0; i < 8; i++) {
    int vi = i * 256 + tid;
    kv[i] = rankkey(sp[vi], vi);
    p[i] = 0;
  }
#pragma unroll 8
  for (int j = 0; j < 64; j += 2) {
    unsigned long long k0 = ck[j], k1 = ck[j + 1];
#pragma unroll
    for (int i = 0; i < 8; i++) {
      p[i] += (k0 > kv[i]);
      p[i] += (k1 > kv[i]);
    }
  }
#pragma unroll
  for (int i = 0; i < 8; i++)
    pranks[((size_t)row * 32 + c) * SEQ + i * 256 + tid] = p[i];
}

// ---------------- top-k stage 2: sum partials, ballot-scan, emit ----------------
__global__ __launch_bounds__(1024) void topk_select(const float* __restrict__ scores,
    const int* __restrict__ pranks, int* __restrict__ sel, float* __restrict__ gates) {
  int bn = blockIdx.x;
  __shared__ int wsum[16];
  int tid = threadIdx.x;
  int t0 = tid * 2;
  int r0 = 0, r1 = 0;
#pragma unroll
  for (int c = 0; c < 32; c++) {
    const int2 pp = *(const int2*)&pranks[((size_t)bn * 32 + c) * SEQ + t0];
    r0 += pp.x; r1 += pp.y;
  }
  int f0 = r0 < KSEL, f1 = r1 < KSEL;
  unsigned long long b0 = __ballot(f0), b1 = __ballot(f1);
  int lane = tid & 63, wv = tid >> 6;
  unsigned long long lower = (1ULL << lane) - 1ULL;
  int before = __popcll(b0 & lower) + __popcll(b1 & lower);
  int wtotal = __popcll(b0) + __popcll(b1);
  if (lane == 0) wsum[wv] = wtotal;
  __syncthreads();
  int woff = 0;
#pragma unroll
  for (int i2 = 0; i2 < 16; i2++) woff += (i2 < wv) ? wsum[i2] : 0;
  int base = woff + before;
  if (f0) { sel[bn * KSEL + base] = t0;
            gates[bn * KSEL + base] = 1.f / (1.f + __expf(-scores[(size_t)bn * SEQ + t0]));
            base++; }
  if (f1) { sel[bn * KSEL + base] = t0 + 1;
            gates[bn * KSEL + base] = 1.f / (1.f + __expf(-scores[(size_t)bn * SEQ + t0 + 1])); }
}

// ---------------- mosa qkv: gathered-A bf16 MFMA GEMM -> split Q/K/V^T layouts ----------
__global__ __launch_bounds__(256) void gemm_mosa_bf16(const ushort* __restrict__ Xb,
    const ushort* __restrict__ Wt, const int* __restrict__ sel,
    ushort* __restrict__ Qmg, ushort* __restrict__ Kmg, ushort* __restrict__ Vtmg) {
  __shared__ __align__(16) ushort As[64][40];
  __shared__ __align__(16) ushort Bs[64][40];
  int bn = blockIdx.x; int b = bn >> 3, n = bn & 7;
  int m0 = blockIdx.y * 64, n0 = blockIdx.z * 64;
  int tid = threadIdx.x;
  int lane = tid & 63, w = tid >> 6;
  int wm = w & 1, wn = w >> 1;
  int cc = lane & 15, quad = lane >> 4;
  int sr = tid >> 2, sc4 = tid & 3;

  int grow = sel[bn * KSEL + m0 + sr];
  const ushort* arow = Xb + ((size_t)(b * SEQ) + grow) * HD;
  const ushort* brow = Wt + ((size_t)(n * D3 + n0 + sr)) * HD;

  f32x4 acc[2][2];
#pragma unroll
  for (int i = 0; i < 2; i++)
#pragma unroll
    for (int j = 0; j < 2; j++)
#pragma unroll
      for (int r = 0; r < 4; r++) acc[i][j][r] = 0.f;

  for (int k0 = 0; k0 < HD; k0 += 32) {
    __syncthreads();
    *(short8*)&As[sr][8 * sc4] = *(const short8*)(arow + k0 + 8 * sc4);
    *(short8*)&Bs[sr][8 * sc4] = *(const short8*)(brow + k0 + 8 * sc4);
    __syncthreads();
    short8 af[2], bf_[2];
#pragma unroll
    for (int i = 0; i < 2; i++) af[i] = *(const short8*)&As[32 * wm + 16 * i + cc][8 * quad];
#pragma unroll
    for (int j = 0; j < 2; j++) bf_[j] = *(const short8*)&Bs[32 * wn + 16 * j + cc][8 * quad];
#pragma unroll
    for (int i = 0; i < 2; i++)
#pragma unroll
      for (int j = 0; j < 2; j++)
        acc[i][j] = __builtin_amdgcn_mfma_f32_16x16x32_bf16(af[i], bf_[j], acc[i][j], 0, 0, 0);
  }

#pragma unroll
  for (int i = 0; i < 2; i++)
#pragma unroll
    for (int j = 0; j < 2; j++) {
      int col = n0 + 32 * wn + 16 * j + cc;   // 0..191, segment = n0 (uniform)
      int row0 = m0 + 32 * wm + 16 * i + 4 * quad;
      if (col < 64) {
#pragma unroll
        for (int r = 0; r < 4; r++)
          Qmg[((size_t)bn * KSEL + row0 + r) * 64 + col] = bf16u(acc[i][j][r] * 0.125f);
      } else if (col < 128) {
#pragma unroll
        for (int r = 0; r < 4; r++)
          Kmg[((size_t)bn * KSEL + row0 + r) * 64 + (col - 64)] = bf16u(acc[i][j][r]);
      } else {
        ushort4 pk;
        pk.x = bf16u(acc[i][j][0]); pk.y = bf16u(acc[i][j][1]);
        pk.z = bf16u(acc[i][j][2]); pk.w = bf16u(acc[i][j][3]);
        *(ushort4*)&Vtmg[((size_t)bn * 64 + (col - 128)) * KSEL + row0] = pk;
      }
    }
}

// ---------------- RoPE on split Q/K layouts (rows of 64) ----------------
__global__ void rope_split(ushort* __restrict__ Qb, ushort* __restrict__ Kb,
                           const int* __restrict__ sel, int mosa) {
  int tid = blockIdx.x * 256 + threadIdx.x;
  int j = tid & 15;
  int which = (tid >> 4) & 1;                 // 0: Q, 1: K
  int row = tid >> 5;
  float pos = mosa ? (float)sel[row] : (float)(row & (SEQ - 1));
  float inv = __expf((float)j * -0.5756462732485115f);
  float ang = pos * inv;
  float c = cosf(ang), sn = sinf(ang);
  ushort* p = (which ? Kb : Qb) + (size_t)row * 64 + j;
  float x1 = bf2f(p[0]), x2 = bf2f(p[16]);
  p[0] = bf16u(x1 * c - x2 * sn);
  p[16] = bf16u(x1 * sn + x2 * c);
}

// ---------------- flash6: split-K flash attention ----------------
// bx in [0,2048): dense, bn=bx&15, qt=(bx>>4)&31, chunk=bx>>9; chunk c handles
// kt = c, c+4, ... (strided -> inherently balanced, <=8 tiles critical path).
// Partial (unnormalized O bf16, m/l f32) to Opart/Mlp; flash_merge combines.
// bx in [2048,2112): mosa, direct gated scatter to avm (<=4 tiles).
__global__ __launch_bounds__(256) void flash6(
    const ushort* __restrict__ Qg, const ushort* __restrict__ Kg,
    const ushort* __restrict__ Vtg,
    const ushort* __restrict__ Qmg, const ushort* __restrict__ Kmg,
    const ushort* __restrict__ Vtmg,
    const int* __restrict__ sel, const float* __restrict__ gates,
    ushort* __restrict__ Opart, float2* __restrict__ Mlp,
    ushort* __restrict__ avm) {
  __shared__ __align__(16) ushort Ks[2][64][64];
  __shared__ __align__(16) ushort Vt[2][64][64];
  __shared__ __align__(16) ushort Ps[64][64];

  int bx = blockIdx.x;
  bool mosa = bx >= 2048;
  int bn, qt, T, kstart, kstride;
  const ushort *Qb, *Kb, *Vb;
  if (!mosa) {
    bn = bx & 15; qt = (bx >> 4) & 31;
    kstart = bx >> 9; kstride = 4; T = SEQ;
    Qb = Qg + (size_t)bn * SEQ * 64;
    Kb = Kg + (size_t)bn * SEQ * 64;
    Vb = Vtg + (size_t)bn * 64 * SEQ;
  } else {
    int rr = bx - 2048;
    bn = rr & 15; qt = 3 - (rr >> 4);
    kstart = 0; kstride = 1; T = KSEL;
    Qb = Qmg + (size_t)bn * KSEL * 64;
    Kb = Kmg + (size_t)bn * KSEL * 64;
    Vb = Vtmg + (size_t)bn * 64 * KSEL;
  }
  int b = bn >> 3, n = bn & 7;
  int tid = threadIdx.x;
  int lane = tid & 63, w = tid >> 6;
  int cc = lane & 15, quad = lane >> 4;
  int qrow = 16 * w + cc;

  // Q fragments straight from global (pre-scaled by 1/8 upstream); loop-invariant
  short8 bq[2];
  {
    const ushort* qsrc = Qb + (size_t)(qt * 64 + qrow) * 64;
    bq[0] = *(const short8*)(qsrc + 8 * quad);
    bq[1] = *(const short8*)(qsrc + 8 * (quad + 4));
  }

  // staging addresses: slice = 8 rows x 128B per wave-instr; lane l -> row +(l>>3),
  // phys chunk l&7 holds logical chunk (l&7)^(row&7)  (xor swizzle inverse)
  int rloc = lane >> 3;
  int c_log = (lane & 7) ^ rloc;
  int row0 = 16 * w + rloc, row1 = row0 + 8;
  const ushort* pK0 = Kb + (size_t)row0 * 64 + 8 * c_log;
  const ushort* pK1 = Kb + (size_t)row1 * 64 + 8 * c_log;
  const ushort* pV0 = Vb + (size_t)row0 * T + 8 * c_log;
  const ushort* pV1 = Vb + (size_t)row1 * T + 8 * c_log;

  f32x4 oacc[4];
  float m = NEG, l = 0.f;
#pragma unroll
  for (int jd = 0; jd < 4; jd++)
#pragma unroll
    for (int r = 0; r < 4; r++) oacc[jd][r] = 0.f;

  if (kstart <= qt) {
    // prefetch first tile into buf 0
    gl_lds16(pK0 + (size_t)kstart * 4096, &Ks[0][16 * w][0]);
    gl_lds16(pK1 + (size_t)kstart * 4096, &Ks[0][16 * w + 8][0]);
    gl_lds16(pV0 + kstart * 64, &Vt[0][16 * w][0]);
    gl_lds16(pV1 + kstart * 64, &Vt[0][16 * w + 8][0]);
  }

  int it = 0;
  for (int kt = kstart; kt <= qt; kt += kstride, it++) {
    int buf = it & 1;
    __syncthreads();          // implicit vmcnt(0): buf's loads complete; prev buf free
    int nk = kt + kstride;
    if (nk <= qt) {
      int nb = buf ^ 1;
      gl_lds16(pK0 + (size_t)nk * 4096, &Ks[nb][16 * w][0]);
      gl_lds16(pK1 + (size_t)nk * 4096, &Ks[nb][16 * w + 8][0]);
      gl_lds16(pV0 + nk * 64, &Vt[nb][16 * w][0]);
      gl_lds16(pV1 + nk * 64, &Vt[nb][16 * w + 8][0]);
    }

    // S^T = K.Q^T : C col = q (cc), row = key (16j + 4quad + r)
    f32x4 sacc[4];
#pragma unroll
    for (int j = 0; j < 4; j++)
#pragma unroll
      for (int r = 0; r < 4; r++) sacc[j][r] = 0.f;
#pragma unroll
    for (int ks = 0; ks < 2; ks++) {
#pragma unroll
      for (int j = 0; j < 4; j++) {
        int krow = 16 * j + cc;
        short8 ak = *(const short8*)&Ks[buf][krow][8 * ((quad + 4 * ks) ^ (krow & 7))];
        sacc[j] = __builtin_amdgcn_mfma_f32_16x16x32_bf16(ak, bq[ks], sacc[j], 0, 0, 0);
      }
    }
    if (kt == qt) {
#pragma unroll
      for (int j = 0; j < 4; j++)
#pragma unroll
        for (int r = 0; r < 4; r++)
          if (16 * j + 4 * quad + r > qrow) sacc[j][r] = NEG;
    }
    // per-lane online softmax (q = 16w+cc fixed per lane)
    float mx = NEG;
#pragma unroll
    for (int j = 0; j < 4; j++)
#pragma unroll
      for (int r = 0; r < 4; r++) mx = fmaxf(mx, sacc[j][r]);
    mx = fmaxf(mx, __shfl_xor(mx, 16));
    mx = fmaxf(mx, __shfl_xor(mx, 32));
    float mn = fmaxf(m, mx);
    float sc = __expf(m - mn);
    m = mn;
    float rsum = 0.f;
    float p[4][4];
#pragma unroll
    for (int j = 0; j < 4; j++)
#pragma unroll
      for (int r = 0; r < 4; r++) { p[j][r] = __expf(sacc[j][r] - mn); rsum += p[j][r]; }
    rsum += __shfl_xor(rsum, 16);
    rsum += __shfl_xor(rsum, 32);
    l = l * sc + rsum;
    // Ps[q][key] packed b64 (wave-local rows)
#pragma unroll
    for (int j = 0; j < 4; j++) {
      ushort4 pk;
      pk.x = bf16u(p[j][0]); pk.y = bf16u(p[j][1]);
      pk.z = bf16u(p[j][2]); pk.w = bf16u(p[j][3]);
      int phys = (2 * j + (quad >> 1)) ^ (qrow & 7);
      *(ushort4*)&Ps[qrow][phys * 8 + 4 * (quad & 1)] = pk;
    }
    // rescale O rows (q-local = 4quad+r) by that q's sc
#pragma unroll
    for (int r = 0; r < 4; r++) {
      float scr = __shfl(sc, 16 * quad + 4 * quad + r);
#pragma unroll
      for (int jd = 0; jd < 4; jd++) oacc[jd][r] *= scr;
    }
    __asm__ volatile("s_waitcnt lgkmcnt(0)" ::: "memory");
    // O += P.V
#pragma unroll
    for (int ks = 0; ks < 2; ks++) {
      short8 ap = *(const short8*)&Ps[qrow][8 * ((quad + 4 * ks) ^ (qrow & 7))];
#pragma unroll
      for (int jd = 0; jd < 4; jd++) {
        int vrow = 16 * jd + cc;
        short8 bv = *(const short8*)&Vt[buf][vrow][8 * ((quad + 4 * ks) ^ (vrow & 7))];
        oacc[jd] = __builtin_amdgcn_mfma_f32_16x16x32_bf16(ap, bv, oacc[jd], 0, 0, 0);
      }
    }
  }

  if (!mosa) {
    // partial epilogue: unnormalized O (bf16) + (m,l) per q-row
    size_t pb = ((size_t)(bn * 32 + qt) * 4 + (size_t)(kstart));
    ushort* obase = Opart + pb * 4096;
#pragma unroll
    for (int r = 0; r < 4; r++) {
      int ql = 16 * w + 4 * quad + r;
#pragma unroll
      for (int jd = 0; jd < 4; jd++)
        obase[ql * 64 + 16 * jd + cc] = bf16u(oacc[jd][r]);
    }
    if (quad == 0) Mlp[pb * 64 + qrow] = make_float2(m, l);
  } else {
    // direct gated scatter (unchanged)
#pragma unroll
    for (int r = 0; r < 4; r++) {
      float lr = __shfl(l, 16 * quad + 4 * quad + r);
      int q = qt * 64 + 16 * w + 4 * quad + r;
      int trow = sel[bn * KSEL + q];
      float scale = gates[bn * KSEL + q] / lr;
      size_t row = (size_t)(b * SEQ + trow);
      ushort* orow = avm + row * (NHEAD * DH) + n * DH;
#pragma unroll
      for (int jd = 0; jd < 4; jd++)
        orow[16 * jd + cc] = bf16u(oacc[jd][r] * scale);
    }
  }
}

// ---------------- merge 4 split-K partials -> avd ----------------
__global__ __launch_bounds__(256) void flash_merge(const ushort* __restrict__ Opart,
    const float2* __restrict__ Mlp, ushort* __restrict__ avd) {
  int bq = blockIdx.x;            // bn*32 + qt
  int bn = bq >> 5, qt = bq & 31;
  int b = bn >> 3, n = bn & 7;
  int tid = threadIdx.x;
  int q = tid >> 2, ds = (tid & 3) * 16;
  size_t pb = (size_t)bq * 4;
  float2 ml[4];
#pragma unroll
  for (int c = 0; c < 4; c++) ml[c] = Mlp[(pb + c) * 64 + q];
  float M = fmaxf(fmaxf(ml[0].x, ml[1].x), fmaxf(ml[2].x, ml[3].x));
  float wgt[4], L = 0.f;
#pragma unroll
  for (int c = 0; c < 4; c++) { wgt[c] = __expf(ml[c].x - M); L += wgt[c] * ml[c].y; }
  float inv = 1.f / L;
  float acc[16] = {};
#pragma unroll
  for (int c = 0; c < 4; c++) {
    const ushort* op = Opart + (pb + c) * 4096 + q * 64 + ds;
#pragma unroll
    for (int d = 0; d < 16; d++) acc[d] += wgt[c] * bf2f(op[d]);
  }
  ushort* orow = avd + ((size_t)(b * SEQ + qt * 64 + q)) * (NHEAD * DH) + n * DH + ds;
#pragma unroll
  for (int d = 0; d < 16; d++) orow[d] = bf16u(acc[d] * inv);
}

// ---------------- bf16 MFMA GEMM, 128x128 tile, BK=32, async gl_lds staging ----------
template <int MODE>
__global__ __launch_bounds__(256) void gemm_bf16(
    const ushort* __restrict__ A1, const ushort* __restrict__ B1t, int K1,
    const ushort* __restrict__ A2, const ushort* __restrict__ B2t, int K2,
    void* __restrict__ outv, int N,
    ushort* __restrict__ Qo, ushort* __restrict__ Ko, ushort* __restrict__ Vto) {
  __shared__ __align__(16) ushort As[128][32];
  __shared__ __align__(16) ushort Bs[128][32];
  int m0 = blockIdx.x * 128, n0 = blockIdx.y * 128;
  int tid = threadIdx.x;
  int lane = tid & 63, wave = tid >> 6;
  int wm = wave & 1, wn = wave >> 1;
  int cc = lane & 15, quad = lane >> 4;

  int srow = 16 * wave + (lane >> 2);
  int c_log = ((lane & 3) - (lane >> 3)) & 3;

  f32x4 acc[4][4];
#pragma unroll
  for (int i = 0; i < 4; i++)
#pragma unroll
    for (int j = 0; j < 4; j++)
#pragma unroll
      for (int r = 0; r < 4; r++) acc[i][j][r] = 0.f;

  const int npass = (MODE == 0) ? 2 : 1;
  for (int pass = 0; pass < npass; pass++) {
    const ushort* A = pass ? A2 : A1;
    const ushort* Bt = pass ? B2t : B1t;
    int K = pass ? K2 : K1;
    const ushort* pA0 = A + (size_t)(m0 + srow) * K + 8 * c_log;
    const ushort* pA1 = A + (size_t)(m0 + srow + 64) * K + 8 * c_log;
    const ushort* pB0 = Bt + (size_t)(n0 + srow) * K + 8 * c_log;
    const ushort* pB1 = Bt + (size_t)(n0 + srow + 64) * K + 8 * c_log;
    for (int k0 = 0; k0 < K; k0 += 32) {
      __syncthreads();
      gl_lds16(pA0 + k0, &As[16 * wave][0]);
      gl_lds16(pA1 + k0, &As[16 * wave + 64][0]);
      gl_lds16(pB0 + k0, &Bs[16 * wave][0]);
      gl_lds16(pB1 + k0, &Bs[16 * wave + 64][0]);
      __syncthreads();
      short8 af[4], bfr[4];
#pragma unroll
      for (int i = 0; i < 4; i++) {
        int ra = 64 * wm + 16 * i + cc;
        af[i] = *(const short8*)&As[ra][8 * ((quad + (ra >> 1)) & 3)];
      }
#pragma unroll
      for (int j = 0; j < 4; j++) {
        int rb = 64 * wn + 16 * j + cc;
        bfr[j] = *(const short8*)&Bs[rb][8 * ((quad + (rb >> 1)) & 3)];
      }
#pragma unroll
      for (int i = 0; i < 4; i++)
#pragma unroll
        for (int j = 0; j < 4; j++)
          acc[i][j] = __builtin_amdgcn_mfma_f32_16x16x32_bf16(af[i], bfr[j], acc[i][j], 0, 0, 0);
    }
  }

#pragma unroll
  for (int i = 0; i < 4; i++) {
#pragma unroll
    for (int j = 0; j < 4; j++) {
      int colg = n0 + 64 * wn + 16 * j + cc;
      int row0 = m0 + 64 * wm + 16 * i + 4 * quad;
      if (MODE == 0) {
#pragma unroll
        for (int r = 0; r < 4; r++)
          ((float*)outv)[(size_t)(row0 + r) * N + colg] = acc[i][j][r];
      } else {
        int nn = colg / 192, c = colg % 192;
        int b2 = row0 >> 11, t2 = row0 & 2047;
        int bn2 = b2 * 8 + nn;
        if (c < 64) {
#pragma unroll
          for (int r = 0; r < 4; r++)
            Qo[((size_t)bn2 * SEQ + t2 + r) * 64 + c] = bf16u(acc[i][j][r] * 0.125f);
        } else if (c < 128) {
#pragma unroll
          for (int r = 0; r < 4; r++)
            Ko[((size_t)bn2 * SEQ + t2 + r) * 64 + (c - 64)] = bf16u(acc[i][j][r]);
        } else {
          ushort4 pk;
          pk.x = bf16u(acc[i][j][0]); pk.y = bf16u(acc[i][j][1]);
          pk.z = bf16u(acc[i][j][2]); pk.w = bf16u(acc[i][j][3]);
          *(ushort4*)&Vto[((size_t)bn2 * 64 + (c - 128)) * SEQ + t2] = pk;
        }
      }
    }
  }
}

extern "C" void kernel_launch(void* const* d_in, const int* in_sizes, int n_in,
                              void* d_out, int out_size, void* d_ws, size_t ws_size,
                              hipStream_t stream) {
  const float* X          = (const float*)d_in[0];
  const float* router_w   = (const float*)d_in[1];
  const float* mosa_wqkv  = (const float*)d_in[2];
  const float* mosa_wo    = (const float*)d_in[3];
  const float* dense_wqkv = (const float*)d_in[4];
  const float* dense_wo   = (const float*)d_in[5];
  float* out = (float*)d_out;
  char* ws = (char*)d_ws;

  // workspace layout (bytes)
  float*  scores  = (float*) (ws + 0);          // 131072
  int*    sel     = (int*)   (ws + 131072);     // 16384
  float*  gates   = (float*) (ws + 147456);     // 16384
  ushort* avm     = (ushort*)(ws + 163840);     // 4194304
  ushort* avd     = (ushort*)(ws + 4358144);    // 4194304
  ushort* Xb      = (ushort*)(ws + 8552448);    // 8388608
  ushort* Wqkv_t  = (ushort*)(ws + 16941056);   // 3145728
  ushort* Wmq_t   = (ushort*)(ws + 20086784);   // 3145728
  ushort* Wdo_t   = (ushort*)(ws + 23232512);   // 1048576
  ushort* Wmo_t   = (ushort*)(ws + 24281088);   // 1048576
  ushort* Qg      = (ushort*)(ws + 25329664);   // 4194304  (16 bn x 2048 x 64)
  ushort* Kg      = (ushort*)(ws + 29523968);   // 4194304
  ushort* Vtg     = (ushort*)(ws + 33718272);   // 4194304  (16 bn x 64 x 2048)
  ushort* Qmg     = (ushort*)(ws + 37912576);   // 524288   (16 bn x 256 x 64)
  ushort* Kmg     = (ushort*)(ws + 38436864);   // 524288
  ushort* Vtmg    = (ushort*)(ws + 38961152);   // 524288
  int*    pranks  = (int*)   (ws + 39485440);   // 4194304
  ushort* Opart   = (ushort*)(ws + 43679744);   // 16*32*4*4096*2 = 16777216
  float2* Mlp     = (float2*)(ws + 60456960);   // 16*32*4*64*8   = 2097152 (end 62554112)

  hipMemsetAsync(avm, 0, (size_t)BB * SEQ * NHEAD * DH * sizeof(ushort), stream);

  // casts / transposes
  cast_bf16x4<<<4096, 256, 0, stream>>>(X, Xb, BB * SEQ * HD / 4);
  transpose_cast2<<<dim3(48, 32, 2), 256, 0, stream>>>(dense_wqkv, Wqkv_t,
                                                       mosa_wqkv, Wmq_t, 1024, 1536);
  transpose_cast2<<<dim3(32, 16, 2), 256, 0, stream>>>(dense_wo, Wdo_t,
                                                       mosa_wo, Wmo_t, 512, 1024);

  // router + top-k
  router2<<<BB * SEQ / 32, 256, 0, stream>>>(X, router_w, scores);
  topk_partial<<<dim3(BB * NHEAD, 32), 256, 0, stream>>>(scores, pranks);
  topk_select<<<BB * NHEAD, 1024, 0, stream>>>(scores, pranks, sel, gates);

  // qkv projections (mosa gathered + dense)
  gemm_mosa_bf16<<<dim3(BB * NHEAD, KSEL / 64, D3 / 64), 256, 0, stream>>>(
      Xb, Wmq_t, sel, Qmg, Kmg, Vtmg);
  rope_split<<<(BB * NHEAD * KSEL * 32) / 256, 256, 0, stream>>>(Qmg, Kmg, sel, 1);
  gemm_bf16<1><<<dim3(32, 12), 256, 0, stream>>>(Xb, Wqkv_t, 1024,
      (const ushort*)nullptr, (const ushort*)nullptr, 0, nullptr, NHEAD * D3,
      Qg, Kg, Vtg);
  rope_split<<<(BB * NHEAD * SEQ * 32) / 256, 256, 0, stream>>>(Qg, Kg, nullptr, 0);

  // split-K flash attention (dense 2048 chunk-blocks + mosa 64) + merge
  flash6<<<2112, 256, 0, stream>>>(Qg, Kg, Vtg, Qmg, Kmg, Vtmg, sel, gates,
                                   Opart, Mlp, avm);
  flash_merge<<<512, 256, 0, stream>>>(Opart, Mlp, avd);

  // final: out = avm@mosa_wo + avd@dense_wo  (f32 out)
  gemm_bf16<0><<<dim3(32, 8), 256, 0, stream>>>(avm, Wmo_t, 512, avd, Wdo_t, 512, out, HD,
                                                nullptr, nullptr, nullptr);
}